// Round 12
// baseline (867.990 us; speedup 1.0000x reference)
//
#include <hip/hip_runtime.h>
#include <math.h>

#define B_   4
#define L_   2048
#define DM_  512
#define H_   8
#define DK_  64
#define DFF_ 2048
#define E_   3
#define U_   40
#define R_   8192
#define SCALE_ 0.125f
#define EPS_ 1e-5f

typedef __bf16 bf16x8 __attribute__((ext_vector_type(8)));
typedef float f32x4 __attribute__((ext_vector_type(4)));

__device__ inline unsigned short f2bf(float x) {
  unsigned int u = __float_as_uint(x);
  unsigned int r = (u + 0x7fffu + ((u >> 16) & 1u)) >> 16;
  return (unsigned short)r;
}

// ---------------------------------------------------------------------------
// Weight transpose fp32 [R][C] -> bf16 [C][R].  (Wq/Wk/Wv + W1 + W2 only)
// ---------------------------------------------------------------------------
__global__ __launch_bounds__(256) void wtrans(
    const float* __restrict__ s0, const float* __restrict__ s1,
    const float* __restrict__ s2,
    unsigned short* __restrict__ dst, int R, int C, int permat) {
  __shared__ float tile[32][33];
  int z = blockIdx.z;
  int which = z / 3, e = z % 3;
  const float* src = (which == 0 ? s0 : which == 1 ? s1 : s2);
  src += (size_t)e * permat;
  unsigned short* d = dst + (size_t)z * permat;
  int c0 = blockIdx.x << 5, r0 = blockIdx.y << 5;
  int tx = threadIdx.x & 31, ty = threadIdx.x >> 5;
  for (int rr = ty; rr < 32; rr += 8)
    tile[rr][tx] = src[(size_t)(r0 + rr) * C + c0 + tx];
  __syncthreads();
  for (int cc = ty; cc < 32; cc += 8)
    d[(size_t)(c0 + cc) * R + r0 + tx] = f2bf(tile[tx][cc]);
}

// ---------------------------------------------------------------------------
// x = DNAs @ W_pre + b_pre ; writes fp32 X and bf16 Xbf
// ---------------------------------------------------------------------------
__global__ __launch_bounds__(256) void pre_kernel(
    const float* __restrict__ DNAs, const float* __restrict__ Wp,
    const float* __restrict__ bp, float* __restrict__ X,
    unsigned short* __restrict__ Xbf) {
  int t = blockIdx.x * 256 + threadIdx.x;
  int r = t >> 9, d = t & 511;
  float4 dna = *(const float4*)(DNAs + r * 4);
  float v = dna.x * Wp[d] + dna.y * Wp[512 + d] + dna.z * Wp[1024 + d] +
            dna.w * Wp[1536 + d] + bp[d];
  X[t] = v;
  Xbf[t] = f2bf(v);
}

// ---------------------------------------------------------------------------
// bf16 MFMA GEMM (m97 structure, 128x128 tile, BK=64, XOR-swizzled LDS).
// 1-D grid, XCD-affinity (m-tile = id&63 -> id%8 == m%8). DBUF: 2-phase
// prefetch for 1-block/CU dispatches. OUT: 0 fp32; 1 fp32 QKV remap; 2 bf16+ReLU.
// ---------------------------------------------------------------------------
template <int OUT, bool QKVZ, bool DBUF>
__global__ __launch_bounds__(256) void mgemm(
    const unsigned short* __restrict__ A, const unsigned short* __restrict__ BT,
    const float* __restrict__ bias0, const float* __restrict__ bias1,
    const float* __restrict__ bias2, float* __restrict__ Cf,
    unsigned short* __restrict__ Cb, int M, int N, int K) {
  __shared__ unsigned short As[(DBUF ? 2 : 1) * 128 * 64];
  __shared__ unsigned short Bs[(DBUF ? 2 : 1) * 128 * 64];
  const int t = threadIdx.x, l = t & 63, w = t >> 6;
  const int id = blockIdx.x;
  const int m0 = (id & 63) << 7, n0 = (id >> 6) << 7;
  const int wm = w >> 1, wn = w & 1;
  const float* bias = bias0;
  if (QKVZ) {
    int z = blockIdx.z;
    BT += (size_t)z * 3 * 262144;
    bias = (z == 0 ? bias0 : z == 1 ? bias1 : bias2);
    Cf += (size_t)z * 4194304;
  }
  f32x4 acc[4][4] = {};

  const int srow = l >> 3;
  const int gslot = (l & 7) ^ srow;

  auto stage = [&](int buf, int k0) {
#pragma unroll
    for (int j = 0; j < 4; ++j) {
      int c = (w << 2) + j;
      int row = (c << 3) + srow;
      const unsigned short* ga = A + (size_t)(m0 + row) * K + k0 + gslot * 8;
      const unsigned short* gb = BT + (size_t)(n0 + row) * K + k0 + gslot * 8;
      __builtin_amdgcn_global_load_lds(
          (const __attribute__((address_space(1))) void*)ga,
          (__attribute__((address_space(3))) void*)(As + buf * 8192 + (c << 9)), 16, 0, 0);
      __builtin_amdgcn_global_load_lds(
          (const __attribute__((address_space(1))) void*)gb,
          (__attribute__((address_space(3))) void*)(Bs + buf * 8192 + (c << 9)), 16, 0, 0);
    }
  };
  auto compute = [&](int buf) {
#pragma unroll
    for (int ks = 0; ks < 2; ++ks) {
      bf16x8 af[4], bg[4];
      int slot = (ks << 2) + (l >> 4);
#pragma unroll
      for (int i = 0; i < 4; ++i) {
        int ar = (wm << 6) + (i << 4) + (l & 15);
        af[i] = *(const bf16x8*)(As + buf * 8192 + ar * 64 + (slot ^ (ar & 7)) * 8);
        int br = (wn << 6) + (i << 4) + (l & 15);
        bg[i] = *(const bf16x8*)(Bs + buf * 8192 + br * 64 + (slot ^ (br & 7)) * 8);
      }
#pragma unroll
      for (int i = 0; i < 4; ++i)
#pragma unroll
        for (int j = 0; j < 4; ++j)
          acc[i][j] = __builtin_amdgcn_mfma_f32_16x16x32_bf16(af[i], bg[j],
                                                              acc[i][j], 0, 0, 0);
    }
  };

  if (DBUF) {
    int nk = K >> 6, cur = 0;
    stage(0, 0);
    __syncthreads();
    for (int s = 0; s < nk; ++s) {
      if (s + 1 < nk) stage(cur ^ 1, (s + 1) << 6);
      compute(cur);
      __syncthreads();
      cur ^= 1;
    }
  } else {
    for (int k0 = 0; k0 < K; k0 += 64) {
      stage(0, k0);
      __syncthreads();
      compute(0);
      __syncthreads();
    }
  }

#pragma unroll
  for (int i = 0; i < 4; ++i) {
    int rbase = m0 + (wm << 6) + (i << 4) + ((l >> 4) << 2);
#pragma unroll
    for (int j = 0; j < 4; ++j) {
      int col = n0 + (wn << 6) + (j << 4) + (l & 15);
      float bv = bias[col];
#pragma unroll
      for (int r = 0; r < 4; ++r) {
        int row = rbase + r;
        float v = acc[i][j][r] + bv;
        if (OUT == 2) {
          v = fmaxf(v, 0.f);
          Cb[(size_t)row * N + col] = f2bf(v);
        } else if (OUT == 1) {
          int b = row >> 11, ll = row & 2047, h = col >> 6, d = col & 63;
          Cf[((size_t)(((b << 3) + h) << 11) + ll) * 64 + d] = v;
        } else {
          Cf[(size_t)row * N + col] = v;
        }
      }
    }
  }
}

// ---------------------------------------------------------------------------
// Sampled-score M: 8 queries/wave, 8 lanes/query, line-contiguous loads.
// ---------------------------------------------------------------------------
__global__ __launch_bounds__(256) void qk_m_kernel(
    const float* __restrict__ Q, const float* __restrict__ K,
    const int* __restrict__ sidx, float* __restrict__ Mout) {
  int t = threadIdx.x;
  int wave = t >> 6, lane = t & 63;
  int grp = lane >> 3, sub = lane & 7;
  int bh = blockIdx.x & 31;
  int j = blockIdx.x >> 5;
  int item = (bh << 11) + (j << 5) + wave * 8 + grp;
  int l = item & 2047;
  const float* Qr = Q + (size_t)item * 64;
  float4 q0 = *(const float4*)(Qr + sub * 4);
  float4 q1 = *(const float4*)(Qr + 32 + sub * 4);
  const float* Kb = K + (((size_t)bh << 11) << 6);
  const int* sp = sidx + l * U_;
  float mx = -INFINITY, sm = 0.f;
#pragma unroll 8
  for (int u = 0; u < U_; ++u) {
    int kidx = sp[u];
    const float* kr = Kb + ((size_t)kidx << 6);
    float4 k0 = *(const float4*)(kr + sub * 4);
    float4 k1 = *(const float4*)(kr + 32 + sub * 4);
    float p = q0.x * k0.x + q0.y * k0.y + q0.z * k0.z + q0.w * k0.w;
    p = fmaf(q1.x, k1.x, p); p = fmaf(q1.y, k1.y, p);
    p = fmaf(q1.z, k1.z, p); p = fmaf(q1.w, k1.w, p);
    p += __shfl_xor(p, 1);
    p += __shfl_xor(p, 2);
    p += __shfl_xor(p, 4);
    mx = fmaxf(mx, p);
    sm += p;
  }
  if (sub == 0) Mout[item] = mx - sm * (1.0f / U_);
}

// ---------------------------------------------------------------------------
// Exact top-40 via 4-pass radix select. INV packed [b][l][8]: row (b,l)'s
// 8 head-slots are contiguous (32B) so lnattn reads them in 2 int4 loads.
// ---------------------------------------------------------------------------
__global__ __launch_bounds__(256) void topk_kernel(
    const float* __restrict__ Mb, int* __restrict__ TOP, int* __restrict__ INV) {
  __shared__ unsigned vals[2048];
  __shared__ int hist[256];
  __shared__ int suf[256];
  __shared__ unsigned s_prefix;
  __shared__ int s_want, s_cnt, s_run;
  __shared__ int wcnt[4];
  int bh = blockIdx.x, t = threadIdx.x;
  int lane = t & 63, w = t >> 6;
  int b = bh >> 3, h = bh & 7;
  int* INVb = INV + ((size_t)b << 14) + h;      // [b][l][8] + h
  for (int i = t; i < 2048; i += 256) {
    unsigned u = __float_as_uint(Mb[bh * 2048 + i]);
    vals[i] = (u & 0x80000000u) ? ~u : (u | 0x80000000u);
    INVb[i << 3] = -1;
  }
  if (t == 0) { s_prefix = 0; s_want = U_; s_cnt = 0; s_run = 0; }
  __syncthreads();
#pragma unroll
  for (int shift = 24; shift >= 0; shift -= 8) {
    unsigned pref = s_prefix;
    int want = s_want;
    unsigned hmask = (shift == 24) ? 0u : (0xFFFFFFFFu << (shift + 8));
    hist[t] = 0;
    __syncthreads();
    for (int i = t; i < 2048; i += 256) {
      unsigned v = vals[i];
      if ((v & hmask) == pref) atomicAdd(&hist[(v >> shift) & 255], 1);
    }
    __syncthreads();
    suf[t] = hist[t];
    __syncthreads();
    for (int off = 1; off < 256; off <<= 1) {
      int add = (t + off < 256) ? suf[t + off] : 0;
      __syncthreads();
      suf[t] += add;
      __syncthreads();
    }
    int cgt = (t == 255) ? 0 : suf[t + 1];
    if (suf[t] >= want && cgt < want) {
      s_prefix = pref | ((unsigned)t << shift);
      s_want = want - cgt;
    }
    __syncthreads();
  }
  unsigned T = s_prefix;
  int want_eq = s_want;
  int base = U_ - want_eq;
  for (int i = t; i < 2048; i += 256) {
    if (vals[i] > T) {
      int slot = atomicAdd(&s_cnt, 1);
      TOP[bh * U_ + slot] = i;
      INVb[i << 3] = slot;
    }
  }
  for (int c = 0; c < 8; ++c) {
    int i = (c << 8) + t;
    bool eq = (vals[i] == T);
    unsigned long long m = __ballot(eq);
    if (lane == 0) wcnt[w] = __popcll(m);
    __syncthreads();
    int woff = 0;
    for (int ww = 0; ww < w; ++ww) woff += wcnt[ww];
    if (eq) {
      int rank = s_run + woff + __popcll(m & ((1ull << lane) - 1ull));
      if (rank < want_eq) {
        TOP[bh * U_ + base + rank] = i;
        INVb[i << 3] = base + rank;
      }
    }
    __syncthreads();
    if (t == 0) s_run += wcnt[0] + wcnt[1] + wcnt[2] + wcnt[3];
    __syncthreads();
  }
}

// ---------------------------------------------------------------------------
// vmean[bh,d] = mean over L of V[bh,l,d]
// ---------------------------------------------------------------------------
__global__ __launch_bounds__(256) void vmean_kernel(
    const float* __restrict__ V, float* __restrict__ VM) {
  __shared__ float p[4][64];
  int bh = blockIdx.x;
  int d = threadIdx.x & 63, c = threadIdx.x >> 6;
  const float* Vb = V + (((size_t)bh << 11) + c * 512) * 64;
  float s = 0.f;
  for (int l = 0; l < 512; ++l) s += Vb[l * 64 + d];
  p[c][d] = s;
  __syncthreads();
  if (threadIdx.x < 64)
    VM[bh * 64 + d] = (p[0][d] + p[1][d] + p[2][d] + p[3][d]) * (1.0f / 2048.0f);
}

// ---------------------------------------------------------------------------
// base[b][c] = concat_h(vmean[b,h,:]) @ Wo[:,c] + bo[c]   (4 x 512)
// ---------------------------------------------------------------------------
__global__ __launch_bounds__(512) void base_kernel(
    const float* __restrict__ VM, const float* __restrict__ Wo,
    const float* __restrict__ bo, float* __restrict__ BASEA) {
  int b = blockIdx.x, c = threadIdx.x;
  const float* vm = VM + (b << 9);
  float acc = bo[c];
#pragma unroll 8
  for (int d = 0; d < 512; ++d) acc = fmaf(vm[d], Wo[d * 512 + c], acc);
  BASEA[(b << 9) + c] = acc;
}

// ---------------------------------------------------------------------------
// S[bh,u,k] = scale * dot(Q[top[bh,u]], K[bh,k]).
// ---------------------------------------------------------------------------
__global__ __launch_bounds__(256) void attn_score(
    const float* __restrict__ Q, const float* __restrict__ K,
    const int* __restrict__ TOP, float* __restrict__ S) {
  __shared__ float Ks[128 * 65];
  __shared__ float Qs[40 * 64];
  int bh = blockIdx.y, k0 = blockIdx.x << 7;
  int t = threadIdx.x;
  for (int i = t; i < 2560; i += 256) {
    int u = i >> 6, d = i & 63;
    int row = TOP[bh * U_ + u];
    Qs[i] = Q[(((size_t)bh << 11) + row) * 64 + d];
  }
  for (int i = t; i < 8192; i += 256) {
    int k = i >> 6, d = i & 63;
    Ks[k * 65 + d] = K[(((size_t)bh << 11) + k0 + k) * 64 + d];
  }
  __syncthreads();
  int kk = t & 127, ug = (t >> 7) * 20;
  const float* kp = Ks + kk * 65;
  for (int u = ug; u < ug + 20; ++u) {
    const float* qp = Qs + u * 64;
    float s = 0.f;
#pragma unroll 8
    for (int d = 0; d < 64; ++d) s = fmaf(qp[d], kp[d], s);
    S[((size_t)bh * U_ + u) * 2048 + k0 + kk] = s * SCALE_;
  }
}

// ---------------------------------------------------------------------------
// softmax + P@V: 512 threads, 8 waves, one row per wave. Writes dense UPD.
// ---------------------------------------------------------------------------
__global__ __launch_bounds__(512) void attn_pv(
    const float* __restrict__ S, const float* __restrict__ V,
    float* __restrict__ UPD) {
  __shared__ float Vs[128][64];
  __shared__ float ps[8][128];
  __shared__ float mred[8], ired[8];
  int id = blockIdx.x;
  int bh = id & 31, ug = id >> 5;
  int t = threadIdx.x, lane = t & 63, w = t >> 6;
  int rowbase = bh * U_ + ug * 8;
  int row = rowbase + w;

  const float* Sr = S + (size_t)row * 2048;
  float mx = -INFINITY;
  for (int j = 0; j < 32; ++j) mx = fmaxf(mx, Sr[j * 64 + lane]);
#pragma unroll
  for (int s = 32; s; s >>= 1) mx = fmaxf(mx, __shfl_xor(mx, s));
  float sm = 0.f;
  for (int j = 0; j < 32; ++j) sm += __expf(Sr[j * 64 + lane] - mx);
#pragma unroll
  for (int s = 32; s; s >>= 1) sm += __shfl_xor(sm, s);
  if (lane == 0) { mred[w] = mx; ired[w] = 1.0f / sm; }
  __syncthreads();

  const float* Vb = V + (((size_t)bh << 11) << 6);
  float acc = 0.f;
  for (int c = 0; c < 16; ++c) {
    int k0 = c << 7;
#pragma unroll
    for (int i = 0; i < 4; ++i) {
      int ve = t + i * 512;
      int k = ve >> 4, dq = ve & 15;
      *(float4*)&Vs[k][dq << 2] = *(const float4*)(Vb + (size_t)(k0 + k) * 64 + (dq << 2));
    }
#pragma unroll
    for (int i = 0; i < 2; ++i) {
      int e = t + i * 512;
      int r = e >> 7, kk = e & 127;
      ps[r][kk] = __expf(S[(size_t)(rowbase + r) * 2048 + k0 + kk] - mred[r]);
    }
    __syncthreads();
    const float* p = ps[w];
#pragma unroll 4
    for (int kk = 0; kk < 128; kk += 4) {
      float4 p4 = *(const float4*)(p + kk);
      acc = fmaf(p4.x, Vs[kk + 0][lane], acc);
      acc = fmaf(p4.y, Vs[kk + 1][lane], acc);
      acc = fmaf(p4.z, Vs[kk + 2][lane], acc);
      acc = fmaf(p4.w, Vs[kk + 3][lane], acc);
    }
    __syncthreads();
  }
  UPD[((size_t)row << 6) + lane] = acc * ired[w];
}

// ---------------------------------------------------------------------------
// Fused: a = base[b] + sparse head deltas (= ctx@Wo + bo), x = LN(x + a).
// INV packed [b][l][8] -> 2 int4 loads; delta loop unrolled.
// ---------------------------------------------------------------------------
__global__ __launch_bounds__(256) void lnattn_kernel(
    const float* __restrict__ X, const float* __restrict__ BASEA,
    const int* __restrict__ INV, const float* __restrict__ UPD,
    const float* __restrict__ VM, const float* __restrict__ Wo,
    const float* __restrict__ g, const float* __restrict__ bta,
    float* __restrict__ Xout, unsigned short* __restrict__ Xbf) {
  __shared__ float red[8];
  int r = blockIdx.x, t = threadIdx.x;
  int b = r >> 11, l = r & 2047;
  int c0 = t << 1;
  // packed INV row: 8 ints in 32B
  const int4* ip = (const int4*)(INV + (((size_t)(b << 11) + l) << 3));
  int4 ua = ip[0], ub = ip[1];
  int uu[8] = {ua.x, ua.y, ua.z, ua.w, ub.x, ub.y, ub.z, ub.w};
  float2 av = *(const float2*)(BASEA + (b << 9) + c0);
  float a0 = av.x, a1 = av.y;
  int bh0 = b << 3;
#pragma unroll
  for (int h = 0; h < 8; ++h) {
    int u = uu[h];
    if (u >= 0) {                                  // block-uniform branch
      const float* up = UPD + ((size_t)((bh0 + h) * U_ + u) << 6);
      const float* vm = VM + ((bh0 + h) << 6);
      const float* wrow = Wo + ((h << 6) * 512);
#pragma unroll 8
      for (int d = 0; d < 64; ++d) {
        float dv = up[d] - vm[d];
        float2 w2 = *(const float2*)(wrow + d * 512 + c0);
        a0 = fmaf(dv, w2.x, a0);
        a1 = fmaf(dv, w2.y, a1);
      }
    }
  }
  int i0 = (r << 9) + c0;
  float2 xv = *(const float2*)(X + i0);
  float v0 = xv.x + a0, v1 = xv.y + a1;
  float sm = v0 + v1;
#pragma unroll
  for (int s = 32; s; s >>= 1) sm += __shfl_xor(sm, s);
  int lane = t & 63, w = t >> 6;
  if (lane == 0) red[w] = sm;
  __syncthreads();
  float mean = (red[0] + red[1] + red[2] + red[3]) * (1.0f / 512.0f);
  float d0 = v0 - mean, d1 = v1 - mean;
  float sq = d0 * d0 + d1 * d1;
#pragma unroll
  for (int s = 32; s; s >>= 1) sq += __shfl_xor(sq, s);
  if (lane == 0) red[4 + w] = sq;
  __syncthreads();
  float var = (red[4] + red[5] + red[6] + red[7]) * (1.0f / 512.0f);
  float rstd = rsqrtf(var + EPS_);
  float2 gv = *(const float2*)(g + c0);
  float2 bv = *(const float2*)(bta + c0);
  float o0 = d0 * rstd * gv.x + bv.x;
  float o1 = d1 * rstd * gv.y + bv.y;
  *(float2*)(Xout + i0) = make_float2(o0, o1);
  *(unsigned*)(Xbf + i0) = (unsigned)f2bf(o0) | ((unsigned)f2bf(o1) << 16);
}

// ---------------------------------------------------------------------------
// LayerNorm(512) with optional residual; float2-vectorized.
// ---------------------------------------------------------------------------
template <bool ADD, bool WB>
__global__ __launch_bounds__(256) void ln_kernel(
    const float* __restrict__ Xin, const float* __restrict__ Tin,
    const float* __restrict__ g, const float* __restrict__ bta,
    float* __restrict__ Xout, unsigned short* __restrict__ Xbf) {
  __shared__ float red[8];
  int r = blockIdx.x, t = threadIdx.x;
  int i0 = (r << 9) + (t << 1);
  float2 v = *(const float2*)(Xin + i0);
  if constexpr (ADD) {
    float2 tv = *(const float2*)(Tin + i0);
    v.x += tv.x; v.y += tv.y;
  }
  float sm = v.x + v.y;
#pragma unroll
  for (int s = 32; s; s >>= 1) sm += __shfl_xor(sm, s);
  int lane = t & 63, w = t >> 6;
  if (lane == 0) red[w] = sm;
  __syncthreads();
  float mean = (red[0] + red[1] + red[2] + red[3]) * (1.0f / 512.0f);
  float d0 = v.x - mean, d1 = v.y - mean;
  float sq = d0 * d0 + d1 * d1;
#pragma unroll
  for (int s = 32; s; s >>= 1) sq += __shfl_xor(sq, s);
  if (lane == 0) red[4 + w] = sq;
  __syncthreads();
  float var = (red[4] + red[5] + red[6] + red[7]) * (1.0f / 512.0f);
  float rstd = rsqrtf(var + EPS_);
  float2 gv = *(const float2*)(g + (t << 1));
  float2 bv = *(const float2*)(bta + (t << 1));
  float o0 = d0 * rstd * gv.x + bv.x;
  float o1 = d1 * rstd * gv.y + bv.y;
  *(float2*)(Xout + i0) = make_float2(o0, o1);
  if constexpr (WB) {
    *(unsigned*)(Xbf + i0) = (unsigned)f2bf(o0) | ((unsigned)f2bf(o1) << 16);
  }
}

// ---------------------------------------------------------------------------
// out = softmax(X @ W_out + b_out); one wave per row.
// ---------------------------------------------------------------------------
__global__ __launch_bounds__(256) void out_kernel(
    const float* __restrict__ X, const float* __restrict__ Wout,
    const float* __restrict__ bout, float* __restrict__ out) {
  int w = threadIdx.x >> 6, lane = threadIdx.x & 63;
  int r = blockIdx.x * 4 + w;
  float p0 = 0.f, p1 = 0.f, p2 = 0.f;
  for (int d = lane; d < 512; d += 64) {
    float x = X[(r << 9) + d];
    p0 += x * Wout[d * 3 + 0];
    p1 += x * Wout[d * 3 + 1];
    p2 += x * Wout[d * 3 + 2];
  }
#pragma unroll
  for (int s = 32; s; s >>= 1) {
    p0 += __shfl_xor(p0, s);
    p1 += __shfl_xor(p1, s);
    p2 += __shfl_xor(p2, s);
  }
  if (lane == 0) {
    p0 += bout[0]; p1 += bout[1]; p2 += bout[2];
    float m = fmaxf(p0, fmaxf(p1, p2));
    float e0 = __expf(p0 - m), e1 = __expf(p1 - m), e2 = __expf(p2 - m);
    float z = 1.0f / (e0 + e1 + e2);
    out[r * 3 + 0] = e0 * z;
    out[r * 3 + 1] = e1 * z;
    out[r * 3 + 2] = e2 * z;
  }
}

// ---------------------------------------------------------------------------
extern "C" void kernel_launch(void* const* d_in, const int* in_sizes, int n_in,
                              void* d_out, int out_size, void* d_ws, size_t ws_size,
                              hipStream_t stream) {
  const float* DNAs  = (const float*)d_in[0];
  const float* W_pre = (const float*)d_in[1];
  const float* b_pre = (const float*)d_in[2];
  const float* Wq    = (const float*)d_in[3];
  const float* bq    = (const float*)d_in[4];
  const float* Wk    = (const float*)d_in[5];
  const float* bk    = (const float*)d_in[6];
  const float* Wv    = (const float*)d_in[7];
  const float* bv    = (const float*)d_in[8];
  const float* Wo    = (const float*)d_in[9];
  const float* bo    = (const float*)d_in[10];
  const float* ln1_g = (const float*)d_in[11];
  const float* ln1_b = (const float*)d_in[12];
  const float* W1    = (const float*)d_in[13];
  const float* b1    = (const float*)d_in[14];
  const float* W2    = (const float*)d_in[15];
  const float* b2    = (const float*)d_in[16];
  const float* ln2_g = (const float*)d_in[17];
  const float* ln2_b = (const float*)d_in[18];
  const float* lnf_g = (const float*)d_in[19];
  const float* lnf_b = (const float*)d_in[20];
  const float* W_out = (const float*)d_in[21];
  const float* b_out = (const float*)d_in[22];
  const int*   sidx  = (const int*)d_in[23];
  float* out = (float*)d_out;

  float* ws = (float*)d_ws;
  float*          X     = ws;
  unsigned short* Xbf   = (unsigned short*)(ws + 4194304);
  float*          Qb    = ws + 6291456;
  float*          T     = Qb;
  float*          Kb    = ws + 10485760;
  float*          Vb    = ws + 14680064;
  float*          S     = ws + 18874368;
  unsigned short* HBbf  = (unsigned short*)(ws + 18874368);
  unsigned short* WT    = (unsigned short*)(ws + 27262976);
  float*          Mb    = ws + 31981568;
  float*          UPD   = ws + 32047104;
  float*          VM    = ws + 32129024;
  int*            TOP   = (int*)(ws + 32131072);
  float*          BASEA = ws + 32132352;
  int*            INV   = (int*)(ws + 32134400);     // 65536 i, packed [b][l][8]
  unsigned short* WTqkvo = WT;
  unsigned short* WT1    = WT + 3145728;
  unsigned short* WT2    = WT + 6291456;
  (void)in_sizes; (void)n_in; (void)out_size; (void)ws_size;

  wtrans<<<dim3(16, 16, 9), 256, 0, stream>>>(Wq, Wk, Wv, WTqkvo, 512, 512, 262144);
  wtrans<<<dim3(64, 16, 3), 256, 0, stream>>>(W1, nullptr, nullptr, WT1, 512, 2048, 1048576);
  wtrans<<<dim3(16, 64, 3), 256, 0, stream>>>(W2, nullptr, nullptr, WT2, 2048, 512, 1048576);

  pre_kernel<<<16384, 256, 0, stream>>>(DNAs, W_pre, b_pre, X, Xbf);

  for (int i = 0; i < E_; ++i) {
    const int bOff = i * DM_;
    const float* Wo_i = Wo + (size_t)i * 262144;
    mgemm<1, true, false><<<dim3(256, 1, 3), 256, 0, stream>>>(
        Xbf, WTqkvo + (size_t)i * 262144, bq + bOff, bk + bOff, bv + bOff,
        Qb, nullptr, R_, DM_, DM_);

    qk_m_kernel<<<2048, 256, 0, stream>>>(Qb, Kb, sidx, Mb);
    topk_kernel<<<32, 256, 0, stream>>>(Mb, TOP, INV);
    vmean_kernel<<<32, 256, 0, stream>>>(Vb, VM);
    attn_score<<<dim3(16, 32), 256, 0, stream>>>(Qb, Kb, TOP, S);
    attn_pv<<<160, 512, 0, stream>>>(S, Vb, UPD);
    base_kernel<<<4, 512, 0, stream>>>(VM, Wo_i, bo + bOff, BASEA);
    lnattn_kernel<<<8192, 256, 0, stream>>>(X, BASEA, INV, UPD, VM, Wo_i,
                                            ln1_g + bOff, ln1_b + bOff, X, Xbf);

    mgemm<2, false, false><<<1024, 256, 0, stream>>>(
        Xbf, WT1 + (size_t)i * 1048576, b1 + i * DFF_, nullptr, nullptr,
        nullptr, HBbf, R_, DFF_, DM_);
    mgemm<0, false, true><<<256, 256, 0, stream>>>(
        HBbf, WT2 + (size_t)i * 1048576, b2 + bOff, nullptr, nullptr,
        T, nullptr, R_, DM_, DFF_);
    ln_kernel<true, true><<<8192, 256, 0, stream>>>(X, T, ln2_g + bOff, ln2_b + bOff, X, Xbf);
  }

  ln_kernel<false, false><<<8192, 256, 0, stream>>>(X, nullptr, lnf_g, lnf_b, X, nullptr);
  out_kernel<<<2048, 256, 0, stream>>>(X, W_out, b_out, out);
}

// Round 13
// 783.715 us; speedup vs baseline: 1.1075x; 1.1075x over previous
//
#include <hip/hip_runtime.h>
#include <math.h>

#define B_   4
#define L_   2048
#define DM_  512
#define H_   8
#define DK_  64
#define DFF_ 2048
#define E_   3
#define U_   40
#define R_   8192
#define SCALE_ 0.125f
#define EPS_ 1e-5f

typedef __bf16 bf16x8 __attribute__((ext_vector_type(8)));
typedef float f32x4 __attribute__((ext_vector_type(4)));

__device__ inline unsigned short f2bf(float x) {
  unsigned int u = __float_as_uint(x);
  unsigned int r = (u + 0x7fffu + ((u >> 16) & 1u)) >> 16;
  return (unsigned short)r;
}

// ---------------------------------------------------------------------------
// Weight transpose fp32 [R][C] -> bf16 [C][R].
// ---------------------------------------------------------------------------
__global__ __launch_bounds__(256) void wtrans(
    const float* __restrict__ s0, const float* __restrict__ s1,
    const float* __restrict__ s2, const float* __restrict__ s3,
    unsigned short* __restrict__ dst, int R, int C, int permat) {
  __shared__ float tile[32][33];
  int z = blockIdx.z;
  int which = z / 3, e = z % 3;
  const float* src = (which == 0 ? s0 : which == 1 ? s1 : which == 2 ? s2 : s3);
  src += (size_t)e * permat;
  unsigned short* d = dst + (size_t)z * permat;
  int c0 = blockIdx.x << 5, r0 = blockIdx.y << 5;
  int tx = threadIdx.x & 31, ty = threadIdx.x >> 5;
  for (int rr = ty; rr < 32; rr += 8)
    tile[rr][tx] = src[(size_t)(r0 + rr) * C + c0 + tx];
  __syncthreads();
  for (int cc = ty; cc < 32; cc += 8)
    d[(size_t)(c0 + cc) * R + r0 + tx] = f2bf(tile[tx][cc]);
}

// ---------------------------------------------------------------------------
// x = DNAs @ W_pre + b_pre ; writes fp32 X and bf16 Xbf
// ---------------------------------------------------------------------------
__global__ __launch_bounds__(256) void pre_kernel(
    const float* __restrict__ DNAs, const float* __restrict__ Wp,
    const float* __restrict__ bp, float* __restrict__ X,
    unsigned short* __restrict__ Xbf) {
  int t = blockIdx.x * 256 + threadIdx.x;
  int r = t >> 9, d = t & 511;
  float4 dna = *(const float4*)(DNAs + r * 4);
  float v = dna.x * Wp[d] + dna.y * Wp[512 + d] + dna.z * Wp[1024 + d] +
            dna.w * Wp[1536 + d] + bp[d];
  X[t] = v;
  Xbf[t] = f2bf(v);
}

// ---------------------------------------------------------------------------
// bf16 MFMA GEMM (m97 structure, 128x128 tile, BK=64, XOR-swizzled LDS).
// 1-D grid, XCD-affinity (m-tile = id&63 -> id%8 == m%8).
// DBUF=true for 1-block/CU dispatches (Wo, FFN2): 2-phase prefetch hides
// staging latency where no cross-block overlap exists.
// OUT: 0 fp32 [M,N]; 1 fp32 QKV remap; 2 bf16+ReLU.
// ---------------------------------------------------------------------------
template <int OUT, bool QKVZ, bool DBUF>
__global__ __launch_bounds__(256) void mgemm(
    const unsigned short* __restrict__ A, const unsigned short* __restrict__ BT,
    const float* __restrict__ bias0, const float* __restrict__ bias1,
    const float* __restrict__ bias2, float* __restrict__ Cf,
    unsigned short* __restrict__ Cb, int M, int N, int K) {
  __shared__ unsigned short As[(DBUF ? 2 : 1) * 128 * 64];
  __shared__ unsigned short Bs[(DBUF ? 2 : 1) * 128 * 64];
  const int t = threadIdx.x, l = t & 63, w = t >> 6;
  const int id = blockIdx.x;
  const int m0 = (id & 63) << 7, n0 = (id >> 6) << 7;
  const int wm = w >> 1, wn = w & 1;
  const float* bias = bias0;
  if (QKVZ) {
    int z = blockIdx.z;
    BT += (size_t)z * 3 * 262144;
    bias = (z == 0 ? bias0 : z == 1 ? bias1 : bias2);
    Cf += (size_t)z * 4194304;
  }
  f32x4 acc[4][4] = {};

  const int srow = l >> 3;
  const int gslot = (l & 7) ^ srow;

  auto stage = [&](int buf, int k0) {
#pragma unroll
    for (int j = 0; j < 4; ++j) {
      int c = (w << 2) + j;
      int row = (c << 3) + srow;
      const unsigned short* ga = A + (size_t)(m0 + row) * K + k0 + gslot * 8;
      const unsigned short* gb = BT + (size_t)(n0 + row) * K + k0 + gslot * 8;
      __builtin_amdgcn_global_load_lds(
          (const __attribute__((address_space(1))) void*)ga,
          (__attribute__((address_space(3))) void*)(As + buf * 8192 + (c << 9)), 16, 0, 0);
      __builtin_amdgcn_global_load_lds(
          (const __attribute__((address_space(1))) void*)gb,
          (__attribute__((address_space(3))) void*)(Bs + buf * 8192 + (c << 9)), 16, 0, 0);
    }
  };
  auto compute = [&](int buf) {
#pragma unroll
    for (int ks = 0; ks < 2; ++ks) {
      bf16x8 af[4], bg[4];
      int slot = (ks << 2) + (l >> 4);
#pragma unroll
      for (int i = 0; i < 4; ++i) {
        int ar = (wm << 6) + (i << 4) + (l & 15);
        af[i] = *(const bf16x8*)(As + buf * 8192 + ar * 64 + (slot ^ (ar & 7)) * 8);
        int br = (wn << 6) + (i << 4) + (l & 15);
        bg[i] = *(const bf16x8*)(Bs + buf * 8192 + br * 64 + (slot ^ (br & 7)) * 8);
      }
#pragma unroll
      for (int i = 0; i < 4; ++i)
#pragma unroll
        for (int j = 0; j < 4; ++j)
          acc[i][j] = __builtin_amdgcn_mfma_f32_16x16x32_bf16(af[i], bg[j],
                                                              acc[i][j], 0, 0, 0);
    }
  };

  if (DBUF) {
    int nk = K >> 6, cur = 0;
    stage(0, 0);
    __syncthreads();
    for (int s = 0; s < nk; ++s) {
      if (s + 1 < nk) stage(cur ^ 1, (s + 1) << 6);
      compute(cur);
      __syncthreads();
      cur ^= 1;
    }
  } else {
    for (int k0 = 0; k0 < K; k0 += 64) {
      stage(0, k0);
      __syncthreads();
      compute(0);
      __syncthreads();
    }
  }

#pragma unroll
  for (int i = 0; i < 4; ++i) {
    int rbase = m0 + (wm << 6) + (i << 4) + ((l >> 4) << 2);
#pragma unroll
    for (int j = 0; j < 4; ++j) {
      int col = n0 + (wn << 6) + (j << 4) + (l & 15);
      float bv = bias[col];
#pragma unroll
      for (int r = 0; r < 4; ++r) {
        int row = rbase + r;
        float v = acc[i][j][r] + bv;
        if (OUT == 2) {
          v = fmaxf(v, 0.f);
          Cb[(size_t)row * N + col] = f2bf(v);
        } else if (OUT == 1) {
          int b = row >> 11, ll = row & 2047, h = col >> 6, d = col & 63;
          Cf[((size_t)(((b << 3) + h) << 11) + ll) * 64 + d] = v;
        } else {
          Cf[(size_t)row * N + col] = v;
        }
      }
    }
  }
}

// ---------------------------------------------------------------------------
// Sampled-score M: 8 queries/wave, 8 lanes/query, line-contiguous loads.
// XCD-affinity (bh = blockIdx&31) keeps each head's K panel L2-resident.
// ---------------------------------------------------------------------------
__global__ __launch_bounds__(256) void qk_m_kernel(
    const float* __restrict__ Q, const float* __restrict__ K,
    const int* __restrict__ sidx, float* __restrict__ Mout) {
  int t = threadIdx.x;
  int wave = t >> 6, lane = t & 63;
  int grp = lane >> 3, sub = lane & 7;
  int bh = blockIdx.x & 31;
  int j = blockIdx.x >> 5;
  int item = (bh << 11) + (j << 5) + wave * 8 + grp;
  int l = item & 2047;
  const float* Qr = Q + (size_t)item * 64;
  float4 q0 = *(const float4*)(Qr + sub * 4);
  float4 q1 = *(const float4*)(Qr + 32 + sub * 4);
  const float* Kb = K + (((size_t)bh << 11) << 6);
  const int* sp = sidx + l * U_;
  float mx = -INFINITY, sm = 0.f;
#pragma unroll 8
  for (int u = 0; u < U_; ++u) {
    int kidx = sp[u];
    const float* kr = Kb + ((size_t)kidx << 6);
    float4 k0 = *(const float4*)(kr + sub * 4);
    float4 k1 = *(const float4*)(kr + 32 + sub * 4);
    float p = q0.x * k0.x + q0.y * k0.y + q0.z * k0.z + q0.w * k0.w;
    p = fmaf(q1.x, k1.x, p); p = fmaf(q1.y, k1.y, p);
    p = fmaf(q1.z, k1.z, p); p = fmaf(q1.w, k1.w, p);
    p += __shfl_xor(p, 1);
    p += __shfl_xor(p, 2);
    p += __shfl_xor(p, 4);
    mx = fmaxf(mx, p);
    sm += p;
  }
  if (sub == 0) Mout[item] = mx - sm * (1.0f / U_);
}

// ---------------------------------------------------------------------------
// Exact top-40 via 4-pass radix select — fully parallel (no serial tails).
// ---------------------------------------------------------------------------
__global__ __launch_bounds__(256) void topk_kernel(
    const float* __restrict__ Mb, int* __restrict__ TOP) {
  __shared__ unsigned vals[2048];
  __shared__ int hist[256];
  __shared__ int suf[256];
  __shared__ unsigned s_prefix;
  __shared__ int s_want, s_cnt, s_run;
  __shared__ int wcnt[4];
  int bh = blockIdx.x, t = threadIdx.x;
  int lane = t & 63, w = t >> 6;
  for (int i = t; i < 2048; i += 256) {
    unsigned u = __float_as_uint(Mb[bh * 2048 + i]);
    vals[i] = (u & 0x80000000u) ? ~u : (u | 0x80000000u);
  }
  if (t == 0) { s_prefix = 0; s_want = U_; s_cnt = 0; s_run = 0; }
  __syncthreads();
#pragma unroll
  for (int shift = 24; shift >= 0; shift -= 8) {
    unsigned pref = s_prefix;
    int want = s_want;
    unsigned hmask = (shift == 24) ? 0u : (0xFFFFFFFFu << (shift + 8));
    hist[t] = 0;
    __syncthreads();
    for (int i = t; i < 2048; i += 256) {
      unsigned v = vals[i];
      if ((v & hmask) == pref) atomicAdd(&hist[(v >> shift) & 255], 1);
    }
    __syncthreads();
    suf[t] = hist[t];
    __syncthreads();
    for (int off = 1; off < 256; off <<= 1) {
      int add = (t + off < 256) ? suf[t + off] : 0;
      __syncthreads();
      suf[t] += add;
      __syncthreads();
    }
    int cgt = (t == 255) ? 0 : suf[t + 1];
    if (suf[t] >= want && cgt < want) {
      s_prefix = pref | ((unsigned)t << shift);
      s_want = want - cgt;
    }
    __syncthreads();
  }
  unsigned T = s_prefix;
  int want_eq = s_want;
  int base = U_ - want_eq;
  for (int i = t; i < 2048; i += 256) {
    if (vals[i] > T) {
      int slot = atomicAdd(&s_cnt, 1);
      TOP[bh * U_ + slot] = i;
    }
  }
  for (int c = 0; c < 8; ++c) {
    int i = (c << 8) + t;
    bool eq = (vals[i] == T);
    unsigned long long m = __ballot(eq);
    if (lane == 0) wcnt[w] = __popcll(m);
    __syncthreads();
    int woff = 0;
    for (int ww = 0; ww < w; ++ww) woff += wcnt[ww];
    if (eq) {
      int rank = s_run + woff + __popcll(m & ((1ull << lane) - 1ull));
      if (rank < want_eq) TOP[bh * U_ + base + rank] = i;
    }
    __syncthreads();
    if (t == 0) s_run += wcnt[0] + wcnt[1] + wcnt[2] + wcnt[3];
    __syncthreads();
  }
}

// ---------------------------------------------------------------------------
// vmean[bh,d] = mean over L of V[bh,l,d]; also bf16 copy for ctxfill.
// ---------------------------------------------------------------------------
__global__ __launch_bounds__(256) void vmean_kernel(
    const float* __restrict__ V, float* __restrict__ VM,
    unsigned short* __restrict__ VMbf) {
  __shared__ float p[4][64];
  int bh = blockIdx.x;
  int d = threadIdx.x & 63, c = threadIdx.x >> 6;
  const float* Vb = V + (((size_t)bh << 11) + c * 512) * 64;
  float s = 0.f;
  for (int l = 0; l < 512; ++l) s += Vb[l * 64 + d];
  p[c][d] = s;
  __syncthreads();
  if (threadIdx.x < 64) {
    float m = (p[0][d] + p[1][d] + p[2][d] + p[3][d]) * (1.0f / 2048.0f);
    VM[bh * 64 + d] = m;
    VMbf[bh * 64 + d] = f2bf(m);
  }
}

// ---------------------------------------------------------------------------
// S[bh,u,k] = scale * dot(Q[top[bh,u]], K[bh,k]).
// ---------------------------------------------------------------------------
__global__ __launch_bounds__(256) void attn_score(
    const float* __restrict__ Q, const float* __restrict__ K,
    const int* __restrict__ TOP, float* __restrict__ S) {
  __shared__ float Ks[128 * 65];
  __shared__ float Qs[40 * 64];
  int bh = blockIdx.y, k0 = blockIdx.x << 7;
  int t = threadIdx.x;
  for (int i = t; i < 2560; i += 256) {
    int u = i >> 6, d = i & 63;
    int row = TOP[bh * U_ + u];
    Qs[i] = Q[(((size_t)bh << 11) + row) * 64 + d];
  }
  for (int i = t; i < 8192; i += 256) {
    int k = i >> 6, d = i & 63;
    Ks[k * 65 + d] = K[(((size_t)bh << 11) + k0 + k) * 64 + d];
  }
  __syncthreads();
  int kk = t & 127, ug = (t >> 7) * 20;
  const float* kp = Ks + kk * 65;
  for (int u = ug; u < ug + 20; ++u) {
    const float* qp = Qs + u * 64;
    float s = 0.f;
#pragma unroll 8
    for (int d = 0; d < 64; ++d) s = fmaf(qp[d], kp[d], s);
    S[((size_t)bh * U_ + u) * 2048 + k0 + kk] = s * SCALE_;
  }
}

// ---------------------------------------------------------------------------
// softmax + P@V: 512 threads, 8 waves, one row per wave. Linear grid 160,
// bh = id&31 XCD-affinity (V L2-resident). Fused bf16 scatter into CTX.
// ---------------------------------------------------------------------------
__global__ __launch_bounds__(512) void attn_pv(
    const float* __restrict__ S, const float* __restrict__ V,
    const int* __restrict__ TOP, unsigned short* __restrict__ CTX) {
  __shared__ float Vs[128][64];
  __shared__ float ps[8][128];
  __shared__ float mred[8], ired[8];
  int id = blockIdx.x;
  int bh = id & 31, ug = id >> 5;
  int t = threadIdx.x, lane = t & 63, w = t >> 6;
  int rowbase = bh * U_ + ug * 8;
  int row = rowbase + w;

  const float* Sr = S + (size_t)row * 2048;
  float mx = -INFINITY;
  for (int j = 0; j < 32; ++j) mx = fmaxf(mx, Sr[j * 64 + lane]);
#pragma unroll
  for (int s = 32; s; s >>= 1) mx = fmaxf(mx, __shfl_xor(mx, s));
  float sm = 0.f;
  for (int j = 0; j < 32; ++j) sm += __expf(Sr[j * 64 + lane] - mx);
#pragma unroll
  for (int s = 32; s; s >>= 1) sm += __shfl_xor(sm, s);
  if (lane == 0) { mred[w] = mx; ired[w] = 1.0f / sm; }
  __syncthreads();

  const float* Vb = V + (((size_t)bh << 11) << 6);
  float acc = 0.f;
  for (int c = 0; c < 16; ++c) {
    int k0 = c << 7;
#pragma unroll
    for (int i = 0; i < 4; ++i) {
      int ve = t + i * 512;
      int k = ve >> 4, dq = ve & 15;
      *(float4*)&Vs[k][dq << 2] = *(const float4*)(Vb + (size_t)(k0 + k) * 64 + (dq << 2));
    }
#pragma unroll
    for (int i = 0; i < 2; ++i) {
      int e = t + i * 512;
      int r = e >> 7, kk = e & 127;
      ps[r][kk] = __expf(S[(size_t)(rowbase + r) * 2048 + k0 + kk] - mred[r]);
    }
    __syncthreads();
    const float* p = ps[w];
#pragma unroll 4
    for (int kk = 0; kk < 128; kk += 4) {
      float4 p4 = *(const float4*)(p + kk);
      acc = fmaf(p4.x, Vs[kk + 0][lane], acc);
      acc = fmaf(p4.y, Vs[kk + 1][lane], acc);
      acc = fmaf(p4.z, Vs[kk + 2][lane], acc);
      acc = fmaf(p4.w, Vs[kk + 3][lane], acc);
    }
    __syncthreads();
  }
  int b = bh >> 3, h = bh & 7;
  int orow = TOP[row];
  CTX[((size_t)((b << 11) + orow) << 9) + (h << 6) + lane] = f2bf(acc * ired[w]);
}

// ---------------------------------------------------------------------------
// ctx fill (vectorized: 8 bf16 per thread; 2048 blocks x 256 x 8 = 4194304)
// ---------------------------------------------------------------------------
__global__ __launch_bounds__(256) void ctxfill_kernel(
    const unsigned short* __restrict__ VMbf, unsigned short* __restrict__ CTX) {
  int t8 = (blockIdx.x * 256 + threadIdx.x) << 3;
  int c0 = t8 & 511;
  int b = t8 >> 20;
  *(uint4*)(CTX + t8) = *(const uint4*)(VMbf + (b << 9) + c0);
}

// ---------------------------------------------------------------------------
// LayerNorm(512) with optional residual; float2-vectorized.
// ---------------------------------------------------------------------------
template <bool ADD, bool WB>
__global__ __launch_bounds__(256) void ln_kernel(
    const float* __restrict__ Xin, const float* __restrict__ Tin,
    const float* __restrict__ g, const float* __restrict__ bta,
    float* __restrict__ Xout, unsigned short* __restrict__ Xbf) {
  __shared__ float red[8];
  int r = blockIdx.x, t = threadIdx.x;
  int i0 = (r << 9) + (t << 1);
  float2 v = *(const float2*)(Xin + i0);
  if constexpr (ADD) {
    float2 tv = *(const float2*)(Tin + i0);
    v.x += tv.x; v.y += tv.y;
  }
  float sm = v.x + v.y;
#pragma unroll
  for (int s = 32; s; s >>= 1) sm += __shfl_xor(sm, s);
  int lane = t & 63, w = t >> 6;
  if (lane == 0) red[w] = sm;
  __syncthreads();
  float mean = (red[0] + red[1] + red[2] + red[3]) * (1.0f / 512.0f);
  float d0 = v.x - mean, d1 = v.y - mean;
  float sq = d0 * d0 + d1 * d1;
#pragma unroll
  for (int s = 32; s; s >>= 1) sq += __shfl_xor(sq, s);
  if (lane == 0) red[4 + w] = sq;
  __syncthreads();
  float var = (red[4] + red[5] + red[6] + red[7]) * (1.0f / 512.0f);
  float rstd = rsqrtf(var + EPS_);
  float2 gv = *(const float2*)(g + (t << 1));
  float2 bv = *(const float2*)(bta + (t << 1));
  float o0 = d0 * rstd * gv.x + bv.x;
  float o1 = d1 * rstd * gv.y + bv.y;
  *(float2*)(Xout + i0) = make_float2(o0, o1);
  if constexpr (WB) {
    *(unsigned*)(Xbf + i0) = (unsigned)f2bf(o0) | ((unsigned)f2bf(o1) << 16);
  }
}

// ---------------------------------------------------------------------------
// out = softmax(X @ W_out + b_out); one wave per row.
// ---------------------------------------------------------------------------
__global__ __launch_bounds__(256) void out_kernel(
    const float* __restrict__ X, const float* __restrict__ Wout,
    const float* __restrict__ bout, float* __restrict__ out) {
  int w = threadIdx.x >> 6, lane = threadIdx.x & 63;
  int r = blockIdx.x * 4 + w;
  float p0 = 0.f, p1 = 0.f, p2 = 0.f;
  for (int d = lane; d < 512; d += 64) {
    float x = X[(r << 9) + d];
    p0 += x * Wout[d * 3 + 0];
    p1 += x * Wout[d * 3 + 1];
    p2 += x * Wout[d * 3 + 2];
  }
#pragma unroll
  for (int s = 32; s; s >>= 1) {
    p0 += __shfl_xor(p0, s);
    p1 += __shfl_xor(p1, s);
    p2 += __shfl_xor(p2, s);
  }
  if (lane == 0) {
    p0 += bout[0]; p1 += bout[1]; p2 += bout[2];
    float m = fmaxf(p0, fmaxf(p1, p2));
    float e0 = __expf(p0 - m), e1 = __expf(p1 - m), e2 = __expf(p2 - m);
    float z = 1.0f / (e0 + e1 + e2);
    out[r * 3 + 0] = e0 * z;
    out[r * 3 + 1] = e1 * z;
    out[r * 3 + 2] = e2 * z;
  }
}

// ---------------------------------------------------------------------------
extern "C" void kernel_launch(void* const* d_in, const int* in_sizes, int n_in,
                              void* d_out, int out_size, void* d_ws, size_t ws_size,
                              hipStream_t stream) {
  const float* DNAs  = (const float*)d_in[0];
  const float* W_pre = (const float*)d_in[1];
  const float* b_pre = (const float*)d_in[2];
  const float* Wq    = (const float*)d_in[3];
  const float* bq    = (const float*)d_in[4];
  const float* Wk    = (const float*)d_in[5];
  const float* bk    = (const float*)d_in[6];
  const float* Wv    = (const float*)d_in[7];
  const float* bv    = (const float*)d_in[8];
  const float* Wo    = (const float*)d_in[9];
  const float* bo    = (const float*)d_in[10];
  const float* ln1_g = (const float*)d_in[11];
  const float* ln1_b = (const float*)d_in[12];
  const float* W1    = (const float*)d_in[13];
  const float* b1    = (const float*)d_in[14];
  const float* W2    = (const float*)d_in[15];
  const float* b2    = (const float*)d_in[16];
  const float* ln2_g = (const float*)d_in[17];
  const float* ln2_b = (const float*)d_in[18];
  const float* lnf_g = (const float*)d_in[19];
  const float* lnf_b = (const float*)d_in[20];
  const float* W_out = (const float*)d_in[21];
  const float* b_out = (const float*)d_in[22];
  const int*   sidx  = (const int*)d_in[23];
  float* out = (float*)d_out;

  float* ws = (float*)d_ws;
  float*          X     = ws;
  unsigned short* Xbf   = (unsigned short*)(ws + 4194304);
  float*          Qb    = ws + 6291456;
  float*          T     = Qb;
  float*          Kb    = ws + 10485760;
  float*          Vb    = ws + 14680064;
  float*          S     = ws + 18874368;
  unsigned short* CTXbf = (unsigned short*)(ws + 18874368 + 3276800);
  unsigned short* HBbf  = (unsigned short*)(ws + 18874368);
  unsigned short* WT    = (unsigned short*)(ws + 27262976);
  float*          Mb    = ws + 31981568;
  float*          VM    = ws + 32129024;
  int*            TOP   = (int*)(ws + 32131072);
  unsigned short* VMbf  = (unsigned short*)(ws + 32132352);
  unsigned short* WTqkvo = WT;                 // 12 x 262144 (Wq,Wk,Wv,Wo)
  unsigned short* WT1    = WT + 3145728;
  unsigned short* WT2    = WT + 6291456;
  (void)in_sizes; (void)n_in; (void)out_size; (void)ws_size;

  wtrans<<<dim3(16, 16, 12), 256, 0, stream>>>(Wq, Wk, Wv, Wo, WTqkvo, 512, 512, 262144);
  wtrans<<<dim3(64, 16, 3), 256, 0, stream>>>(W1, nullptr, nullptr, nullptr, WT1, 512, 2048, 1048576);
  wtrans<<<dim3(16, 64, 3), 256, 0, stream>>>(W2, nullptr, nullptr, nullptr, WT2, 2048, 512, 1048576);

  pre_kernel<<<16384, 256, 0, stream>>>(DNAs, W_pre, b_pre, X, Xbf);

  for (int i = 0; i < E_; ++i) {
    const int bOff = i * DM_;
    mgemm<1, true, false><<<dim3(256, 1, 3), 256, 0, stream>>>(
        Xbf, WTqkvo + (size_t)i * 262144, bq + bOff, bk + bOff, bv + bOff,
        Qb, nullptr, R_, DM_, DM_);

    qk_m_kernel<<<2048, 256, 0, stream>>>(Qb, Kb, sidx, Mb);
    topk_kernel<<<32, 256, 0, stream>>>(Mb, TOP);
    vmean_kernel<<<32, 256, 0, stream>>>(Vb, VM, VMbf);
    attn_score<<<dim3(16, 32), 256, 0, stream>>>(Qb, Kb, TOP, S);
    ctxfill_kernel<<<2048, 256, 0, stream>>>(VMbf, CTXbf);
    attn_pv<<<160, 512, 0, stream>>>(S, Vb, TOP, CTXbf);

    mgemm<0, false, true><<<256, 256, 0, stream>>>(
        CTXbf, WTqkvo + (size_t)(9 + i) * 262144, bo + bOff, nullptr, nullptr,
        T, nullptr, R_, DM_, DM_);
    ln_kernel<true, true><<<8192, 256, 0, stream>>>(X, T, ln1_g + bOff, ln1_b + bOff, X, Xbf);

    mgemm<2, false, false><<<1024, 256, 0, stream>>>(
        Xbf, WT1 + (size_t)i * 1048576, b1 + i * DFF_, nullptr, nullptr,
        nullptr, HBbf, R_, DFF_, DM_);
    mgemm<0, false, true><<<256, 256, 0, stream>>>(
        HBbf, WT2 + (size_t)i * 1048576, b2 + bOff, nullptr, nullptr,
        T, nullptr, R_, DM_, DFF_);
    ln_kernel<true, true><<<8192, 256, 0, stream>>>(X, T, ln2_g + bOff, ln2_b + bOff, X, Xbf);
  }

  ln_kernel<false, false><<<8192, 256, 0, stream>>>(X, nullptr, lnf_g, lnf_b, X, nullptr);
  out_kernel<<<2048, 256, 0, stream>>>(X, W_out, b_out, out);
}

// Round 14
// 760.074 us; speedup vs baseline: 1.1420x; 1.0311x over previous
//
#include <hip/hip_runtime.h>
#include <math.h>

#define B_   4
#define L_   2048
#define DM_  512
#define H_   8
#define DK_  64
#define DFF_ 2048
#define E_   3
#define U_   40
#define R_   8192
#define SCALE_ 0.125f
#define EPS_ 1e-5f

typedef __bf16 bf16x8 __attribute__((ext_vector_type(8)));
typedef float f32x4 __attribute__((ext_vector_type(4)));

__device__ inline unsigned short f2bf(float x) {
  unsigned int u = __float_as_uint(x);
  unsigned int r = (u + 0x7fffu + ((u >> 16) & 1u)) >> 16;
  return (unsigned short)r;
}

// ---------------------------------------------------------------------------
// Weight transpose fp32 [R][C] -> bf16 [C][R].
// ---------------------------------------------------------------------------
__global__ __launch_bounds__(256) void wtrans(
    const float* __restrict__ s0, const float* __restrict__ s1,
    const float* __restrict__ s2, const float* __restrict__ s3,
    unsigned short* __restrict__ dst, int R, int C, int permat) {
  __shared__ float tile[32][33];
  int z = blockIdx.z;
  int which = z / 3, e = z % 3;
  const float* src = (which == 0 ? s0 : which == 1 ? s1 : which == 2 ? s2 : s3);
  src += (size_t)e * permat;
  unsigned short* d = dst + (size_t)z * permat;
  int c0 = blockIdx.x << 5, r0 = blockIdx.y << 5;
  int tx = threadIdx.x & 31, ty = threadIdx.x >> 5;
  for (int rr = ty; rr < 32; rr += 8)
    tile[rr][tx] = src[(size_t)(r0 + rr) * C + c0 + tx];
  __syncthreads();
  for (int cc = ty; cc < 32; cc += 8)
    d[(size_t)(c0 + cc) * R + r0 + tx] = f2bf(tile[tx][cc]);
}

// ---------------------------------------------------------------------------
// x = DNAs @ W_pre + b_pre ; writes fp32 X and bf16 Xbf
// ---------------------------------------------------------------------------
__global__ __launch_bounds__(256) void pre_kernel(
    const float* __restrict__ DNAs, const float* __restrict__ Wp,
    const float* __restrict__ bp, float* __restrict__ X,
    unsigned short* __restrict__ Xbf) {
  int t = blockIdx.x * 256 + threadIdx.x;
  int r = t >> 9, d = t & 511;
  float4 dna = *(const float4*)(DNAs + r * 4);
  float v = dna.x * Wp[d] + dna.y * Wp[512 + d] + dna.z * Wp[1024 + d] +
            dna.w * Wp[1536 + d] + bp[d];
  X[t] = v;
  Xbf[t] = f2bf(v);
}

// ---------------------------------------------------------------------------
// bf16 MFMA GEMM (m97 structure, 128x128 tile, BK=64, XOR-swizzled LDS).
// 1-D grid, XCD-affinity (m-tile = id&63). DBUF for 1-block/CU dispatches.
// OUT: 0 fp32 [M,N]; 1 fp32 QKV remap; 2 bf16+ReLU.
// ---------------------------------------------------------------------------
template <int OUT, bool QKVZ, bool DBUF>
__global__ __launch_bounds__(256) void mgemm(
    const unsigned short* __restrict__ A, const unsigned short* __restrict__ BT,
    const float* __restrict__ bias0, const float* __restrict__ bias1,
    const float* __restrict__ bias2, float* __restrict__ Cf,
    unsigned short* __restrict__ Cb, int M, int N, int K) {
  __shared__ unsigned short As[(DBUF ? 2 : 1) * 128 * 64];
  __shared__ unsigned short Bs[(DBUF ? 2 : 1) * 128 * 64];
  const int t = threadIdx.x, l = t & 63, w = t >> 6;
  const int id = blockIdx.x;
  const int m0 = (id & 63) << 7, n0 = (id >> 6) << 7;
  const int wm = w >> 1, wn = w & 1;
  const float* bias = bias0;
  if (QKVZ) {
    int z = blockIdx.z;
    BT += (size_t)z * 3 * 262144;
    bias = (z == 0 ? bias0 : z == 1 ? bias1 : bias2);
    Cf += (size_t)z * 4194304;
  }
  f32x4 acc[4][4] = {};

  const int srow = l >> 3;
  const int gslot = (l & 7) ^ srow;

  auto stage = [&](int buf, int k0) {
#pragma unroll
    for (int j = 0; j < 4; ++j) {
      int c = (w << 2) + j;
      int row = (c << 3) + srow;
      const unsigned short* ga = A + (size_t)(m0 + row) * K + k0 + gslot * 8;
      const unsigned short* gb = BT + (size_t)(n0 + row) * K + k0 + gslot * 8;
      __builtin_amdgcn_global_load_lds(
          (const __attribute__((address_space(1))) void*)ga,
          (__attribute__((address_space(3))) void*)(As + buf * 8192 + (c << 9)), 16, 0, 0);
      __builtin_amdgcn_global_load_lds(
          (const __attribute__((address_space(1))) void*)gb,
          (__attribute__((address_space(3))) void*)(Bs + buf * 8192 + (c << 9)), 16, 0, 0);
    }
  };
  auto compute = [&](int buf) {
#pragma unroll
    for (int ks = 0; ks < 2; ++ks) {
      bf16x8 af[4], bg[4];
      int slot = (ks << 2) + (l >> 4);
#pragma unroll
      for (int i = 0; i < 4; ++i) {
        int ar = (wm << 6) + (i << 4) + (l & 15);
        af[i] = *(const bf16x8*)(As + buf * 8192 + ar * 64 + (slot ^ (ar & 7)) * 8);
        int br = (wn << 6) + (i << 4) + (l & 15);
        bg[i] = *(const bf16x8*)(Bs + buf * 8192 + br * 64 + (slot ^ (br & 7)) * 8);
      }
#pragma unroll
      for (int i = 0; i < 4; ++i)
#pragma unroll
        for (int j = 0; j < 4; ++j)
          acc[i][j] = __builtin_amdgcn_mfma_f32_16x16x32_bf16(af[i], bg[j],
                                                              acc[i][j], 0, 0, 0);
    }
  };

  if (DBUF) {
    int nk = K >> 6, cur = 0;
    stage(0, 0);
    __syncthreads();
    for (int s = 0; s < nk; ++s) {
      if (s + 1 < nk) stage(cur ^ 1, (s + 1) << 6);
      compute(cur);
      __syncthreads();
      cur ^= 1;
    }
  } else {
    for (int k0 = 0; k0 < K; k0 += 64) {
      stage(0, k0);
      __syncthreads();
      compute(0);
      __syncthreads();
    }
  }

#pragma unroll
  for (int i = 0; i < 4; ++i) {
    int rbase = m0 + (wm << 6) + (i << 4) + ((l >> 4) << 2);
#pragma unroll
    for (int j = 0; j < 4; ++j) {
      int col = n0 + (wn << 6) + (j << 4) + (l & 15);
      float bv = bias[col];
#pragma unroll
      for (int r = 0; r < 4; ++r) {
        int row = rbase + r;
        float v = acc[i][j][r] + bv;
        if (OUT == 2) {
          v = fmaxf(v, 0.f);
          Cb[(size_t)row * N + col] = f2bf(v);
        } else if (OUT == 1) {
          int b = row >> 11, ll = row & 2047, h = col >> 6, d = col & 63;
          Cf[((size_t)(((b << 3) + h) << 11) + ll) * 64 + d] = v;
        } else {
          Cf[(size_t)row * N + col] = v;
        }
      }
    }
  }
}

// ---------------------------------------------------------------------------
// Sampled-score M: 8 queries/wave, 8 lanes/query, line-contiguous loads.
// ---------------------------------------------------------------------------
__global__ __launch_bounds__(256) void qk_m_kernel(
    const float* __restrict__ Q, const float* __restrict__ K,
    const int* __restrict__ sidx, float* __restrict__ Mout) {
  int t = threadIdx.x;
  int wave = t >> 6, lane = t & 63;
  int grp = lane >> 3, sub = lane & 7;
  int bh = blockIdx.x & 31;
  int j = blockIdx.x >> 5;
  int item = (bh << 11) + (j << 5) + wave * 8 + grp;
  int l = item & 2047;
  const float* Qr = Q + (size_t)item * 64;
  float4 q0 = *(const float4*)(Qr + sub * 4);
  float4 q1 = *(const float4*)(Qr + 32 + sub * 4);
  const float* Kb = K + (((size_t)bh << 11) << 6);
  const int* sp = sidx + l * U_;
  float mx = -INFINITY, sm = 0.f;
#pragma unroll 8
  for (int u = 0; u < U_; ++u) {
    int kidx = sp[u];
    const float* kr = Kb + ((size_t)kidx << 6);
    float4 k0 = *(const float4*)(kr + sub * 4);
    float4 k1 = *(const float4*)(kr + 32 + sub * 4);
    float p = q0.x * k0.x + q0.y * k0.y + q0.z * k0.z + q0.w * k0.w;
    p = fmaf(q1.x, k1.x, p); p = fmaf(q1.y, k1.y, p);
    p = fmaf(q1.z, k1.z, p); p = fmaf(q1.w, k1.w, p);
    p += __shfl_xor(p, 1);
    p += __shfl_xor(p, 2);
    p += __shfl_xor(p, 4);
    mx = fmaxf(mx, p);
    sm += p;
  }
  if (sub == 0) Mout[item] = mx - sm * (1.0f / U_);
}

// ---------------------------------------------------------------------------
// Exact top-40 via 4-pass radix select — fully parallel.
// ---------------------------------------------------------------------------
__global__ __launch_bounds__(256) void topk_kernel(
    const float* __restrict__ Mb, int* __restrict__ TOP) {
  __shared__ unsigned vals[2048];
  __shared__ int hist[256];
  __shared__ int suf[256];
  __shared__ unsigned s_prefix;
  __shared__ int s_want, s_cnt, s_run;
  __shared__ int wcnt[4];
  int bh = blockIdx.x, t = threadIdx.x;
  int lane = t & 63, w = t >> 6;
  for (int i = t; i < 2048; i += 256) {
    unsigned u = __float_as_uint(Mb[bh * 2048 + i]);
    vals[i] = (u & 0x80000000u) ? ~u : (u | 0x80000000u);
  }
  if (t == 0) { s_prefix = 0; s_want = U_; s_cnt = 0; s_run = 0; }
  __syncthreads();
#pragma unroll
  for (int shift = 24; shift >= 0; shift -= 8) {
    unsigned pref = s_prefix;
    int want = s_want;
    unsigned hmask = (shift == 24) ? 0u : (0xFFFFFFFFu << (shift + 8));
    hist[t] = 0;
    __syncthreads();
    for (int i = t; i < 2048; i += 256) {
      unsigned v = vals[i];
      if ((v & hmask) == pref) atomicAdd(&hist[(v >> shift) & 255], 1);
    }
    __syncthreads();
    suf[t] = hist[t];
    __syncthreads();
    for (int off = 1; off < 256; off <<= 1) {
      int add = (t + off < 256) ? suf[t + off] : 0;
      __syncthreads();
      suf[t] += add;
      __syncthreads();
    }
    int cgt = (t == 255) ? 0 : suf[t + 1];
    if (suf[t] >= want && cgt < want) {
      s_prefix = pref | ((unsigned)t << shift);
      s_want = want - cgt;
    }
    __syncthreads();
  }
  unsigned T = s_prefix;
  int want_eq = s_want;
  int base = U_ - want_eq;
  for (int i = t; i < 2048; i += 256) {
    if (vals[i] > T) {
      int slot = atomicAdd(&s_cnt, 1);
      TOP[bh * U_ + slot] = i;
    }
  }
  for (int c = 0; c < 8; ++c) {
    int i = (c << 8) + t;
    bool eq = (vals[i] == T);
    unsigned long long m = __ballot(eq);
    if (lane == 0) wcnt[w] = __popcll(m);
    __syncthreads();
    int woff = 0;
    for (int ww = 0; ww < w; ++ww) woff += wcnt[ww];
    if (eq) {
      int rank = s_run + woff + __popcll(m & ((1ull << lane) - 1ull));
      if (rank < want_eq) TOP[bh * U_ + base + rank] = i;
    }
    __syncthreads();
    if (t == 0) s_run += wcnt[0] + wcnt[1] + wcnt[2] + wcnt[3];
    __syncthreads();
  }
}

// ---------------------------------------------------------------------------
// vmean[bh,d] = mean over L of V[bh,l,d]; also bf16 copy for ctxfill.
// ---------------------------------------------------------------------------
__global__ __launch_bounds__(256) void vmean_kernel(
    const float* __restrict__ V, float* __restrict__ VM,
    unsigned short* __restrict__ VMbf) {
  __shared__ float p[4][64];
  int bh = blockIdx.x;
  int d = threadIdx.x & 63, c = threadIdx.x >> 6;
  const float* Vb = V + (((size_t)bh << 11) + c * 512) * 64;
  float s = 0.f;
  for (int l = 0; l < 512; ++l) s += Vb[l * 64 + d];
  p[c][d] = s;
  __syncthreads();
  if (threadIdx.x < 64) {
    float m = (p[0][d] + p[1][d] + p[2][d] + p[3][d]) * (1.0f / 2048.0f);
    VM[bh * 64 + d] = m;
    VMbf[bh * 64 + d] = f2bf(m);
  }
}

// ---------------------------------------------------------------------------
// S[bh,u,k] = scale * dot(Q[top[bh,u]], K[bh,k]).
// ---------------------------------------------------------------------------
__global__ __launch_bounds__(256) void attn_score(
    const float* __restrict__ Q, const float* __restrict__ K,
    const int* __restrict__ TOP, float* __restrict__ S) {
  __shared__ float Ks[128 * 65];
  __shared__ float Qs[40 * 64];
  int bh = blockIdx.y, k0 = blockIdx.x << 7;
  int t = threadIdx.x;
  for (int i = t; i < 2560; i += 256) {
    int u = i >> 6, d = i & 63;
    int row = TOP[bh * U_ + u];
    Qs[i] = Q[(((size_t)bh << 11) + row) * 64 + d];
  }
  for (int i = t; i < 8192; i += 256) {
    int k = i >> 6, d = i & 63;
    Ks[k * 65 + d] = K[(((size_t)bh << 11) + k0 + k) * 64 + d];
  }
  __syncthreads();
  int kk = t & 127, ug = (t >> 7) * 20;
  const float* kp = Ks + kk * 65;
  for (int u = ug; u < ug + 20; ++u) {
    const float* qp = Qs + u * 64;
    float s = 0.f;
#pragma unroll 8
    for (int d = 0; d < 64; ++d) s = fmaf(qp[d], kp[d], s);
    S[((size_t)bh * U_ + u) * 2048 + k0 + kk] = s * SCALE_;
  }
}

// ---------------------------------------------------------------------------
// attn_pv_part: K-split PV. grid 640: bh = id&31 (XCD affinity),
// sub = id>>5 in [0,20): ug = sub>>2, kc = sub&3. Each block: phase-1
// (row max/expsum, redundant across kc) + 4 of 16 V-chunks -> unscaled
// partial PART[kc][row][64]. kc==0 also writes IRED[row].
// 4 independent accumulators break the serial fma chain.
// ---------------------------------------------------------------------------
__global__ __launch_bounds__(512) void attn_pv_part(
    const float* __restrict__ S, const float* __restrict__ V,
    float* __restrict__ PART, float* __restrict__ IRED) {
  __shared__ float Vs[128][64];
  __shared__ float ps[8][128];
  __shared__ float mred[8];
  int id = blockIdx.x;
  int bh = id & 31, sub = id >> 5;
  int ug = sub >> 2, kc = sub & 3;
  int t = threadIdx.x, lane = t & 63, w = t >> 6;
  int rowbase = bh * U_ + ug * 8;
  int row = rowbase + w;

  // phase 1: this wave's row max & expsum (redundant across the 4 kc blocks)
  const float* Sr = S + (size_t)row * 2048;
  float mx = -INFINITY;
  for (int j = 0; j < 32; ++j) mx = fmaxf(mx, Sr[j * 64 + lane]);
#pragma unroll
  for (int s = 32; s; s >>= 1) mx = fmaxf(mx, __shfl_xor(mx, s));
  float sm = 0.f;
  for (int j = 0; j < 32; ++j) sm += __expf(Sr[j * 64 + lane] - mx);
#pragma unroll
  for (int s = 32; s; s >>= 1) sm += __shfl_xor(sm, s);
  if (lane == 0) {
    mred[w] = mx;
    if (kc == 0) IRED[row] = 1.0f / sm;
  }
  __syncthreads();

  const float* Vb = V + (((size_t)bh << 11) << 6);
  float a0 = 0.f, a1 = 0.f, a2 = 0.f, a3 = 0.f;
  for (int c = kc * 4; c < kc * 4 + 4; ++c) {
    int k0 = c << 7;
#pragma unroll
    for (int i = 0; i < 4; ++i) {
      int ve = t + i * 512;
      int k = ve >> 4, dq = ve & 15;
      *(float4*)&Vs[k][dq << 2] = *(const float4*)(Vb + (size_t)(k0 + k) * 64 + (dq << 2));
    }
#pragma unroll
    for (int i = 0; i < 2; ++i) {
      int e = t + i * 512;
      int r = e >> 7, kk = e & 127;
      ps[r][kk] = __expf(S[(size_t)(rowbase + r) * 2048 + k0 + kk] - mred[r]);
    }
    __syncthreads();
    const float* p = ps[w];
#pragma unroll 4
    for (int kk = 0; kk < 128; kk += 4) {
      float4 p4 = *(const float4*)(p + kk);
      a0 = fmaf(p4.x, Vs[kk + 0][lane], a0);
      a1 = fmaf(p4.y, Vs[kk + 1][lane], a1);
      a2 = fmaf(p4.z, Vs[kk + 2][lane], a2);
      a3 = fmaf(p4.w, Vs[kk + 3][lane], a3);
    }
    __syncthreads();
  }
  PART[((size_t)kc * 1280 + row) * 64 + lane] = (a0 + a1) + (a2 + a3);
}

// ---------------------------------------------------------------------------
// pv_reduce: sum 4 partials (fixed order -> deterministic), scale by IRED,
// fused bf16 scatter into CTX. 320 blocks x 256 = 81920 threads.
// ---------------------------------------------------------------------------
__global__ __launch_bounds__(256) void pv_reduce(
    const float* __restrict__ PART, const float* __restrict__ IRED,
    const int* __restrict__ TOP, unsigned short* __restrict__ CTX) {
  int gid = blockIdx.x * 256 + threadIdx.x;
  int row = gid >> 6, lane = gid & 63;
  float v = (PART[(size_t)row * 64 + lane] + PART[(size_t)(1280 + row) * 64 + lane]) +
            (PART[(size_t)(2560 + row) * 64 + lane] + PART[(size_t)(3840 + row) * 64 + lane]);
  v *= IRED[row];
  int bh = row / U_;
  int b = bh >> 3, h = bh & 7;
  int orow = TOP[row];
  CTX[((size_t)((b << 11) + orow) << 9) + (h << 6) + lane] = f2bf(v);
}

// ---------------------------------------------------------------------------
// ctx fill (vectorized: 8 bf16 per thread)
// ---------------------------------------------------------------------------
__global__ __launch_bounds__(256) void ctxfill_kernel(
    const unsigned short* __restrict__ VMbf, unsigned short* __restrict__ CTX) {
  int t8 = (blockIdx.x * 256 + threadIdx.x) << 3;
  int c0 = t8 & 511;
  int b = t8 >> 20;
  *(uint4*)(CTX + t8) = *(const uint4*)(VMbf + (b << 9) + c0);
}

// ---------------------------------------------------------------------------
// LayerNorm(512) with optional residual; float2-vectorized.
// ---------------------------------------------------------------------------
template <bool ADD, bool WB>
__global__ __launch_bounds__(256) void ln_kernel(
    const float* __restrict__ Xin, const float* __restrict__ Tin,
    const float* __restrict__ g, const float* __restrict__ bta,
    float* __restrict__ Xout, unsigned short* __restrict__ Xbf) {
  __shared__ float red[8];
  int r = blockIdx.x, t = threadIdx.x;
  int i0 = (r << 9) + (t << 1);
  float2 v = *(const float2*)(Xin + i0);
  if constexpr (ADD) {
    float2 tv = *(const float2*)(Tin + i0);
    v.x += tv.x; v.y += tv.y;
  }
  float sm = v.x + v.y;
#pragma unroll
  for (int s = 32; s; s >>= 1) sm += __shfl_xor(sm, s);
  int lane = t & 63, w = t >> 6;
  if (lane == 0) red[w] = sm;
  __syncthreads();
  float mean = (red[0] + red[1] + red[2] + red[3]) * (1.0f / 512.0f);
  float d0 = v.x - mean, d1 = v.y - mean;
  float sq = d0 * d0 + d1 * d1;
#pragma unroll
  for (int s = 32; s; s >>= 1) sq += __shfl_xor(sq, s);
  if (lane == 0) red[4 + w] = sq;
  __syncthreads();
  float var = (red[4] + red[5] + red[6] + red[7]) * (1.0f / 512.0f);
  float rstd = rsqrtf(var + EPS_);
  float2 gv = *(const float2*)(g + (t << 1));
  float2 bv = *(const float2*)(bta + (t << 1));
  float o0 = d0 * rstd * gv.x + bv.x;
  float o1 = d1 * rstd * gv.y + bv.y;
  *(float2*)(Xout + i0) = make_float2(o0, o1);
  if constexpr (WB) {
    *(unsigned*)(Xbf + i0) = (unsigned)f2bf(o0) | ((unsigned)f2bf(o1) << 16);
  }
}

// ---------------------------------------------------------------------------
// out = softmax(X @ W_out + b_out); one wave per row.
// ---------------------------------------------------------------------------
__global__ __launch_bounds__(256) void out_kernel(
    const float* __restrict__ X, const float* __restrict__ Wout,
    const float* __restrict__ bout, float* __restrict__ out) {
  int w = threadIdx.x >> 6, lane = threadIdx.x & 63;
  int r = blockIdx.x * 4 + w;
  float p0 = 0.f, p1 = 0.f, p2 = 0.f;
  for (int d = lane; d < 512; d += 64) {
    float x = X[(r << 9) + d];
    p0 += x * Wout[d * 3 + 0];
    p1 += x * Wout[d * 3 + 1];
    p2 += x * Wout[d * 3 + 2];
  }
#pragma unroll
  for (int s = 32; s; s >>= 1) {
    p0 += __shfl_xor(p0, s);
    p1 += __shfl_xor(p1, s);
    p2 += __shfl_xor(p2, s);
  }
  if (lane == 0) {
    p0 += bout[0]; p1 += bout[1]; p2 += bout[2];
    float m = fmaxf(p0, fmaxf(p1, p2));
    float e0 = __expf(p0 - m), e1 = __expf(p1 - m), e2 = __expf(p2 - m);
    float z = 1.0f / (e0 + e1 + e2);
    out[r * 3 + 0] = e0 * z;
    out[r * 3 + 1] = e1 * z;
    out[r * 3 + 2] = e2 * z;
  }
}

// ---------------------------------------------------------------------------
extern "C" void kernel_launch(void* const* d_in, const int* in_sizes, int n_in,
                              void* d_out, int out_size, void* d_ws, size_t ws_size,
                              hipStream_t stream) {
  const float* DNAs  = (const float*)d_in[0];
  const float* W_pre = (const float*)d_in[1];
  const float* b_pre = (const float*)d_in[2];
  const float* Wq    = (const float*)d_in[3];
  const float* bq    = (const float*)d_in[4];
  const float* Wk    = (const float*)d_in[5];
  const float* bk    = (const float*)d_in[6];
  const float* Wv    = (const float*)d_in[7];
  const float* bv    = (const float*)d_in[8];
  const float* Wo    = (const float*)d_in[9];
  const float* bo    = (const float*)d_in[10];
  const float* ln1_g = (const float*)d_in[11];
  const float* ln1_b = (const float*)d_in[12];
  const float* W1    = (const float*)d_in[13];
  const float* b1    = (const float*)d_in[14];
  const float* W2    = (const float*)d_in[15];
  const float* b2    = (const float*)d_in[16];
  const float* ln2_g = (const float*)d_in[17];
  const float* ln2_b = (const float*)d_in[18];
  const float* lnf_g = (const float*)d_in[19];
  const float* lnf_b = (const float*)d_in[20];
  const float* W_out = (const float*)d_in[21];
  const float* b_out = (const float*)d_in[22];
  const int*   sidx  = (const int*)d_in[23];
  float* out = (float*)d_out;

  float* ws = (float*)d_ws;
  float*          X     = ws;
  unsigned short* Xbf   = (unsigned short*)(ws + 4194304);
  float*          Qb    = ws + 6291456;
  float*          T     = Qb;                  // Wo/FFN2 out (Q dead then)
  float*          PART  = Qb;                  // PV partials (Q dead after attn_score;
                                               // consumed by pv_reduce before T written)
  float*          IRED  = Qb + 327680;         // 1280 f
  float*          Kb    = ws + 10485760;
  float*          Vb    = ws + 14680064;
  float*          S     = ws + 18874368;
  unsigned short* CTXbf = (unsigned short*)(ws + 18874368 + 3276800);
  unsigned short* HBbf  = (unsigned short*)(ws + 18874368);
  unsigned short* WT    = (unsigned short*)(ws + 27262976);
  float*          Mb    = ws + 31981568;
  float*          VM    = ws + 32129024;
  int*            TOP   = (int*)(ws + 32131072);
  unsigned short* VMbf  = (unsigned short*)(ws + 32132352);
  unsigned short* WTqkvo = WT;
  unsigned short* WT1    = WT + 3145728;
  unsigned short* WT2    = WT + 6291456;
  (void)in_sizes; (void)n_in; (void)out_size; (void)ws_size;

  wtrans<<<dim3(16, 16, 12), 256, 0, stream>>>(Wq, Wk, Wv, Wo, WTqkvo, 512, 512, 262144);
  wtrans<<<dim3(64, 16, 3), 256, 0, stream>>>(W1, nullptr, nullptr, nullptr, WT1, 512, 2048, 1048576);
  wtrans<<<dim3(16, 64, 3), 256, 0, stream>>>(W2, nullptr, nullptr, nullptr, WT2, 2048, 512, 1048576);

  pre_kernel<<<16384, 256, 0, stream>>>(DNAs, W_pre, b_pre, X, Xbf);

  for (int i = 0; i < E_; ++i) {
    const int bOff = i * DM_;
    mgemm<1, true, false><<<dim3(256, 1, 3), 256, 0, stream>>>(
        Xbf, WTqkvo + (size_t)i * 262144, bq + bOff, bk + bOff, bv + bOff,
        Qb, nullptr, R_, DM_, DM_);

    qk_m_kernel<<<2048, 256, 0, stream>>>(Qb, Kb, sidx, Mb);
    topk_kernel<<<32, 256, 0, stream>>>(Mb, TOP);
    vmean_kernel<<<32, 256, 0, stream>>>(Vb, VM, VMbf);
    attn_score<<<dim3(16, 32), 256, 0, stream>>>(Qb, Kb, TOP, S);
    ctxfill_kernel<<<2048, 256, 0, stream>>>(VMbf, CTXbf);
    attn_pv_part<<<640, 512, 0, stream>>>(S, Vb, PART, IRED);   // PART in dead Qb
    pv_reduce<<<320, 256, 0, stream>>>(PART, IRED, TOP, CTXbf);

    mgemm<0, false, true><<<256, 256, 0, stream>>>(
        CTXbf, WTqkvo + (size_t)(9 + i) * 262144, bo + bOff, nullptr, nullptr,
        T, nullptr, R_, DM_, DM_);
    ln_kernel<true, true><<<8192, 256, 0, stream>>>(X, T, ln1_g + bOff, ln1_b + bOff, X, Xbf);

    mgemm<2, false, false><<<1024, 256, 0, stream>>>(
        Xbf, WT1 + (size_t)i * 1048576, b1 + i * DFF_, nullptr, nullptr,
        nullptr, HBbf, R_, DFF_, DM_);
    mgemm<0, false, true><<<256, 256, 0, stream>>>(
        HBbf, WT2 + (size_t)i * 1048576, b2 + bOff, nullptr, nullptr,
        T, nullptr, R_, DM_, DFF_);
    ln_kernel<true, true><<<8192, 256, 0, stream>>>(X, T, ln2_g + bOff, ln2_b + bOff, X, Xbf);
  }

  ln_kernel<false, false><<<8192, 256, 0, stream>>>(X, nullptr, lnf_g, lnf_b, X, nullptr);
  out_kernel<<<2048, 256, 0, stream>>>(X, W_out, b_out, out);
}

// Round 15
// 734.282 us; speedup vs baseline: 1.1821x; 1.0351x over previous
//
#include <hip/hip_runtime.h>
#include <math.h>

#define B_   4
#define L_   2048
#define DM_  512
#define H_   8
#define DK_  64
#define DFF_ 2048
#define E_   3
#define U_   40
#define R_   8192
#define SCALE_ 0.125f
#define EPS_ 1e-5f

typedef __bf16 bf16x8 __attribute__((ext_vector_type(8)));
typedef float f32x4 __attribute__((ext_vector_type(4)));

__device__ inline unsigned short f2bf(float x) {
  unsigned int u = __float_as_uint(x);
  unsigned int r = (u + 0x7fffu + ((u >> 16) & 1u)) >> 16;
  return (unsigned short)r;
}

// ---------------------------------------------------------------------------
// Weight transpose fp32 [R][C] -> bf16 [C][R].
// ---------------------------------------------------------------------------
__global__ __launch_bounds__(256) void wtrans(
    const float* __restrict__ s0, const float* __restrict__ s1,
    const float* __restrict__ s2, const float* __restrict__ s3,
    unsigned short* __restrict__ dst, int R, int C, int permat) {
  __shared__ float tile[32][33];
  int z = blockIdx.z;
  int which = z / 3, e = z % 3;
  const float* src = (which == 0 ? s0 : which == 1 ? s1 : which == 2 ? s2 : s3);
  src += (size_t)e * permat;
  unsigned short* d = dst + (size_t)z * permat;
  int c0 = blockIdx.x << 5, r0 = blockIdx.y << 5;
  int tx = threadIdx.x & 31, ty = threadIdx.x >> 5;
  for (int rr = ty; rr < 32; rr += 8)
    tile[rr][tx] = src[(size_t)(r0 + rr) * C + c0 + tx];
  __syncthreads();
  for (int cc = ty; cc < 32; cc += 8)
    d[(size_t)(c0 + cc) * R + r0 + tx] = f2bf(tile[tx][cc]);
}

// ---------------------------------------------------------------------------
// x = DNAs @ W_pre + b_pre ; writes fp32 X and bf16 Xbf
// ---------------------------------------------------------------------------
__global__ __launch_bounds__(256) void pre_kernel(
    const float* __restrict__ DNAs, const float* __restrict__ Wp,
    const float* __restrict__ bp, float* __restrict__ X,
    unsigned short* __restrict__ Xbf) {
  int t = blockIdx.x * 256 + threadIdx.x;
  int r = t >> 9, d = t & 511;
  float4 dna = *(const float4*)(DNAs + r * 4);
  float v = dna.x * Wp[d] + dna.y * Wp[512 + d] + dna.z * Wp[1024 + d] +
            dna.w * Wp[1536 + d] + bp[d];
  X[t] = v;
  Xbf[t] = f2bf(v);
}

// ---------------------------------------------------------------------------
// bf16 MFMA GEMM (m97 structure, 128xBN tile, BK=64, XOR-swizzled LDS).
// 1-D grid, XCD-affinity (m-tile = id&63). DBUF = 2-phase prefetch.
// BN = 128 (4-wave 2x2, acc[4][4]) or 64 (4-wave 2x2, acc[4][2]) — BN=64
// doubles block count for 1-block/CU shapes (Wo, FFN2) -> 2 blocks/CU.
// OUT: 0 fp32 [M,N]; 1 fp32 QKV remap; 2 bf16+ReLU.
// ---------------------------------------------------------------------------
template <int OUT, bool QKVZ, bool DBUF, int BN>
__global__ __launch_bounds__(256) void mgemm(
    const unsigned short* __restrict__ A, const unsigned short* __restrict__ BT,
    const float* __restrict__ bias0, const float* __restrict__ bias1,
    const float* __restrict__ bias2, float* __restrict__ Cf,
    unsigned short* __restrict__ Cb, int M, int N, int K) {
  constexpr int NFRAG = BN / 32;            // N-frags per wave (4 or 2)
  constexpr int BCH = BN / 8;               // B staging chunks (16 or 8)
  constexpr int ASZ = 128 * 64, BSZ = BN * 64;
  __shared__ unsigned short As[(DBUF ? 2 : 1) * ASZ];
  __shared__ unsigned short Bs[(DBUF ? 2 : 1) * BSZ];
  const int t = threadIdx.x, l = t & 63, w = t >> 6;
  const int id = blockIdx.x;
  const int m0 = (id & 63) << 7;
  const int n0 = (id >> 6) * BN;
  const int wm = w >> 1, wn = w & 1;
  const float* bias = bias0;
  if (QKVZ) {
    int z = blockIdx.z;
    BT += (size_t)z * 3 * 262144;
    bias = (z == 0 ? bias0 : z == 1 ? bias1 : bias2);
    Cf += (size_t)z * 4194304;
  }
  f32x4 acc[4][NFRAG] = {};

  const int srow = l >> 3;
  const int gslot = (l & 7) ^ srow;

  auto stage = [&](int buf, int k0) {
#pragma unroll
    for (int j = 0; j < 4; ++j) {
      int c = (w << 2) + j;                       // A: 16 chunks
      int row = (c << 3) + srow;
      const unsigned short* ga = A + (size_t)(m0 + row) * K + k0 + gslot * 8;
      __builtin_amdgcn_global_load_lds(
          (const __attribute__((address_space(1))) void*)ga,
          (__attribute__((address_space(3))) void*)(As + buf * ASZ + (c << 9)), 16, 0, 0);
      if (BN == 128 || j < 2) {                   // B: BCH chunks
        int cb = (BN == 128) ? c : ((w << 1) + j);
        int brow = (cb << 3) + srow;
        const unsigned short* gb = BT + (size_t)(n0 + brow) * K + k0 + gslot * 8;
        __builtin_amdgcn_global_load_lds(
            (const __attribute__((address_space(1))) void*)gb,
            (__attribute__((address_space(3))) void*)(Bs + buf * BSZ + (cb << 9)), 16, 0, 0);
      }
    }
  };
  auto compute = [&](int buf) {
#pragma unroll
    for (int ks = 0; ks < 2; ++ks) {
      bf16x8 af[4], bg[NFRAG];
      int slot = (ks << 2) + (l >> 4);
#pragma unroll
      for (int i = 0; i < 4; ++i) {
        int ar = (wm << 6) + (i << 4) + (l & 15);
        af[i] = *(const bf16x8*)(As + buf * ASZ + ar * 64 + (slot ^ (ar & 7)) * 8);
      }
#pragma unroll
      for (int j = 0; j < NFRAG; ++j) {
        int br = wn * (BN >> 1) + (j << 4) + (l & 15);
        bg[j] = *(const bf16x8*)(Bs + buf * BSZ + br * 64 + (slot ^ (br & 7)) * 8);
      }
#pragma unroll
      for (int i = 0; i < 4; ++i)
#pragma unroll
        for (int j = 0; j < NFRAG; ++j)
          acc[i][j] = __builtin_amdgcn_mfma_f32_16x16x32_bf16(af[i], bg[j],
                                                              acc[i][j], 0, 0, 0);
    }
  };

  if (DBUF) {
    int nk = K >> 6, cur = 0;
    stage(0, 0);
    __syncthreads();
    for (int s = 0; s < nk; ++s) {
      if (s + 1 < nk) stage(cur ^ 1, (s + 1) << 6);
      compute(cur);
      __syncthreads();
      cur ^= 1;
    }
  } else {
    for (int k0 = 0; k0 < K; k0 += 64) {
      stage(0, k0);
      __syncthreads();
      compute(0);
      __syncthreads();
    }
  }

#pragma unroll
  for (int i = 0; i < 4; ++i) {
    int rbase = m0 + (wm << 6) + (i << 4) + ((l >> 4) << 2);
#pragma unroll
    for (int j = 0; j < NFRAG; ++j) {
      int col = n0 + wn * (BN >> 1) + (j << 4) + (l & 15);
      float bv = bias[col];
#pragma unroll
      for (int r = 0; r < 4; ++r) {
        int row = rbase + r;
        float v = acc[i][j][r] + bv;
        if (OUT == 2) {
          v = fmaxf(v, 0.f);
          Cb[(size_t)row * N + col] = f2bf(v);
        } else if (OUT == 1) {
          int b = row >> 11, ll = row & 2047, h = col >> 6, d = col & 63;
          Cf[((size_t)(((b << 3) + h) << 11) + ll) * 64 + d] = v;
        } else {
          Cf[(size_t)row * N + col] = v;
        }
      }
    }
  }
}

// ---------------------------------------------------------------------------
// Sampled-score M: 8 queries/wave, 8 lanes/query, line-contiguous loads.
// ---------------------------------------------------------------------------
__global__ __launch_bounds__(256) void qk_m_kernel(
    const float* __restrict__ Q, const float* __restrict__ K,
    const int* __restrict__ sidx, float* __restrict__ Mout) {
  int t = threadIdx.x;
  int wave = t >> 6, lane = t & 63;
  int grp = lane >> 3, sub = lane & 7;
  int bh = blockIdx.x & 31;
  int j = blockIdx.x >> 5;
  int item = (bh << 11) + (j << 5) + wave * 8 + grp;
  int l = item & 2047;
  const float* Qr = Q + (size_t)item * 64;
  float4 q0 = *(const float4*)(Qr + sub * 4);
  float4 q1 = *(const float4*)(Qr + 32 + sub * 4);
  const float* Kb = K + (((size_t)bh << 11) << 6);
  const int* sp = sidx + l * U_;
  float mx = -INFINITY, sm = 0.f;
#pragma unroll 8
  for (int u = 0; u < U_; ++u) {
    int kidx = sp[u];
    const float* kr = Kb + ((size_t)kidx << 6);
    float4 k0 = *(const float4*)(kr + sub * 4);
    float4 k1 = *(const float4*)(kr + 32 + sub * 4);
    float p = q0.x * k0.x + q0.y * k0.y + q0.z * k0.z + q0.w * k0.w;
    p = fmaf(q1.x, k1.x, p); p = fmaf(q1.y, k1.y, p);
    p = fmaf(q1.z, k1.z, p); p = fmaf(q1.w, k1.w, p);
    p += __shfl_xor(p, 1);
    p += __shfl_xor(p, 2);
    p += __shfl_xor(p, 4);
    mx = fmaxf(mx, p);
    sm += p;
  }
  if (sub == 0) Mout[item] = mx - sm * (1.0f / U_);
}

// ---------------------------------------------------------------------------
// Exact top-40 via 4-pass radix select — fully parallel.
// ---------------------------------------------------------------------------
__global__ __launch_bounds__(256) void topk_kernel(
    const float* __restrict__ Mb, int* __restrict__ TOP) {
  __shared__ unsigned vals[2048];
  __shared__ int hist[256];
  __shared__ int suf[256];
  __shared__ unsigned s_prefix;
  __shared__ int s_want, s_cnt, s_run;
  __shared__ int wcnt[4];
  int bh = blockIdx.x, t = threadIdx.x;
  int lane = t & 63, w = t >> 6;
  for (int i = t; i < 2048; i += 256) {
    unsigned u = __float_as_uint(Mb[bh * 2048 + i]);
    vals[i] = (u & 0x80000000u) ? ~u : (u | 0x80000000u);
  }
  if (t == 0) { s_prefix = 0; s_want = U_; s_cnt = 0; s_run = 0; }
  __syncthreads();
#pragma unroll
  for (int shift = 24; shift >= 0; shift -= 8) {
    unsigned pref = s_prefix;
    int want = s_want;
    unsigned hmask = (shift == 24) ? 0u : (0xFFFFFFFFu << (shift + 8));
    hist[t] = 0;
    __syncthreads();
    for (int i = t; i < 2048; i += 256) {
      unsigned v = vals[i];
      if ((v & hmask) == pref) atomicAdd(&hist[(v >> shift) & 255], 1);
    }
    __syncthreads();
    suf[t] = hist[t];
    __syncthreads();
    for (int off = 1; off < 256; off <<= 1) {
      int add = (t + off < 256) ? suf[t + off] : 0;
      __syncthreads();
      suf[t] += add;
      __syncthreads();
    }
    int cgt = (t == 255) ? 0 : suf[t + 1];
    if (suf[t] >= want && cgt < want) {
      s_prefix = pref | ((unsigned)t << shift);
      s_want = want - cgt;
    }
    __syncthreads();
  }
  unsigned T = s_prefix;
  int want_eq = s_want;
  int base = U_ - want_eq;
  for (int i = t; i < 2048; i += 256) {
    if (vals[i] > T) {
      int slot = atomicAdd(&s_cnt, 1);
      TOP[bh * U_ + slot] = i;
    }
  }
  for (int c = 0; c < 8; ++c) {
    int i = (c << 8) + t;
    bool eq = (vals[i] == T);
    unsigned long long m = __ballot(eq);
    if (lane == 0) wcnt[w] = __popcll(m);
    __syncthreads();
    int woff = 0;
    for (int ww = 0; ww < w; ++ww) woff += wcnt[ww];
    if (eq) {
      int rank = s_run + woff + __popcll(m & ((1ull << lane) - 1ull));
      if (rank < want_eq) TOP[bh * U_ + base + rank] = i;
    }
    __syncthreads();
    if (t == 0) s_run += wcnt[0] + wcnt[1] + wcnt[2] + wcnt[3];
    __syncthreads();
  }
}

// ---------------------------------------------------------------------------
// vmean[bh,d] = mean over L of V[bh,l,d]; also bf16 copy for ctxfill.
// ---------------------------------------------------------------------------
__global__ __launch_bounds__(256) void vmean_kernel(
    const float* __restrict__ V, float* __restrict__ VM,
    unsigned short* __restrict__ VMbf) {
  __shared__ float p[4][64];
  int bh = blockIdx.x;
  int d = threadIdx.x & 63, c = threadIdx.x >> 6;
  const float* Vb = V + (((size_t)bh << 11) + c * 512) * 64;
  float s = 0.f;
  for (int l = 0; l < 512; ++l) s += Vb[l * 64 + d];
  p[c][d] = s;
  __syncthreads();
  if (threadIdx.x < 64) {
    float m = (p[0][d] + p[1][d] + p[2][d] + p[3][d]) * (1.0f / 2048.0f);
    VM[bh * 64 + d] = m;
    VMbf[bh * 64 + d] = f2bf(m);
  }
}

// ---------------------------------------------------------------------------
// S[bh,u,k] = scale * dot(Q[top[bh,u]], K[bh,k]).
// ---------------------------------------------------------------------------
__global__ __launch_bounds__(256) void attn_score(
    const float* __restrict__ Q, const float* __restrict__ K,
    const int* __restrict__ TOP, float* __restrict__ S) {
  __shared__ float Ks[128 * 65];
  __shared__ float Qs[40 * 64];
  int bh = blockIdx.y, k0 = blockIdx.x << 7;
  int t = threadIdx.x;
  for (int i = t; i < 2560; i += 256) {
    int u = i >> 6, d = i & 63;
    int row = TOP[bh * U_ + u];
    Qs[i] = Q[(((size_t)bh << 11) + row) * 64 + d];
  }
  for (int i = t; i < 8192; i += 256) {
    int k = i >> 6, d = i & 63;
    Ks[k * 65 + d] = K[(((size_t)bh << 11) + k0 + k) * 64 + d];
  }
  __syncthreads();
  int kk = t & 127, ug = (t >> 7) * 20;
  const float* kp = Ks + kk * 65;
  for (int u = ug; u < ug + 20; ++u) {
    const float* qp = Qs + u * 64;
    float s = 0.f;
#pragma unroll 8
    for (int d = 0; d < 64; ++d) s = fmaf(qp[d], kp[d], s);
    S[((size_t)bh * U_ + u) * 2048 + k0 + kk] = s * SCALE_;
  }
}

// ---------------------------------------------------------------------------
// attn_pv_part: K-split PV (4 chunks). grid 640.
// ---------------------------------------------------------------------------
__global__ __launch_bounds__(512) void attn_pv_part(
    const float* __restrict__ S, const float* __restrict__ V,
    float* __restrict__ PART, float* __restrict__ IRED) {
  __shared__ float Vs[128][64];
  __shared__ float ps[8][128];
  __shared__ float mred[8];
  int id = blockIdx.x;
  int bh = id & 31, sub = id >> 5;
  int ug = sub >> 2, kc = sub & 3;
  int t = threadIdx.x, lane = t & 63, w = t >> 6;
  int rowbase = bh * U_ + ug * 8;
  int row = rowbase + w;

  const float* Sr = S + (size_t)row * 2048;
  float mx = -INFINITY;
  for (int j = 0; j < 32; ++j) mx = fmaxf(mx, Sr[j * 64 + lane]);
#pragma unroll
  for (int s = 32; s; s >>= 1) mx = fmaxf(mx, __shfl_xor(mx, s));
  float sm = 0.f;
  for (int j = 0; j < 32; ++j) sm += __expf(Sr[j * 64 + lane] - mx);
#pragma unroll
  for (int s = 32; s; s >>= 1) sm += __shfl_xor(sm, s);
  if (lane == 0) {
    mred[w] = mx;
    if (kc == 0) IRED[row] = 1.0f / sm;
  }
  __syncthreads();

  const float* Vb = V + (((size_t)bh << 11) << 6);
  float a0 = 0.f, a1 = 0.f, a2 = 0.f, a3 = 0.f;
  for (int c = kc * 4; c < kc * 4 + 4; ++c) {
    int k0 = c << 7;
#pragma unroll
    for (int i = 0; i < 4; ++i) {
      int ve = t + i * 512;
      int k = ve >> 4, dq = ve & 15;
      *(float4*)&Vs[k][dq << 2] = *(const float4*)(Vb + (size_t)(k0 + k) * 64 + (dq << 2));
    }
#pragma unroll
    for (int i = 0; i < 2; ++i) {
      int e = t + i * 512;
      int r = e >> 7, kk = e & 127;
      ps[r][kk] = __expf(S[(size_t)(rowbase + r) * 2048 + k0 + kk] - mred[r]);
    }
    __syncthreads();
    const float* p = ps[w];
#pragma unroll 4
    for (int kk = 0; kk < 128; kk += 4) {
      float4 p4 = *(const float4*)(p + kk);
      a0 = fmaf(p4.x, Vs[kk + 0][lane], a0);
      a1 = fmaf(p4.y, Vs[kk + 1][lane], a1);
      a2 = fmaf(p4.z, Vs[kk + 2][lane], a2);
      a3 = fmaf(p4.w, Vs[kk + 3][lane], a3);
    }
    __syncthreads();
  }
  PART[((size_t)kc * 1280 + row) * 64 + lane] = (a0 + a1) + (a2 + a3);
}

// ---------------------------------------------------------------------------
// pv_reduce: sum 4 partials (fixed order), scale, fused bf16 scatter.
// ---------------------------------------------------------------------------
__global__ __launch_bounds__(256) void pv_reduce(
    const float* __restrict__ PART, const float* __restrict__ IRED,
    const int* __restrict__ TOP, unsigned short* __restrict__ CTX) {
  int gid = blockIdx.x * 256 + threadIdx.x;
  int row = gid >> 6, lane = gid & 63;
  float v = (PART[(size_t)row * 64 + lane] + PART[(size_t)(1280 + row) * 64 + lane]) +
            (PART[(size_t)(2560 + row) * 64 + lane] + PART[(size_t)(3840 + row) * 64 + lane]);
  v *= IRED[row];
  int bh = row / U_;
  int b = bh >> 3, h = bh & 7;
  int orow = TOP[row];
  CTX[((size_t)((b << 11) + orow) << 9) + (h << 6) + lane] = f2bf(v);
}

// ---------------------------------------------------------------------------
// ctx fill (vectorized: 8 bf16 per thread)
// ---------------------------------------------------------------------------
__global__ __launch_bounds__(256) void ctxfill_kernel(
    const unsigned short* __restrict__ VMbf, unsigned short* __restrict__ CTX) {
  int t8 = (blockIdx.x * 256 + threadIdx.x) << 3;
  int c0 = t8 & 511;
  int b = t8 >> 20;
  *(uint4*)(CTX + t8) = *(const uint4*)(VMbf + (b << 9) + c0);
}

// ---------------------------------------------------------------------------
// LayerNorm(512) with optional residual; float2-vectorized.
// ---------------------------------------------------------------------------
template <bool ADD, bool WB>
__global__ __launch_bounds__(256) void ln_kernel(
    const float* __restrict__ Xin, const float* __restrict__ Tin,
    const float* __restrict__ g, const float* __restrict__ bta,
    float* __restrict__ Xout, unsigned short* __restrict__ Xbf) {
  __shared__ float red[8];
  int r = blockIdx.x, t = threadIdx.x;
  int i0 = (r << 9) + (t << 1);
  float2 v = *(const float2*)(Xin + i0);
  if constexpr (ADD) {
    float2 tv = *(const float2*)(Tin + i0);
    v.x += tv.x; v.y += tv.y;
  }
  float sm = v.x + v.y;
#pragma unroll
  for (int s = 32; s; s >>= 1) sm += __shfl_xor(sm, s);
  int lane = t & 63, w = t >> 6;
  if (lane == 0) red[w] = sm;
  __syncthreads();
  float mean = (red[0] + red[1] + red[2] + red[3]) * (1.0f / 512.0f);
  float d0 = v.x - mean, d1 = v.y - mean;
  float sq = d0 * d0 + d1 * d1;
#pragma unroll
  for (int s = 32; s; s >>= 1) sq += __shfl_xor(sq, s);
  if (lane == 0) red[4 + w] = sq;
  __syncthreads();
  float var = (red[4] + red[5] + red[6] + red[7]) * (1.0f / 512.0f);
  float rstd = rsqrtf(var + EPS_);
  float2 gv = *(const float2*)(g + (t << 1));
  float2 bv = *(const float2*)(bta + (t << 1));
  float o0 = d0 * rstd * gv.x + bv.x;
  float o1 = d1 * rstd * gv.y + bv.y;
  *(float2*)(Xout + i0) = make_float2(o0, o1);
  if constexpr (WB) {
    *(unsigned*)(Xbf + i0) = (unsigned)f2bf(o0) | ((unsigned)f2bf(o1) << 16);
  }
}

// ---------------------------------------------------------------------------
// out = softmax(X @ W_out + b_out); one wave per row.
// ---------------------------------------------------------------------------
__global__ __launch_bounds__(256) void out_kernel(
    const float* __restrict__ X, const float* __restrict__ Wout,
    const float* __restrict__ bout, float* __restrict__ out) {
  int w = threadIdx.x >> 6, lane = threadIdx.x & 63;
  int r = blockIdx.x * 4 + w;
  float p0 = 0.f, p1 = 0.f, p2 = 0.f;
  for (int d = lane; d < 512; d += 64) {
    float x = X[(r << 9) + d];
    p0 += x * Wout[d * 3 + 0];
    p1 += x * Wout[d * 3 + 1];
    p2 += x * Wout[d * 3 + 2];
  }
#pragma unroll
  for (int s = 32; s; s >>= 1) {
    p0 += __shfl_xor(p0, s);
    p1 += __shfl_xor(p1, s);
    p2 += __shfl_xor(p2, s);
  }
  if (lane == 0) {
    p0 += bout[0]; p1 += bout[1]; p2 += bout[2];
    float m = fmaxf(p0, fmaxf(p1, p2));
    float e0 = __expf(p0 - m), e1 = __expf(p1 - m), e2 = __expf(p2 - m);
    float z = 1.0f / (e0 + e1 + e2);
    out[r * 3 + 0] = e0 * z;
    out[r * 3 + 1] = e1 * z;
    out[r * 3 + 2] = e2 * z;
  }
}

// ---------------------------------------------------------------------------
extern "C" void kernel_launch(void* const* d_in, const int* in_sizes, int n_in,
                              void* d_out, int out_size, void* d_ws, size_t ws_size,
                              hipStream_t stream) {
  const float* DNAs  = (const float*)d_in[0];
  const float* W_pre = (const float*)d_in[1];
  const float* b_pre = (const float*)d_in[2];
  const float* Wq    = (const float*)d_in[3];
  const float* bq    = (const float*)d_in[4];
  const float* Wk    = (const float*)d_in[5];
  const float* bk    = (const float*)d_in[6];
  const float* Wv    = (const float*)d_in[7];
  const float* bv    = (const float*)d_in[8];
  const float* Wo    = (const float*)d_in[9];
  const float* bo    = (const float*)d_in[10];
  const float* ln1_g = (const float*)d_in[11];
  const float* ln1_b = (const float*)d_in[12];
  const float* W1    = (const float*)d_in[13];
  const float* b1    = (const float*)d_in[14];
  const float* W2    = (const float*)d_in[15];
  const float* b2    = (const float*)d_in[16];
  const float* ln2_g = (const float*)d_in[17];
  const float* ln2_b = (const float*)d_in[18];
  const float* lnf_g = (const float*)d_in[19];
  const float* lnf_b = (const float*)d_in[20];
  const float* W_out = (const float*)d_in[21];
  const float* b_out = (const float*)d_in[22];
  const int*   sidx  = (const int*)d_in[23];
  float* out = (float*)d_out;

  float* ws = (float*)d_ws;
  float*          X     = ws;
  unsigned short* Xbf   = (unsigned short*)(ws + 4194304);
  float*          Qb    = ws + 6291456;
  float*          T     = Qb;
  float*          PART  = Qb;
  float*          IRED  = Qb + 327680;
  float*          Kb    = ws + 10485760;
  float*          Vb    = ws + 14680064;
  float*          S     = ws + 18874368;
  unsigned short* CTXbf = (unsigned short*)(ws + 18874368 + 3276800);
  unsigned short* HBbf  = (unsigned short*)(ws + 18874368);
  unsigned short* WT    = (unsigned short*)(ws + 27262976);
  float*          Mb    = ws + 31981568;
  float*          VM    = ws + 32129024;
  int*            TOP   = (int*)(ws + 32131072);
  unsigned short* VMbf  = (unsigned short*)(ws + 32132352);
  unsigned short* WTqkvo = WT;
  unsigned short* WT1    = WT + 3145728;
  unsigned short* WT2    = WT + 6291456;
  (void)in_sizes; (void)n_in; (void)out_size; (void)ws_size;

  wtrans<<<dim3(16, 16, 12), 256, 0, stream>>>(Wq, Wk, Wv, Wo, WTqkvo, 512, 512, 262144);
  wtrans<<<dim3(64, 16, 3), 256, 0, stream>>>(W1, nullptr, nullptr, nullptr, WT1, 512, 2048, 1048576);
  wtrans<<<dim3(16, 64, 3), 256, 0, stream>>>(W2, nullptr, nullptr, nullptr, WT2, 2048, 512, 1048576);

  pre_kernel<<<16384, 256, 0, stream>>>(DNAs, W_pre, b_pre, X, Xbf);

  for (int i = 0; i < E_; ++i) {
    const int bOff = i * DM_;
    mgemm<1, true, false, 128><<<dim3(256, 1, 3), 256, 0, stream>>>(
        Xbf, WTqkvo + (size_t)i * 262144, bq + bOff, bk + bOff, bv + bOff,
        Qb, nullptr, R_, DM_, DM_);

    qk_m_kernel<<<2048, 256, 0, stream>>>(Qb, Kb, sidx, Mb);
    topk_kernel<<<32, 256, 0, stream>>>(Mb, TOP);
    vmean_kernel<<<32, 256, 0, stream>>>(Vb, VM, VMbf);
    attn_score<<<dim3(16, 32), 256, 0, stream>>>(Qb, Kb, TOP, S);
    ctxfill_kernel<<<2048, 256, 0, stream>>>(VMbf, CTXbf);
    attn_pv_part<<<640, 512, 0, stream>>>(S, Vb, PART, IRED);
    pv_reduce<<<320, 256, 0, stream>>>(PART, IRED, TOP, CTXbf);

    mgemm<0, false, true, 64><<<512, 256, 0, stream>>>(
        CTXbf, WTqkvo + (size_t)(9 + i) * 262144, bo + bOff, nullptr, nullptr,
        T, nullptr, R_, DM_, DM_);
    ln_kernel<true, true><<<8192, 256, 0, stream>>>(X, T, ln1_g + bOff, ln1_b + bOff, X, Xbf);

    mgemm<2, false, false, 128><<<1024, 256, 0, stream>>>(
        Xbf, WT1 + (size_t)i * 1048576, b1 + i * DFF_, nullptr, nullptr,
        nullptr, HBbf, R_, DFF_, DM_);
    mgemm<0, false, true, 64><<<512, 256, 0, stream>>>(
        HBbf, WT2 + (size_t)i * 1048576, b2 + bOff, nullptr, nullptr,
        T, nullptr, R_, DM_, DFF_);
    ln_kernel<true, true><<<8192, 256, 0, stream>>>(X, T, ln2_g + bOff, ln2_b + bOff, X, Xbf);
  }

  ln_kernel<false, false><<<8192, 256, 0, stream>>>(X, nullptr, lnf_g, lnf_b, X, nullptr);
  out_kernel<<<2048, 256, 0, stream>>>(X, W_out, b_out, out);
}

// Round 16
// 663.581 us; speedup vs baseline: 1.3080x; 1.1065x over previous
//
#include <hip/hip_runtime.h>
#include <math.h>

#define B_   4
#define L_   2048
#define DM_  512
#define H_   8
#define DK_  64
#define DFF_ 2048
#define E_   3
#define U_   40
#define R_   8192
#define SCALE_ 0.125f
#define EPS_ 1e-5f

typedef __bf16 bf16x8 __attribute__((ext_vector_type(8)));
typedef float f32x4 __attribute__((ext_vector_type(4)));

__device__ inline unsigned short f2bf(float x) {
  unsigned int u = __float_as_uint(x);
  unsigned int r = (u + 0x7fffu + ((u >> 16) & 1u)) >> 16;
  return (unsigned short)r;
}
__device__ inline float bflo(unsigned u) { return __uint_as_float(u << 16); }
__device__ inline float bfhi(unsigned u) { return __uint_as_float(u & 0xffff0000u); }
__device__ inline float bf1(unsigned short u) { return __uint_as_float((unsigned)u << 16); }

// ---------------------------------------------------------------------------
// Weight transpose fp32 [R][C] -> bf16 [C][R].
// ---------------------------------------------------------------------------
__global__ __launch_bounds__(256) void wtrans(
    const float* __restrict__ s0, const float* __restrict__ s1,
    const float* __restrict__ s2, const float* __restrict__ s3,
    unsigned short* __restrict__ dst, int R, int C, int permat) {
  __shared__ float tile[32][33];
  int z = blockIdx.z;
  int which = z / 3, e = z % 3;
  const float* src = (which == 0 ? s0 : which == 1 ? s1 : which == 2 ? s2 : s3);
  src += (size_t)e * permat;
  unsigned short* d = dst + (size_t)z * permat;
  int c0 = blockIdx.x << 5, r0 = blockIdx.y << 5;
  int tx = threadIdx.x & 31, ty = threadIdx.x >> 5;
  for (int rr = ty; rr < 32; rr += 8)
    tile[rr][tx] = src[(size_t)(r0 + rr) * C + c0 + tx];
  __syncthreads();
  for (int cc = ty; cc < 32; cc += 8)
    d[(size_t)(c0 + cc) * R + r0 + tx] = f2bf(tile[tx][cc]);
}

// ---------------------------------------------------------------------------
// x = DNAs @ W_pre + b_pre ; writes fp32 X and bf16 Xbf
// ---------------------------------------------------------------------------
__global__ __launch_bounds__(256) void pre_kernel(
    const float* __restrict__ DNAs, const float* __restrict__ Wp,
    const float* __restrict__ bp, float* __restrict__ X,
    unsigned short* __restrict__ Xbf) {
  int t = blockIdx.x * 256 + threadIdx.x;
  int r = t >> 9, d = t & 511;
  float4 dna = *(const float4*)(DNAs + r * 4);
  float v = dna.x * Wp[d] + dna.y * Wp[512 + d] + dna.z * Wp[1024 + d] +
            dna.w * Wp[1536 + d] + bp[d];
  X[t] = v;
  Xbf[t] = f2bf(v);
}

// ---------------------------------------------------------------------------
// bf16 MFMA GEMM (m97 structure, 128xBN tile, BK=64, XOR-swizzled LDS).
// 1-D grid, XCD-affinity. DBUF = 2-phase prefetch. BN = 128 or 64.
// OUT: 1 = bf16 QKV remap (B,H,L,DK); 2 = bf16 + ReLU; 3 = bf16 [M,N].
// ---------------------------------------------------------------------------
template <int OUT, bool QKVZ, bool DBUF, int BN>
__global__ __launch_bounds__(256) void mgemm(
    const unsigned short* __restrict__ A, const unsigned short* __restrict__ BT,
    const float* __restrict__ bias0, const float* __restrict__ bias1,
    const float* __restrict__ bias2, unsigned short* __restrict__ Cb,
    int M, int N, int K) {
  constexpr int NFRAG = BN / 32;
  constexpr int ASZ = 128 * 64, BSZ = BN * 64;
  __shared__ unsigned short As[(DBUF ? 2 : 1) * ASZ];
  __shared__ unsigned short Bs[(DBUF ? 2 : 1) * BSZ];
  const int t = threadIdx.x, l = t & 63, w = t >> 6;
  const int id = blockIdx.x;
  const int m0 = (id & 63) << 7;
  const int n0 = (id >> 6) * BN;
  const int wm = w >> 1, wn = w & 1;
  const float* bias = bias0;
  if (QKVZ) {
    int z = blockIdx.z;
    BT += (size_t)z * 3 * 262144;
    bias = (z == 0 ? bias0 : z == 1 ? bias1 : bias2);
    Cb += (size_t)z * 4194304;
  }
  f32x4 acc[4][NFRAG] = {};

  const int srow = l >> 3;
  const int gslot = (l & 7) ^ srow;

  auto stage = [&](int buf, int k0) {
#pragma unroll
    for (int j = 0; j < 4; ++j) {
      int c = (w << 2) + j;
      int row = (c << 3) + srow;
      const unsigned short* ga = A + (size_t)(m0 + row) * K + k0 + gslot * 8;
      __builtin_amdgcn_global_load_lds(
          (const __attribute__((address_space(1))) void*)ga,
          (__attribute__((address_space(3))) void*)(As + buf * ASZ + (c << 9)), 16, 0, 0);
      if (BN == 128 || j < 2) {
        int cb = (BN == 128) ? c : ((w << 1) + j);
        int brow = (cb << 3) + srow;
        const unsigned short* gb = BT + (size_t)(n0 + brow) * K + k0 + gslot * 8;
        __builtin_amdgcn_global_load_lds(
            (const __attribute__((address_space(1))) void*)gb,
            (__attribute__((address_space(3))) void*)(Bs + buf * BSZ + (cb << 9)), 16, 0, 0);
      }
    }
  };
  auto compute = [&](int buf) {
#pragma unroll
    for (int ks = 0; ks < 2; ++ks) {
      bf16x8 af[4], bg[NFRAG];
      int slot = (ks << 2) + (l >> 4);
#pragma unroll
      for (int i = 0; i < 4; ++i) {
        int ar = (wm << 6) + (i << 4) + (l & 15);
        af[i] = *(const bf16x8*)(As + buf * ASZ + ar * 64 + (slot ^ (ar & 7)) * 8);
      }
#pragma unroll
      for (int j = 0; j < NFRAG; ++j) {
        int br = wn * (BN >> 1) + (j << 4) + (l & 15);
        bg[j] = *(const bf16x8*)(Bs + buf * BSZ + br * 64 + (slot ^ (br & 7)) * 8);
      }
#pragma unroll
      for (int i = 0; i < 4; ++i)
#pragma unroll
        for (int j = 0; j < NFRAG; ++j)
          acc[i][j] = __builtin_amdgcn_mfma_f32_16x16x32_bf16(af[i], bg[j],
                                                              acc[i][j], 0, 0, 0);
    }
  };

  if (DBUF) {
    int nk = K >> 6, cur = 0;
    stage(0, 0);
    __syncthreads();
    for (int s = 0; s < nk; ++s) {
      if (s + 1 < nk) stage(cur ^ 1, (s + 1) << 6);
      compute(cur);
      __syncthreads();
      cur ^= 1;
    }
  } else {
    for (int k0 = 0; k0 < K; k0 += 64) {
      stage(0, k0);
      __syncthreads();
      compute(0);
      __syncthreads();
    }
  }

#pragma unroll
  for (int i = 0; i < 4; ++i) {
    int rbase = m0 + (wm << 6) + (i << 4) + ((l >> 4) << 2);
#pragma unroll
    for (int j = 0; j < NFRAG; ++j) {
      int col = n0 + wn * (BN >> 1) + (j << 4) + (l & 15);
      float bv = bias[col];
#pragma unroll
      for (int r = 0; r < 4; ++r) {
        int row = rbase + r;
        float v = acc[i][j][r] + bv;
        if (OUT == 2) {
          v = fmaxf(v, 0.f);
          Cb[(size_t)row * N + col] = f2bf(v);
        } else if (OUT == 1) {
          int b = row >> 11, ll = row & 2047, h = col >> 6, d = col & 63;
          Cb[((size_t)(((b << 3) + h) << 11) + ll) * 64 + d] = f2bf(v);
        } else {
          Cb[(size_t)row * N + col] = f2bf(v);
        }
      }
    }
  }
}

// ---------------------------------------------------------------------------
// Sampled-score M on bf16 Q/K: 8 q/wave, 8 lanes/q, ONE uint4 load per row.
// XCD-affinity (bh = blockIdx&31) keeps each head's K panel L2-resident.
// ---------------------------------------------------------------------------
__global__ __launch_bounds__(256) void qk_m_kernel(
    const unsigned short* __restrict__ Q, const unsigned short* __restrict__ K,
    const int* __restrict__ sidx, float* __restrict__ Mout) {
  int t = threadIdx.x;
  int wave = t >> 6, lane = t & 63;
  int grp = lane >> 3, sub = lane & 7;
  int bh = blockIdx.x & 31;
  int j = blockIdx.x >> 5;
  int item = (bh << 11) + (j << 5) + wave * 8 + grp;
  int l = item & 2047;
  uint4 qv = *(const uint4*)(Q + ((size_t)item << 6) + (sub << 3));
  float qf[8] = {bflo(qv.x), bfhi(qv.x), bflo(qv.y), bfhi(qv.y),
                 bflo(qv.z), bfhi(qv.z), bflo(qv.w), bfhi(qv.w)};
  const unsigned short* Kb = K + (((size_t)bh << 11) << 6) + (sub << 3);
  const int* sp = sidx + l * U_;
  float mx = -INFINITY, sm = 0.f;
#pragma unroll 8
  for (int u = 0; u < U_; ++u) {
    int kidx = sp[u];
    uint4 kv = *(const uint4*)(Kb + ((size_t)kidx << 6));
    float p = qf[0] * bflo(kv.x);
    p = fmaf(qf[1], bfhi(kv.x), p);
    p = fmaf(qf[2], bflo(kv.y), p);
    p = fmaf(qf[3], bfhi(kv.y), p);
    p = fmaf(qf[4], bflo(kv.z), p);
    p = fmaf(qf[5], bfhi(kv.z), p);
    p = fmaf(qf[6], bflo(kv.w), p);
    p = fmaf(qf[7], bfhi(kv.w), p);
    p += __shfl_xor(p, 1);
    p += __shfl_xor(p, 2);
    p += __shfl_xor(p, 4);
    mx = fmaxf(mx, p);
    sm += p;
  }
  if (sub == 0) Mout[item] = mx - sm * (1.0f / U_);
}

// ---------------------------------------------------------------------------
// Exact top-40 via 4-pass radix select — fully parallel.
// ---------------------------------------------------------------------------
__global__ __launch_bounds__(256) void topk_kernel(
    const float* __restrict__ Mb, int* __restrict__ TOP) {
  __shared__ unsigned vals[2048];
  __shared__ int hist[256];
  __shared__ int suf[256];
  __shared__ unsigned s_prefix;
  __shared__ int s_want, s_cnt, s_run;
  __shared__ int wcnt[4];
  int bh = blockIdx.x, t = threadIdx.x;
  int lane = t & 63, w = t >> 6;
  for (int i = t; i < 2048; i += 256) {
    unsigned u = __float_as_uint(Mb[bh * 2048 + i]);
    vals[i] = (u & 0x80000000u) ? ~u : (u | 0x80000000u);
  }
  if (t == 0) { s_prefix = 0; s_want = U_; s_cnt = 0; s_run = 0; }
  __syncthreads();
#pragma unroll
  for (int shift = 24; shift >= 0; shift -= 8) {
    unsigned pref = s_prefix;
    int want = s_want;
    unsigned hmask = (shift == 24) ? 0u : (0xFFFFFFFFu << (shift + 8));
    hist[t] = 0;
    __syncthreads();
    for (int i = t; i < 2048; i += 256) {
      unsigned v = vals[i];
      if ((v & hmask) == pref) atomicAdd(&hist[(v >> shift) & 255], 1);
    }
    __syncthreads();
    suf[t] = hist[t];
    __syncthreads();
    for (int off = 1; off < 256; off <<= 1) {
      int add = (t + off < 256) ? suf[t + off] : 0;
      __syncthreads();
      suf[t] += add;
      __syncthreads();
    }
    int cgt = (t == 255) ? 0 : suf[t + 1];
    if (suf[t] >= want && cgt < want) {
      s_prefix = pref | ((unsigned)t << shift);
      s_want = want - cgt;
    }
    __syncthreads();
  }
  unsigned T = s_prefix;
  int want_eq = s_want;
  int base = U_ - want_eq;
  for (int i = t; i < 2048; i += 256) {
    if (vals[i] > T) {
      int slot = atomicAdd(&s_cnt, 1);
      TOP[bh * U_ + slot] = i;
    }
  }
  for (int c = 0; c < 8; ++c) {
    int i = (c << 8) + t;
    bool eq = (vals[i] == T);
    unsigned long long m = __ballot(eq);
    if (lane == 0) wcnt[w] = __popcll(m);
    __syncthreads();
    int woff = 0;
    for (int ww = 0; ww < w; ++ww) woff += wcnt[ww];
    if (eq) {
      int rank = s_run + woff + __popcll(m & ((1ull << lane) - 1ull));
      if (rank < want_eq) TOP[bh * U_ + base + rank] = i;
    }
    __syncthreads();
    if (t == 0) s_run += wcnt[0] + wcnt[1] + wcnt[2] + wcnt[3];
    __syncthreads();
  }
}

// ---------------------------------------------------------------------------
// vmean[bh,d] = mean over L of V[bh,l,d] (bf16 V); also bf16 copy.
// ---------------------------------------------------------------------------
__global__ __launch_bounds__(256) void vmean_kernel(
    const unsigned short* __restrict__ V, float* __restrict__ VM,
    unsigned short* __restrict__ VMbf) {
  __shared__ float p[4][64];
  int bh = blockIdx.x;
  int d = threadIdx.x & 63, c = threadIdx.x >> 6;
  const unsigned short* Vb = V + (((size_t)bh << 11) + c * 512) * 64;
  float s = 0.f;
  for (int l = 0; l < 512; ++l) s += bf1(Vb[l * 64 + d]);
  p[c][d] = s;
  __syncthreads();
  if (threadIdx.x < 64) {
    float m = (p[0][d] + p[1][d] + p[2][d] + p[3][d]) * (1.0f / 2048.0f);
    VM[bh * 64 + d] = m;
    VMbf[bh * 64 + d] = f2bf(m);
  }
}

// ---------------------------------------------------------------------------
// S[bh,u,k] = scale * dot(Q[top[bh,u]], K[bh,k]) — bf16 inputs, fp32 LDS.
// ---------------------------------------------------------------------------
__global__ __launch_bounds__(256) void attn_score(
    const unsigned short* __restrict__ Q, const unsigned short* __restrict__ K,
    const int* __restrict__ TOP, float* __restrict__ S) {
  __shared__ float Ks[128 * 65];
  __shared__ float Qs[40 * 64];
  int bh = blockIdx.y, k0 = blockIdx.x << 7;
  int t = threadIdx.x;
  const unsigned short* Kbase = K + (((size_t)bh << 11) << 6);
  for (int i = t; i < 4096; i += 256) {            // 128 rows x 32 pairs
    int k = i >> 5, dp = i & 31;
    unsigned u = *(const unsigned*)(Kbase + ((size_t)(k0 + k) << 6) + (dp << 1));
    Ks[k * 65 + (dp << 1)] = bflo(u);
    Ks[k * 65 + (dp << 1) + 1] = bfhi(u);
  }
  for (int i = t; i < 1280; i += 256) {            // 40 rows x 32 pairs
    int uq = i >> 5, dp = i & 31;
    int row = TOP[bh * U_ + uq];
    unsigned u = *(const unsigned*)(Q + ((((size_t)bh << 11) + row) << 6) + (dp << 1));
    Qs[uq * 64 + (dp << 1)] = bflo(u);
    Qs[uq * 64 + (dp << 1) + 1] = bfhi(u);
  }
  __syncthreads();
  int kk = t & 127, ug = (t >> 7) * 20;
  const float* kp = Ks + kk * 65;
  for (int u = ug; u < ug + 20; ++u) {
    const float* qp = Qs + u * 64;
    float s = 0.f;
#pragma unroll 8
    for (int d = 0; d < 64; ++d) s = fmaf(qp[d], kp[d], s);
    S[((size_t)bh * U_ + u) * 2048 + k0 + kk] = s * SCALE_;
  }
}

// ---------------------------------------------------------------------------
// attn_pv_part: K-split PV (4 chunks), bf16 V staged->fp32 LDS. grid 640.
// ---------------------------------------------------------------------------
__global__ __launch_bounds__(512) void attn_pv_part(
    const float* __restrict__ S, const unsigned short* __restrict__ V,
    float* __restrict__ PART, float* __restrict__ IRED) {
  __shared__ float Vs[128][64];
  __shared__ float ps[8][128];
  __shared__ float mred[8];
  int id = blockIdx.x;
  int bh = id & 31, sub = id >> 5;
  int ug = sub >> 2, kc = sub & 3;
  int t = threadIdx.x, lane = t & 63, w = t >> 6;
  int rowbase = bh * U_ + ug * 8;
  int row = rowbase + w;

  const float* Sr = S + (size_t)row * 2048;
  float mx = -INFINITY;
  for (int j = 0; j < 32; ++j) mx = fmaxf(mx, Sr[j * 64 + lane]);
#pragma unroll
  for (int s = 32; s; s >>= 1) mx = fmaxf(mx, __shfl_xor(mx, s));
  float sm = 0.f;
  for (int j = 0; j < 32; ++j) sm += __expf(Sr[j * 64 + lane] - mx);
#pragma unroll
  for (int s = 32; s; s >>= 1) sm += __shfl_xor(sm, s);
  if (lane == 0) {
    mred[w] = mx;
    if (kc == 0) IRED[row] = 1.0f / sm;
  }
  __syncthreads();

  const unsigned short* Vb = V + (((size_t)bh << 11) << 6);
  float a0 = 0.f, a1 = 0.f, a2 = 0.f, a3 = 0.f;
  for (int c = kc * 4; c < kc * 4 + 4; ++c) {
    int k0 = c << 7;
#pragma unroll
    for (int i = 0; i < 8; ++i) {                  // 4096 pairs / 512 threads
      int pe = t + i * 512;
      int k = pe >> 5, dp = pe & 31;
      unsigned u = *(const unsigned*)(Vb + ((size_t)(k0 + k) << 6) + (dp << 1));
      Vs[k][(dp << 1)] = bflo(u);
      Vs[k][(dp << 1) + 1] = bfhi(u);
    }
#pragma unroll
    for (int i = 0; i < 2; ++i) {
      int e = t + i * 512;
      int r = e >> 7, kk = e & 127;
      ps[r][kk] = __expf(S[(size_t)(rowbase + r) * 2048 + k0 + kk] - mred[r]);
    }
    __syncthreads();
    const float* p = ps[w];
#pragma unroll 4
    for (int kk = 0; kk < 128; kk += 4) {
      float4 p4 = *(const float4*)(p + kk);
      a0 = fmaf(p4.x, Vs[kk + 0][lane], a0);
      a1 = fmaf(p4.y, Vs[kk + 1][lane], a1);
      a2 = fmaf(p4.z, Vs[kk + 2][lane], a2);
      a3 = fmaf(p4.w, Vs[kk + 3][lane], a3);
    }
    __syncthreads();
  }
  PART[((size_t)kc * 1280 + row) * 64 + lane] = (a0 + a1) + (a2 + a3);
}

// ---------------------------------------------------------------------------
// pv_reduce: sum 4 partials (fixed order), scale, fused bf16 scatter.
// ---------------------------------------------------------------------------
__global__ __launch_bounds__(256) void pv_reduce(
    const float* __restrict__ PART, const float* __restrict__ IRED,
    const int* __restrict__ TOP, unsigned short* __restrict__ CTX) {
  int gid = blockIdx.x * 256 + threadIdx.x;
  int row = gid >> 6, lane = gid & 63;
  float v = (PART[(size_t)row * 64 + lane] + PART[(size_t)(1280 + row) * 64 + lane]) +
            (PART[(size_t)(2560 + row) * 64 + lane] + PART[(size_t)(3840 + row) * 64 + lane]);
  v *= IRED[row];
  int bh = row / U_;
  int b = bh >> 3, h = bh & 7;
  int orow = TOP[row];
  CTX[((size_t)((b << 11) + orow) << 9) + (h << 6) + lane] = f2bf(v);
}

// ---------------------------------------------------------------------------
// ctx fill (vectorized: 8 bf16 per thread)
// ---------------------------------------------------------------------------
__global__ __launch_bounds__(256) void ctxfill_kernel(
    const unsigned short* __restrict__ VMbf, unsigned short* __restrict__ CTX) {
  int t8 = (blockIdx.x * 256 + threadIdx.x) << 3;
  int c0 = t8 & 511;
  int b = t8 >> 20;
  *(uint4*)(CTX + t8) = *(const uint4*)(VMbf + (b << 9) + c0);
}

// ---------------------------------------------------------------------------
// LayerNorm(512) with residual add from bf16 T; writes fp32 X + bf16 Xbf.
// ---------------------------------------------------------------------------
__global__ __launch_bounds__(256) void ln_kernel(
    const float* __restrict__ Xin, const unsigned short* __restrict__ Tin,
    const float* __restrict__ g, const float* __restrict__ bta,
    float* __restrict__ Xout, unsigned short* __restrict__ Xbf) {
  __shared__ float red[8];
  int r = blockIdx.x, t = threadIdx.x;
  int i0 = (r << 9) + (t << 1);
  float2 v = *(const float2*)(Xin + i0);
  unsigned tu = *(const unsigned*)(Tin + i0);
  v.x += bflo(tu);
  v.y += bfhi(tu);
  float sm = v.x + v.y;
#pragma unroll
  for (int s = 32; s; s >>= 1) sm += __shfl_xor(sm, s);
  int lane = t & 63, w = t >> 6;
  if (lane == 0) red[w] = sm;
  __syncthreads();
  float mean = (red[0] + red[1] + red[2] + red[3]) * (1.0f / 512.0f);
  float d0 = v.x - mean, d1 = v.y - mean;
  float sq = d0 * d0 + d1 * d1;
#pragma unroll
  for (int s = 32; s; s >>= 1) sq += __shfl_xor(sq, s);
  if (lane == 0) red[4 + w] = sq;
  __syncthreads();
  float var = (red[4] + red[5] + red[6] + red[7]) * (1.0f / 512.0f);
  float rstd = rsqrtf(var + EPS_);
  float2 gv = *(const float2*)(g + (t << 1));
  float2 bv = *(const float2*)(bta + (t << 1));
  float o0 = d0 * rstd * gv.x + bv.x;
  float o1 = d1 * rstd * gv.y + bv.y;
  *(float2*)(Xout + i0) = make_float2(o0, o1);
  *(unsigned*)(Xbf + i0) = (unsigned)f2bf(o0) | ((unsigned)f2bf(o1) << 16);
}

// ---------------------------------------------------------------------------
// out = softmax(LN(x; lnf) @ W_out + b_out); lnf fused. One wave per row,
// lane handles dims {lane, lane+64, ..., lane+448}.
// ---------------------------------------------------------------------------
__global__ __launch_bounds__(256) void out_kernel(
    const float* __restrict__ X, const float* __restrict__ lg,
    const float* __restrict__ lb, const float* __restrict__ Wout,
    const float* __restrict__ bout, float* __restrict__ out) {
  int w = threadIdx.x >> 6, lane = threadIdx.x & 63;
  int r = blockIdx.x * 4 + w;
  float xv[8];
  float sm = 0.f;
#pragma unroll
  for (int j = 0; j < 8; ++j) {
    xv[j] = X[(r << 9) + lane + (j << 6)];
    sm += xv[j];
  }
#pragma unroll
  for (int s = 32; s; s >>= 1) sm += __shfl_xor(sm, s);
  float mean = sm * (1.0f / 512.0f);
  float sq = 0.f;
#pragma unroll
  for (int j = 0; j < 8; ++j) {
    float d = xv[j] - mean;
    sq += d * d;
  }
#pragma unroll
  for (int s = 32; s; s >>= 1) sq += __shfl_xor(sq, s);
  float rstd = rsqrtf(sq * (1.0f / 512.0f) + EPS_);
  float p0 = 0.f, p1 = 0.f, p2 = 0.f;
#pragma unroll
  for (int j = 0; j < 8; ++j) {
    int d = lane + (j << 6);
    float xn = (xv[j] - mean) * rstd * lg[d] + lb[d];
    p0 = fmaf(xn, Wout[d * 3 + 0], p0);
    p1 = fmaf(xn, Wout[d * 3 + 1], p1);
    p2 = fmaf(xn, Wout[d * 3 + 2], p2);
  }
#pragma unroll
  for (int s = 32; s; s >>= 1) {
    p0 += __shfl_xor(p0, s);
    p1 += __shfl_xor(p1, s);
    p2 += __shfl_xor(p2, s);
  }
  if (lane == 0) {
    p0 += bout[0]; p1 += bout[1]; p2 += bout[2];
    float m = fmaxf(p0, fmaxf(p1, p2));
    float e0 = __expf(p0 - m), e1 = __expf(p1 - m), e2 = __expf(p2 - m);
    float z = 1.0f / (e0 + e1 + e2);
    out[r * 3 + 0] = e0 * z;
    out[r * 3 + 1] = e1 * z;
    out[r * 3 + 2] = e2 * z;
  }
}

// ---------------------------------------------------------------------------
extern "C" void kernel_launch(void* const* d_in, const int* in_sizes, int n_in,
                              void* d_out, int out_size, void* d_ws, size_t ws_size,
                              hipStream_t stream) {
  const float* DNAs  = (const float*)d_in[0];
  const float* W_pre = (const float*)d_in[1];
  const float* b_pre = (const float*)d_in[2];
  const float* Wq    = (const float*)d_in[3];
  const float* bq    = (const float*)d_in[4];
  const float* Wk    = (const float*)d_in[5];
  const float* bk    = (const float*)d_in[6];
  const float* Wv    = (const float*)d_in[7];
  const float* bv    = (const float*)d_in[8];
  const float* Wo    = (const float*)d_in[9];
  const float* bo    = (const float*)d_in[10];
  const float* ln1_g = (const float*)d_in[11];
  const float* ln1_b = (const float*)d_in[12];
  const float* W1    = (const float*)d_in[13];
  const float* b1    = (const float*)d_in[14];
  const float* W2    = (const float*)d_in[15];
  const float* b2    = (const float*)d_in[16];
  const float* ln2_g = (const float*)d_in[17];
  const float* ln2_b = (const float*)d_in[18];
  const float* lnf_g = (const float*)d_in[19];
  const float* lnf_b = (const float*)d_in[20];
  const float* W_out = (const float*)d_in[21];
  const float* b_out = (const float*)d_in[22];
  const int*   sidx  = (const int*)d_in[23];
  float* out = (float*)d_out;

  float* ws = (float*)d_ws;
  float*          X     = ws;                                   // 4194304 f
  unsigned short* Xbf   = (unsigned short*)(ws + 4194304);      // 2097152 f
  unsigned short* QKVbf = (unsigned short*)(ws + 6291456);      // 3 x 2097152 f
  unsigned short* Qbf   = QKVbf;
  unsigned short* Kbf   = QKVbf + 4194304;
  unsigned short* Vbf   = QKVbf + 8388608;
  unsigned short* Tbf   = (unsigned short*)(ws + 12582912);     // 2097152 f
  float*          PART  = ws + 12582912;                        // 327680 f (pre-Tbf)
  float*          IRED  = ws + 12910592;                        // 1280 f
  float*          S     = ws + 14680064;                        // 2621440 f (pre-HBbf)
  unsigned short* HBbf  = (unsigned short*)(ws + 14680064);     // 8388608 f
  unsigned short* CTXbf = (unsigned short*)(ws + 23068672);     // 2097152 f
  unsigned short* WT    = (unsigned short*)(ws + 25165824);     // 4718592 f
  float*          Mb    = ws + 29884416;                        // 65536 f
  float*          VM    = ws + 29949952;                        // 2048 f
  int*            TOP   = (int*)(ws + 29952000);                // 1280 i
  unsigned short* VMbf  = (unsigned short*)(ws + 29953280);     // 512 f
  unsigned short* WTqkvo = WT;
  unsigned short* WT1    = WT + 3145728;
  unsigned short* WT2    = WT + 6291456;
  (void)in_sizes; (void)n_in; (void)out_size; (void)ws_size;

  wtrans<<<dim3(16, 16, 12), 256, 0, stream>>>(Wq, Wk, Wv, Wo, WTqkvo, 512, 512, 262144);
  wtrans<<<dim3(64, 16, 3), 256, 0, stream>>>(W1, nullptr, nullptr, nullptr, WT1, 512, 2048, 1048576);
  wtrans<<<dim3(16, 64, 3), 256, 0, stream>>>(W2, nullptr, nullptr, nullptr, WT2, 2048, 512, 1048576);

  pre_kernel<<<16384, 256, 0, stream>>>(DNAs, W_pre, b_pre, X, Xbf);

  for (int i = 0; i < E_; ++i) {
    const int bOff = i * DM_;
    mgemm<1, true, false, 128><<<dim3(256, 1, 3), 256, 0, stream>>>(
        Xbf, WTqkvo + (size_t)i * 262144, bq + bOff, bk + bOff, bv + bOff,
        QKVbf, R_, DM_, DM_);

    qk_m_kernel<<<2048, 256, 0, stream>>>(Qbf, Kbf, sidx, Mb);
    topk_kernel<<<32, 256, 0, stream>>>(Mb, TOP);
    vmean_kernel<<<32, 256, 0, stream>>>(Vbf, VM, VMbf);
    attn_score<<<dim3(16, 32), 256, 0, stream>>>(Qbf, Kbf, TOP, S);
    ctxfill_kernel<<<2048, 256, 0, stream>>>(VMbf, CTXbf);
    attn_pv_part<<<640, 512, 0, stream>>>(S, Vbf, PART, IRED);
    pv_reduce<<<320, 256, 0, stream>>>(PART, IRED, TOP, CTXbf);

    mgemm<3, false, true, 64><<<512, 256, 0, stream>>>(
        CTXbf, WTqkvo + (size_t)(9 + i) * 262144, bo + bOff, nullptr, nullptr,
        Tbf, R_, DM_, DM_);
    ln_kernel<<<8192, 256, 0, stream>>>(X, Tbf, ln1_g + bOff, ln1_b + bOff, X, Xbf);

    mgemm<2, false, false, 128><<<1024, 256, 0, stream>>>(
        Xbf, WT1 + (size_t)i * 1048576, b1 + i * DFF_, nullptr, nullptr,
        HBbf, R_, DFF_, DM_);
    mgemm<3, false, true, 64><<<512, 256, 0, stream>>>(
        HBbf, WT2 + (size_t)i * 1048576, b2 + bOff, nullptr, nullptr,
        Tbf, R_, DM_, DFF_);
    ln_kernel<<<8192, 256, 0, stream>>>(X, Tbf, ln2_g + bOff, ln2_b + bOff, X, Xbf);
  }

  out_kernel<<<2048, 256, 0, stream>>>(X, lnf_g, lnf_b, W_out, b_out, out);
}

// Round 17
// 660.324 us; speedup vs baseline: 1.3145x; 1.0049x over previous
//
#include <hip/hip_runtime.h>
#include <math.h>

#define B_   4
#define L_   2048
#define DM_  512
#define H_   8
#define DK_  64
#define DFF_ 2048
#define E_   3
#define U_   40
#define R_   8192
#define SCALE_ 0.125f
#define EPS_ 1e-5f

typedef __bf16 bf16x8 __attribute__((ext_vector_type(8)));
typedef float f32x4 __attribute__((ext_vector_type(4)));

__device__ inline unsigned short f2bf(float x) {
  unsigned int u = __float_as_uint(x);
  unsigned int r = (u + 0x7fffu + ((u >> 16) & 1u)) >> 16;
  return (unsigned short)r;
}
__device__ inline float bflo(unsigned u) { return __uint_as_float(u << 16); }
__device__ inline float bfhi(unsigned u) { return __uint_as_float(u & 0xffff0000u); }
__device__ inline float bf1(unsigned short u) { return __uint_as_float((unsigned)u << 16); }

// ---------------------------------------------------------------------------
// Weight transpose fp32 [R][C] -> bf16 [C][R].
// ---------------------------------------------------------------------------
__global__ __launch_bounds__(256) void wtrans(
    const float* __restrict__ s0, const float* __restrict__ s1,
    const float* __restrict__ s2, const float* __restrict__ s3,
    unsigned short* __restrict__ dst, int R, int C, int permat) {
  __shared__ float tile[32][33];
  int z = blockIdx.z;
  int which = z / 3, e = z % 3;
  const float* src = (which == 0 ? s0 : which == 1 ? s1 : which == 2 ? s2 : s3);
  src += (size_t)e * permat;
  unsigned short* d = dst + (size_t)z * permat;
  int c0 = blockIdx.x << 5, r0 = blockIdx.y << 5;
  int tx = threadIdx.x & 31, ty = threadIdx.x >> 5;
  for (int rr = ty; rr < 32; rr += 8)
    tile[rr][tx] = src[(size_t)(r0 + rr) * C + c0 + tx];
  __syncthreads();
  for (int cc = ty; cc < 32; cc += 8)
    d[(size_t)(c0 + cc) * R + r0 + tx] = f2bf(tile[tx][cc]);
}

// ---------------------------------------------------------------------------
// x = DNAs @ W_pre + b_pre ; writes fp32 X and bf16 Xbf
// ---------------------------------------------------------------------------
__global__ __launch_bounds__(256) void pre_kernel(
    const float* __restrict__ DNAs, const float* __restrict__ Wp,
    const float* __restrict__ bp, float* __restrict__ X,
    unsigned short* __restrict__ Xbf) {
  int t = blockIdx.x * 256 + threadIdx.x;
  int r = t >> 9, d = t & 511;
  float4 dna = *(const float4*)(DNAs + r * 4);
  float v = dna.x * Wp[d] + dna.y * Wp[512 + d] + dna.z * Wp[1024 + d] +
            dna.w * Wp[1536 + d] + bp[d];
  X[t] = v;
  Xbf[t] = f2bf(v);
}

// ---------------------------------------------------------------------------
// bf16 MFMA GEMM, 256x128 tile, 512 threads (8 waves, 4x2), BK=64,
// XOR-swizzled LDS, XCD affinity (m-tile = id&31, 32 tiles -> id%8==m%8).
// For multi-block/CU shapes (QKV, FFN1). OUT: 1 bf16 QKV remap; 2 bf16+ReLU.
// ---------------------------------------------------------------------------
template <int OUT, bool QKVZ>
__global__ __launch_bounds__(512, 4) void mgemm512(
    const unsigned short* __restrict__ A, const unsigned short* __restrict__ BT,
    const float* __restrict__ bias0, const float* __restrict__ bias1,
    const float* __restrict__ bias2, unsigned short* __restrict__ Cb,
    int M, int N, int K) {
  __shared__ unsigned short As[256 * 64];
  __shared__ unsigned short Bs[128 * 64];
  const int t = threadIdx.x, l = t & 63, w = t >> 6;
  const int id = blockIdx.x;
  const int m0 = (id & 31) << 8;
  const int n0 = (id >> 5) << 7;
  const int wm = w >> 1, wn = w & 1;
  const float* bias = bias0;
  if (QKVZ) {
    int z = blockIdx.z;
    BT += (size_t)z * 3 * 262144;
    bias = (z == 0 ? bias0 : z == 1 ? bias1 : bias2);
    Cb += (size_t)z * 4194304;
  }
  f32x4 acc[4][4] = {};

  const int srow = l >> 3;
  const int gslot = (l & 7) ^ srow;

  for (int k0 = 0; k0 < K; k0 += 64) {
#pragma unroll
    for (int j = 0; j < 4; ++j) {                   // A: 32 chunks / 8 waves
      int c = (w << 2) + j;
      int row = (c << 3) + srow;
      const unsigned short* ga = A + (size_t)(m0 + row) * K + k0 + gslot * 8;
      __builtin_amdgcn_global_load_lds(
          (const __attribute__((address_space(1))) void*)ga,
          (__attribute__((address_space(3))) void*)(As + (c << 9)), 16, 0, 0);
    }
#pragma unroll
    for (int j = 0; j < 2; ++j) {                   // B: 16 chunks / 8 waves
      int cb = (w << 1) + j;
      int brow = (cb << 3) + srow;
      const unsigned short* gb = BT + (size_t)(n0 + brow) * K + k0 + gslot * 8;
      __builtin_amdgcn_global_load_lds(
          (const __attribute__((address_space(1))) void*)gb,
          (__attribute__((address_space(3))) void*)(Bs + (cb << 9)), 16, 0, 0);
    }
    __syncthreads();
#pragma unroll
    for (int ks = 0; ks < 2; ++ks) {
      bf16x8 af[4], bg[4];
      int slot = (ks << 2) + (l >> 4);
#pragma unroll
      for (int i = 0; i < 4; ++i) {
        int ar = (wm << 6) + (i << 4) + (l & 15);
        af[i] = *(const bf16x8*)(As + ar * 64 + (slot ^ (ar & 7)) * 8);
        int br = (wn << 6) + (i << 4) + (l & 15);
        bg[i] = *(const bf16x8*)(Bs + br * 64 + (slot ^ (br & 7)) * 8);
      }
#pragma unroll
      for (int i = 0; i < 4; ++i)
#pragma unroll
        for (int j = 0; j < 4; ++j)
          acc[i][j] = __builtin_amdgcn_mfma_f32_16x16x32_bf16(af[i], bg[j],
                                                              acc[i][j], 0, 0, 0);
    }
    __syncthreads();
  }

#pragma unroll
  for (int i = 0; i < 4; ++i) {
    int rbase = m0 + (wm << 6) + (i << 4) + ((l >> 4) << 2);
#pragma unroll
    for (int j = 0; j < 4; ++j) {
      int col = n0 + (wn << 6) + (j << 4) + (l & 15);
      float bv = bias[col];
#pragma unroll
      for (int r = 0; r < 4; ++r) {
        int row = rbase + r;
        float v = acc[i][j][r] + bv;
        if (OUT == 2) {
          v = fmaxf(v, 0.f);
          Cb[(size_t)row * N + col] = f2bf(v);
        } else {
          int b = row >> 11, ll = row & 2047, h = col >> 6, d = col & 63;
          Cb[((size_t)(((b << 3) + h) << 11) + ll) * 64 + d] = f2bf(v);
        }
      }
    }
  }
}

// ---------------------------------------------------------------------------
// bf16 MFMA GEMM (m97 structure, 128xBN tile, 256 thr, DBUF). BN=64 doubles
// block count for 1-block/CU shapes (Wo, FFN2). OUT: 3 = bf16 [M,N].
// ---------------------------------------------------------------------------
template <int OUT, bool DBUF, int BN>
__global__ __launch_bounds__(256) void mgemm(
    const unsigned short* __restrict__ A, const unsigned short* __restrict__ BT,
    const float* __restrict__ bias0, unsigned short* __restrict__ Cb,
    int M, int N, int K) {
  constexpr int NFRAG = BN / 32;
  constexpr int ASZ = 128 * 64, BSZ = BN * 64;
  __shared__ unsigned short As[(DBUF ? 2 : 1) * ASZ];
  __shared__ unsigned short Bs[(DBUF ? 2 : 1) * BSZ];
  const int t = threadIdx.x, l = t & 63, w = t >> 6;
  const int id = blockIdx.x;
  const int m0 = (id & 63) << 7;
  const int n0 = (id >> 6) * BN;
  const int wm = w >> 1, wn = w & 1;
  const float* bias = bias0;
  f32x4 acc[4][NFRAG] = {};

  const int srow = l >> 3;
  const int gslot = (l & 7) ^ srow;

  auto stage = [&](int buf, int k0) {
#pragma unroll
    for (int j = 0; j < 4; ++j) {
      int c = (w << 2) + j;
      int row = (c << 3) + srow;
      const unsigned short* ga = A + (size_t)(m0 + row) * K + k0 + gslot * 8;
      __builtin_amdgcn_global_load_lds(
          (const __attribute__((address_space(1))) void*)ga,
          (__attribute__((address_space(3))) void*)(As + buf * ASZ + (c << 9)), 16, 0, 0);
      if (BN == 128 || j < 2) {
        int cb = (BN == 128) ? c : ((w << 1) + j);
        int brow = (cb << 3) + srow;
        const unsigned short* gb = BT + (size_t)(n0 + brow) * K + k0 + gslot * 8;
        __builtin_amdgcn_global_load_lds(
            (const __attribute__((address_space(1))) void*)gb,
            (__attribute__((address_space(3))) void*)(Bs + buf * BSZ + (cb << 9)), 16, 0, 0);
      }
    }
  };
  auto compute = [&](int buf) {
#pragma unroll
    for (int ks = 0; ks < 2; ++ks) {
      bf16x8 af[4], bg[NFRAG];
      int slot = (ks << 2) + (l >> 4);
#pragma unroll
      for (int i = 0; i < 4; ++i) {
        int ar = (wm << 6) + (i << 4) + (l & 15);
        af[i] = *(const bf16x8*)(As + buf * ASZ + ar * 64 + (slot ^ (ar & 7)) * 8);
      }
#pragma unroll
      for (int j = 0; j < NFRAG; ++j) {
        int br = wn * (BN >> 1) + (j << 4) + (l & 15);
        bg[j] = *(const bf16x8*)(Bs + buf * BSZ + br * 64 + (slot ^ (br & 7)) * 8);
      }
#pragma unroll
      for (int i = 0; i < 4; ++i)
#pragma unroll
        for (int j = 0; j < NFRAG; ++j)
          acc[i][j] = __builtin_amdgcn_mfma_f32_16x16x32_bf16(af[i], bg[j],
                                                              acc[i][j], 0, 0, 0);
    }
  };

  if (DBUF) {
    int nk = K >> 6, cur = 0;
    stage(0, 0);
    __syncthreads();
    for (int s = 0; s < nk; ++s) {
      if (s + 1 < nk) stage(cur ^ 1, (s + 1) << 6);
      compute(cur);
      __syncthreads();
      cur ^= 1;
    }
  } else {
    for (int k0 = 0; k0 < K; k0 += 64) {
      stage(0, k0);
      __syncthreads();
      compute(0);
      __syncthreads();
    }
  }

#pragma unroll
  for (int i = 0; i < 4; ++i) {
    int rbase = m0 + (wm << 6) + (i << 4) + ((l >> 4) << 2);
#pragma unroll
    for (int j = 0; j < NFRAG; ++j) {
      int col = n0 + wn * (BN >> 1) + (j << 4) + (l & 15);
      float bv = bias[col];
#pragma unroll
      for (int r = 0; r < 4; ++r) {
        int row = rbase + r;
        float v = acc[i][j][r] + bv;
        Cb[(size_t)row * N + col] = f2bf(v);
      }
    }
  }
}

// ---------------------------------------------------------------------------
// Sampled-score M on bf16 Q/K: 8 q/wave, 8 lanes/q, ONE uint4 load per row.
// ---------------------------------------------------------------------------
__global__ __launch_bounds__(256) void qk_m_kernel(
    const unsigned short* __restrict__ Q, const unsigned short* __restrict__ K,
    const int* __restrict__ sidx, float* __restrict__ Mout) {
  int t = threadIdx.x;
  int wave = t >> 6, lane = t & 63;
  int grp = lane >> 3, sub = lane & 7;
  int bh = blockIdx.x & 31;
  int j = blockIdx.x >> 5;
  int item = (bh << 11) + (j << 5) + wave * 8 + grp;
  int l = item & 2047;
  uint4 qv = *(const uint4*)(Q + ((size_t)item << 6) + (sub << 3));
  float qf[8] = {bflo(qv.x), bfhi(qv.x), bflo(qv.y), bfhi(qv.y),
                 bflo(qv.z), bfhi(qv.z), bflo(qv.w), bfhi(qv.w)};
  const unsigned short* Kb = K + (((size_t)bh << 11) << 6) + (sub << 3);
  const int* sp = sidx + l * U_;
  float mx = -INFINITY, sm = 0.f;
#pragma unroll 8
  for (int u = 0; u < U_; ++u) {
    int kidx = sp[u];
    uint4 kv = *(const uint4*)(Kb + ((size_t)kidx << 6));
    float p = qf[0] * bflo(kv.x);
    p = fmaf(qf[1], bfhi(kv.x), p);
    p = fmaf(qf[2], bflo(kv.y), p);
    p = fmaf(qf[3], bfhi(kv.y), p);
    p = fmaf(qf[4], bflo(kv.z), p);
    p = fmaf(qf[5], bfhi(kv.z), p);
    p = fmaf(qf[6], bflo(kv.w), p);
    p = fmaf(qf[7], bfhi(kv.w), p);
    p += __shfl_xor(p, 1);
    p += __shfl_xor(p, 2);
    p += __shfl_xor(p, 4);
    mx = fmaxf(mx, p);
    sm += p;
  }
  if (sub == 0) Mout[item] = mx - sm * (1.0f / U_);
}

// ---------------------------------------------------------------------------
// Exact top-40 via 4-pass radix select — fully parallel.
// ---------------------------------------------------------------------------
__global__ __launch_bounds__(256) void topk_kernel(
    const float* __restrict__ Mb, int* __restrict__ TOP) {
  __shared__ unsigned vals[2048];
  __shared__ int hist[256];
  __shared__ int suf[256];
  __shared__ unsigned s_prefix;
  __shared__ int s_want, s_cnt, s_run;
  __shared__ int wcnt[4];
  int bh = blockIdx.x, t = threadIdx.x;
  int lane = t & 63, w = t >> 6;
  for (int i = t; i < 2048; i += 256) {
    unsigned u = __float_as_uint(Mb[bh * 2048 + i]);
    vals[i] = (u & 0x80000000u) ? ~u : (u | 0x80000000u);
  }
  if (t == 0) { s_prefix = 0; s_want = U_; s_cnt = 0; s_run = 0; }
  __syncthreads();
#pragma unroll
  for (int shift = 24; shift >= 0; shift -= 8) {
    unsigned pref = s_prefix;
    int want = s_want;
    unsigned hmask = (shift == 24) ? 0u : (0xFFFFFFFFu << (shift + 8));
    hist[t] = 0;
    __syncthreads();
    for (int i = t; i < 2048; i += 256) {
      unsigned v = vals[i];
      if ((v & hmask) == pref) atomicAdd(&hist[(v >> shift) & 255], 1);
    }
    __syncthreads();
    suf[t] = hist[t];
    __syncthreads();
    for (int off = 1; off < 256; off <<= 1) {
      int add = (t + off < 256) ? suf[t + off] : 0;
      __syncthreads();
      suf[t] += add;
      __syncthreads();
    }
    int cgt = (t == 255) ? 0 : suf[t + 1];
    if (suf[t] >= want && cgt < want) {
      s_prefix = pref | ((unsigned)t << shift);
      s_want = want - cgt;
    }
    __syncthreads();
  }
  unsigned T = s_prefix;
  int want_eq = s_want;
  int base = U_ - want_eq;
  for (int i = t; i < 2048; i += 256) {
    if (vals[i] > T) {
      int slot = atomicAdd(&s_cnt, 1);
      TOP[bh * U_ + slot] = i;
    }
  }
  for (int c = 0; c < 8; ++c) {
    int i = (c << 8) + t;
    bool eq = (vals[i] == T);
    unsigned long long m = __ballot(eq);
    if (lane == 0) wcnt[w] = __popcll(m);
    __syncthreads();
    int woff = 0;
    for (int ww = 0; ww < w; ++ww) woff += wcnt[ww];
    if (eq) {
      int rank = s_run + woff + __popcll(m & ((1ull << lane) - 1ull));
      if (rank < want_eq) TOP[bh * U_ + base + rank] = i;
    }
    __syncthreads();
    if (t == 0) s_run += wcnt[0] + wcnt[1] + wcnt[2] + wcnt[3];
    __syncthreads();
  }
}

// ---------------------------------------------------------------------------
// vmean[bh,d] = mean over L of V[bh,l,d] (bf16 V); also bf16 copy.
// ---------------------------------------------------------------------------
__global__ __launch_bounds__(256) void vmean_kernel(
    const unsigned short* __restrict__ V, float* __restrict__ VM,
    unsigned short* __restrict__ VMbf) {
  __shared__ float p[4][64];
  int bh = blockIdx.x;
  int d = threadIdx.x & 63, c = threadIdx.x >> 6;
  const unsigned short* Vb = V + (((size_t)bh << 11) + c * 512) * 64;
  float s = 0.f;
  for (int l = 0; l < 512; ++l) s += bf1(Vb[l * 64 + d]);
  p[c][d] = s;
  __syncthreads();
  if (threadIdx.x < 64) {
    float m = (p[0][d] + p[1][d] + p[2][d] + p[3][d]) * (1.0f / 2048.0f);
    VM[bh * 64 + d] = m;
    VMbf[bh * 64 + d] = f2bf(m);
  }
}

// ---------------------------------------------------------------------------
// S[bh,u,k] = scale * dot(Q[top[bh,u]], K[bh,k]) — bf16 inputs, fp32 LDS.
// ---------------------------------------------------------------------------
__global__ __launch_bounds__(256) void attn_score(
    const unsigned short* __restrict__ Q, const unsigned short* __restrict__ K,
    const int* __restrict__ TOP, float* __restrict__ S) {
  __shared__ float Ks[128 * 65];
  __shared__ float Qs[40 * 64];
  int bh = blockIdx.y, k0 = blockIdx.x << 7;
  int t = threadIdx.x;
  const unsigned short* Kbase = K + (((size_t)bh << 11) << 6);
  for (int i = t; i < 4096; i += 256) {
    int k = i >> 5, dp = i & 31;
    unsigned u = *(const unsigned*)(Kbase + ((size_t)(k0 + k) << 6) + (dp << 1));
    Ks[k * 65 + (dp << 1)] = bflo(u);
    Ks[k * 65 + (dp << 1) + 1] = bfhi(u);
  }
  for (int i = t; i < 1280; i += 256) {
    int uq = i >> 5, dp = i & 31;
    int row = TOP[bh * U_ + uq];
    unsigned u = *(const unsigned*)(Q + ((((size_t)bh << 11) + row) << 6) + (dp << 1));
    Qs[uq * 64 + (dp << 1)] = bflo(u);
    Qs[uq * 64 + (dp << 1) + 1] = bfhi(u);
  }
  __syncthreads();
  int kk = t & 127, ug = (t >> 7) * 20;
  const float* kp = Ks + kk * 65;
  for (int u = ug; u < ug + 20; ++u) {
    const float* qp = Qs + u * 64;
    float s = 0.f;
#pragma unroll 8
    for (int d = 0; d < 64; ++d) s = fmaf(qp[d], kp[d], s);
    S[((size_t)bh * U_ + u) * 2048 + k0 + kk] = s * SCALE_;
  }
}

// ---------------------------------------------------------------------------
// attn_pv_part: K-split PV (4 chunks), bf16 V staged->fp32 LDS. grid 640.
// ---------------------------------------------------------------------------
__global__ __launch_bounds__(512) void attn_pv_part(
    const float* __restrict__ S, const unsigned short* __restrict__ V,
    float* __restrict__ PART, float* __restrict__ IRED) {
  __shared__ float Vs[128][64];
  __shared__ float ps[8][128];
  __shared__ float mred[8];
  int id = blockIdx.x;
  int bh = id & 31, sub = id >> 5;
  int ug = sub >> 2, kc = sub & 3;
  int t = threadIdx.x, lane = t & 63, w = t >> 6;
  int rowbase = bh * U_ + ug * 8;
  int row = rowbase + w;

  const float* Sr = S + (size_t)row * 2048;
  float mx = -INFINITY;
  for (int j = 0; j < 32; ++j) mx = fmaxf(mx, Sr[j * 64 + lane]);
#pragma unroll
  for (int s = 32; s; s >>= 1) mx = fmaxf(mx, __shfl_xor(mx, s));
  float sm = 0.f;
  for (int j = 0; j < 32; ++j) sm += __expf(Sr[j * 64 + lane] - mx);
#pragma unroll
  for (int s = 32; s; s >>= 1) sm += __shfl_xor(sm, s);
  if (lane == 0) {
    mred[w] = mx;
    if (kc == 0) IRED[row] = 1.0f / sm;
  }
  __syncthreads();

  const unsigned short* Vb = V + (((size_t)bh << 11) << 6);
  float a0 = 0.f, a1 = 0.f, a2 = 0.f, a3 = 0.f;
  for (int c = kc * 4; c < kc * 4 + 4; ++c) {
    int k0 = c << 7;
#pragma unroll
    for (int i = 0; i < 8; ++i) {
      int pe = t + i * 512;
      int k = pe >> 5, dp = pe & 31;
      unsigned u = *(const unsigned*)(Vb + ((size_t)(k0 + k) << 6) + (dp << 1));
      Vs[k][(dp << 1)] = bflo(u);
      Vs[k][(dp << 1) + 1] = bfhi(u);
    }
#pragma unroll
    for (int i = 0; i < 2; ++i) {
      int e = t + i * 512;
      int r = e >> 7, kk = e & 127;
      ps[r][kk] = __expf(S[(size_t)(rowbase + r) * 2048 + k0 + kk] - mred[r]);
    }
    __syncthreads();
    const float* p = ps[w];
#pragma unroll 4
    for (int kk = 0; kk < 128; kk += 4) {
      float4 p4 = *(const float4*)(p + kk);
      a0 = fmaf(p4.x, Vs[kk + 0][lane], a0);
      a1 = fmaf(p4.y, Vs[kk + 1][lane], a1);
      a2 = fmaf(p4.z, Vs[kk + 2][lane], a2);
      a3 = fmaf(p4.w, Vs[kk + 3][lane], a3);
    }
    __syncthreads();
  }
  PART[((size_t)kc * 1280 + row) * 64 + lane] = (a0 + a1) + (a2 + a3);
}

// ---------------------------------------------------------------------------
// pv_reduce: sum 4 partials (fixed order), scale, fused bf16 scatter.
// ---------------------------------------------------------------------------
__global__ __launch_bounds__(256) void pv_reduce(
    const float* __restrict__ PART, const float* __restrict__ IRED,
    const int* __restrict__ TOP, unsigned short* __restrict__ CTX) {
  int gid = blockIdx.x * 256 + threadIdx.x;
  int row = gid >> 6, lane = gid & 63;
  float v = (PART[(size_t)row * 64 + lane] + PART[(size_t)(1280 + row) * 64 + lane]) +
            (PART[(size_t)(2560 + row) * 64 + lane] + PART[(size_t)(3840 + row) * 64 + lane]);
  v *= IRED[row];
  int bh = row / U_;
  int b = bh >> 3, h = bh & 7;
  int orow = TOP[row];
  CTX[((size_t)((b << 11) + orow) << 9) + (h << 6) + lane] = f2bf(v);
}

// ---------------------------------------------------------------------------
// ctx fill (vectorized: 8 bf16 per thread)
// ---------------------------------------------------------------------------
__global__ __launch_bounds__(256) void ctxfill_kernel(
    const unsigned short* __restrict__ VMbf, unsigned short* __restrict__ CTX) {
  int t8 = (blockIdx.x * 256 + threadIdx.x) << 3;
  int c0 = t8 & 511;
  int b = t8 >> 20;
  *(uint4*)(CTX + t8) = *(const uint4*)(VMbf + (b << 9) + c0);
}

// ---------------------------------------------------------------------------
// LayerNorm(512) with residual add from bf16 T; writes fp32 X + bf16 Xbf.
// ---------------------------------------------------------------------------
__global__ __launch_bounds__(256) void ln_kernel(
    const float* __restrict__ Xin, const unsigned short* __restrict__ Tin,
    const float* __restrict__ g, const float* __restrict__ bta,
    float* __restrict__ Xout, unsigned short* __restrict__ Xbf) {
  __shared__ float red[8];
  int r = blockIdx.x, t = threadIdx.x;
  int i0 = (r << 9) + (t << 1);
  float2 v = *(const float2*)(Xin + i0);
  unsigned tu = *(const unsigned*)(Tin + i0);
  v.x += bflo(tu);
  v.y += bfhi(tu);
  float sm = v.x + v.y;
#pragma unroll
  for (int s = 32; s; s >>= 1) sm += __shfl_xor(sm, s);
  int lane = t & 63, w = t >> 6;
  if (lane == 0) red[w] = sm;
  __syncthreads();
  float mean = (red[0] + red[1] + red[2] + red[3]) * (1.0f / 512.0f);
  float d0 = v.x - mean, d1 = v.y - mean;
  float sq = d0 * d0 + d1 * d1;
#pragma unroll
  for (int s = 32; s; s >>= 1) sq += __shfl_xor(sq, s);
  if (lane == 0) red[4 + w] = sq;
  __syncthreads();
  float var = (red[4] + red[5] + red[6] + red[7]) * (1.0f / 512.0f);
  float rstd = rsqrtf(var + EPS_);
  float2 gv = *(const float2*)(g + (t << 1));
  float2 bv = *(const float2*)(bta + (t << 1));
  float o0 = d0 * rstd * gv.x + bv.x;
  float o1 = d1 * rstd * gv.y + bv.y;
  *(float2*)(Xout + i0) = make_float2(o0, o1);
  *(unsigned*)(Xbf + i0) = (unsigned)f2bf(o0) | ((unsigned)f2bf(o1) << 16);
}

// ---------------------------------------------------------------------------
// out = softmax(LN(x; lnf) @ W_out + b_out); lnf fused. One wave per row.
// ---------------------------------------------------------------------------
__global__ __launch_bounds__(256) void out_kernel(
    const float* __restrict__ X, const float* __restrict__ lg,
    const float* __restrict__ lb, const float* __restrict__ Wout,
    const float* __restrict__ bout, float* __restrict__ out) {
  int w = threadIdx.x >> 6, lane = threadIdx.x & 63;
  int r = blockIdx.x * 4 + w;
  float xv[8];
  float sm = 0.f;
#pragma unroll
  for (int j = 0; j < 8; ++j) {
    xv[j] = X[(r << 9) + lane + (j << 6)];
    sm += xv[j];
  }
#pragma unroll
  for (int s = 32; s; s >>= 1) sm += __shfl_xor(sm, s);
  float mean = sm * (1.0f / 512.0f);
  float sq = 0.f;
#pragma unroll
  for (int j = 0; j < 8; ++j) {
    float d = xv[j] - mean;
    sq += d * d;
  }
#pragma unroll
  for (int s = 32; s; s >>= 1) sq += __shfl_xor(sq, s);
  float rstd = rsqrtf(sq * (1.0f / 512.0f) + EPS_);
  float p0 = 0.f, p1 = 0.f, p2 = 0.f;
#pragma unroll
  for (int j = 0; j < 8; ++j) {
    int d = lane + (j << 6);
    float xn = (xv[j] - mean) * rstd * lg[d] + lb[d];
    p0 = fmaf(xn, Wout[d * 3 + 0], p0);
    p1 = fmaf(xn, Wout[d * 3 + 1], p1);
    p2 = fmaf(xn, Wout[d * 3 + 2], p2);
  }
#pragma unroll
  for (int s = 32; s; s >>= 1) {
    p0 += __shfl_xor(p0, s);
    p1 += __shfl_xor(p1, s);
    p2 += __shfl_xor(p2, s);
  }
  if (lane == 0) {
    p0 += bout[0]; p1 += bout[1]; p2 += bout[2];
    float m = fmaxf(p0, fmaxf(p1, p2));
    float e0 = __expf(p0 - m), e1 = __expf(p1 - m), e2 = __expf(p2 - m);
    float z = 1.0f / (e0 + e1 + e2);
    out[r * 3 + 0] = e0 * z;
    out[r * 3 + 1] = e1 * z;
    out[r * 3 + 2] = e2 * z;
  }
}

// ---------------------------------------------------------------------------
extern "C" void kernel_launch(void* const* d_in, const int* in_sizes, int n_in,
                              void* d_out, int out_size, void* d_ws, size_t ws_size,
                              hipStream_t stream) {
  const float* DNAs  = (const float*)d_in[0];
  const float* W_pre = (const float*)d_in[1];
  const float* b_pre = (const float*)d_in[2];
  const float* Wq    = (const float*)d_in[3];
  const float* bq    = (const float*)d_in[4];
  const float* Wk    = (const float*)d_in[5];
  const float* bk    = (const float*)d_in[6];
  const float* Wv    = (const float*)d_in[7];
  const float* bv    = (const float*)d_in[8];
  const float* Wo    = (const float*)d_in[9];
  const float* bo    = (const float*)d_in[10];
  const float* ln1_g = (const float*)d_in[11];
  const float* ln1_b = (const float*)d_in[12];
  const float* W1    = (const float*)d_in[13];
  const float* b1    = (const float*)d_in[14];
  const float* W2    = (const float*)d_in[15];
  const float* b2    = (const float*)d_in[16];
  const float* ln2_g = (const float*)d_in[17];
  const float* ln2_b = (const float*)d_in[18];
  const float* lnf_g = (const float*)d_in[19];
  const float* lnf_b = (const float*)d_in[20];
  const float* W_out = (const float*)d_in[21];
  const float* b_out = (const float*)d_in[22];
  const int*   sidx  = (const int*)d_in[23];
  float* out = (float*)d_out;

  float* ws = (float*)d_ws;
  float*          X     = ws;
  unsigned short* Xbf   = (unsigned short*)(ws + 4194304);
  unsigned short* QKVbf = (unsigned short*)(ws + 6291456);
  unsigned short* Qbf   = QKVbf;
  unsigned short* Kbf   = QKVbf + 4194304;
  unsigned short* Vbf   = QKVbf + 8388608;
  unsigned short* Tbf   = (unsigned short*)(ws + 12582912);
  float*          PART  = ws + 12582912;
  float*          IRED  = ws + 12910592;
  float*          S     = ws + 14680064;
  unsigned short* HBbf  = (unsigned short*)(ws + 14680064);
  unsigned short* CTXbf = (unsigned short*)(ws + 23068672);
  unsigned short* WT    = (unsigned short*)(ws + 25165824);
  float*          Mb    = ws + 29884416;
  float*          VM    = ws + 29949952;
  int*            TOP   = (int*)(ws + 29952000);
  unsigned short* VMbf  = (unsigned short*)(ws + 29953280);
  unsigned short* WTqkvo = WT;
  unsigned short* WT1    = WT + 3145728;
  unsigned short* WT2    = WT + 6291456;
  (void)in_sizes; (void)n_in; (void)out_size; (void)ws_size;

  wtrans<<<dim3(16, 16, 12), 256, 0, stream>>>(Wq, Wk, Wv, Wo, WTqkvo, 512, 512, 262144);
  wtrans<<<dim3(64, 16, 3), 256, 0, stream>>>(W1, nullptr, nullptr, nullptr, WT1, 512, 2048, 1048576);
  wtrans<<<dim3(16, 64, 3), 256, 0, stream>>>(W2, nullptr, nullptr, nullptr, WT2, 2048, 512, 1048576);

  pre_kernel<<<16384, 256, 0, stream>>>(DNAs, W_pre, b_pre, X, Xbf);

  for (int i = 0; i < E_; ++i) {
    const int bOff = i * DM_;
    mgemm512<1, true><<<dim3(128, 1, 3), 512, 0, stream>>>(
        Xbf, WTqkvo + (size_t)i * 262144, bq + bOff, bk + bOff, bv + bOff,
        QKVbf, R_, DM_, DM_);

    qk_m_kernel<<<2048, 256, 0, stream>>>(Qbf, Kbf, sidx, Mb);
    topk_kernel<<<32, 256, 0, stream>>>(Mb, TOP);
    vmean_kernel<<<32, 256, 0, stream>>>(Vbf, VM, VMbf);
    attn_score<<<dim3(16, 32), 256, 0, stream>>>(Qbf, Kbf, TOP, S);
    ctxfill_kernel<<<2048, 256, 0, stream>>>(VMbf, CTXbf);
    attn_pv_part<<<640, 512, 0, stream>>>(S, Vbf, PART, IRED);
    pv_reduce<<<320, 256, 0, stream>>>(PART, IRED, TOP, CTXbf);

    mgemm<3, true, 64><<<512, 256, 0, stream>>>(
        CTXbf, WTqkvo + (size_t)(9 + i) * 262144, bo + bOff, Tbf, R_, DM_, DM_);
    ln_kernel<<<8192, 256, 0, stream>>>(X, Tbf, ln1_g + bOff, ln1_b + bOff, X, Xbf);

    mgemm512<2, false><<<512, 512, 0, stream>>>(
        Xbf, WT1 + (size_t)i * 1048576, b1 + i * DFF_, nullptr, nullptr,
        HBbf, R_, DFF_, DM_);
    mgemm<3, true, 64><<<512, 256, 0, stream>>>(
        HBbf, WT2 + (size_t)i * 1048576, b2 + bOff, Tbf, R_, DM_, DFF_);
    ln_kernel<<<8192, 256, 0, stream>>>(X, Tbf, ln2_g + bOff, ln2_b + bOff, X, Xbf);
  }

  out_kernel<<<2048, 256, 0, stream>>>(X, lnf_g, lnf_b, W_out, b_out, out);
}

// Round 18
// 643.804 us; speedup vs baseline: 1.3482x; 1.0257x over previous
//
#include <hip/hip_runtime.h>
#include <math.h>

#define B_   4
#define L_   2048
#define DM_  512
#define H_   8
#define DK_  64
#define DFF_ 2048
#define E_   3
#define U_   40
#define R_   8192
#define SCALE_ 0.125f
#define EPS_ 1e-5f

typedef __bf16 bf16x8 __attribute__((ext_vector_type(8)));
typedef float f32x4 __attribute__((ext_vector_type(4)));

__device__ inline unsigned short f2bf(float x) {
  unsigned int u = __float_as_uint(x);
  unsigned int r = (u + 0x7fffu + ((u >> 16) & 1u)) >> 16;
  return (unsigned short)r;
}
__device__ inline float bflo(unsigned u) { return __uint_as_float(u << 16); }
__device__ inline float bfhi(unsigned u) { return __uint_as_float(u & 0xffff0000u); }
__device__ inline float bf1(unsigned short u) { return __uint_as_float((unsigned)u << 16); }

// ---------------------------------------------------------------------------
// Weight transpose fp32 [R][C] -> bf16 [C][R].
// ---------------------------------------------------------------------------
__global__ __launch_bounds__(256) void wtrans(
    const float* __restrict__ s0, const float* __restrict__ s1,
    const float* __restrict__ s2, const float* __restrict__ s3,
    unsigned short* __restrict__ dst, int R, int C, int permat) {
  __shared__ float tile[32][33];
  int z = blockIdx.z;
  int which = z / 3, e = z % 3;
  const float* src = (which == 0 ? s0 : which == 1 ? s1 : which == 2 ? s2 : s3);
  src += (size_t)e * permat;
  unsigned short* d = dst + (size_t)z * permat;
  int c0 = blockIdx.x << 5, r0 = blockIdx.y << 5;
  int tx = threadIdx.x & 31, ty = threadIdx.x >> 5;
  for (int rr = ty; rr < 32; rr += 8)
    tile[rr][tx] = src[(size_t)(r0 + rr) * C + c0 + tx];
  __syncthreads();
  for (int cc = ty; cc < 32; cc += 8)
    d[(size_t)(c0 + cc) * R + r0 + tx] = f2bf(tile[tx][cc]);
}

// ---------------------------------------------------------------------------
// x = DNAs @ W_pre + b_pre ; writes fp32 X and bf16 Xbf
// ---------------------------------------------------------------------------
__global__ __launch_bounds__(256) void pre_kernel(
    const float* __restrict__ DNAs, const float* __restrict__ Wp,
    const float* __restrict__ bp, float* __restrict__ X,
    unsigned short* __restrict__ Xbf) {
  int t = blockIdx.x * 256 + threadIdx.x;
  int r = t >> 9, d = t & 511;
  float4 dna = *(const float4*)(DNAs + r * 4);
  float v = dna.x * Wp[d] + dna.y * Wp[512 + d] + dna.z * Wp[1024 + d] +
            dna.w * Wp[1536 + d] + bp[d];
  X[t] = v;
  Xbf[t] = f2bf(v);
}

// ---------------------------------------------------------------------------
// bf16 MFMA GEMM, 256x128 tile, 512 threads (8 waves, 4x2), BK=64,
// XOR-swizzled LDS, XCD affinity. OUT: 1 bf16 QKV remap; 2 bf16+ReLU.
// ---------------------------------------------------------------------------
template <int OUT, bool QKVZ>
__global__ __launch_bounds__(512, 4) void mgemm512(
    const unsigned short* __restrict__ A, const unsigned short* __restrict__ BT,
    const float* __restrict__ bias0, const float* __restrict__ bias1,
    const float* __restrict__ bias2, unsigned short* __restrict__ Cb,
    int M, int N, int K) {
  __shared__ unsigned short As[256 * 64];
  __shared__ unsigned short Bs[128 * 64];
  const int t = threadIdx.x, l = t & 63, w = t >> 6;
  const int id = blockIdx.x;
  const int m0 = (id & 31) << 8;
  const int n0 = (id >> 5) << 7;
  const int wm = w >> 1, wn = w & 1;
  const float* bias = bias0;
  if (QKVZ) {
    int z = blockIdx.z;
    BT += (size_t)z * 3 * 262144;
    bias = (z == 0 ? bias0 : z == 1 ? bias1 : bias2);
    Cb += (size_t)z * 4194304;
  }
  f32x4 acc[4][4] = {};

  const int srow = l >> 3;
  const int gslot = (l & 7) ^ srow;

  for (int k0 = 0; k0 < K; k0 += 64) {
#pragma unroll
    for (int j = 0; j < 4; ++j) {
      int c = (w << 2) + j;
      int row = (c << 3) + srow;
      const unsigned short* ga = A + (size_t)(m0 + row) * K + k0 + gslot * 8;
      __builtin_amdgcn_global_load_lds(
          (const __attribute__((address_space(1))) void*)ga,
          (__attribute__((address_space(3))) void*)(As + (c << 9)), 16, 0, 0);
    }
#pragma unroll
    for (int j = 0; j < 2; ++j) {
      int cb = (w << 1) + j;
      int brow = (cb << 3) + srow;
      const unsigned short* gb = BT + (size_t)(n0 + brow) * K + k0 + gslot * 8;
      __builtin_amdgcn_global_load_lds(
          (const __attribute__((address_space(1))) void*)gb,
          (__attribute__((address_space(3))) void*)(Bs + (cb << 9)), 16, 0, 0);
    }
    __syncthreads();
#pragma unroll
    for (int ks = 0; ks < 2; ++ks) {
      bf16x8 af[4], bg[4];
      int slot = (ks << 2) + (l >> 4);
#pragma unroll
      for (int i = 0; i < 4; ++i) {
        int ar = (wm << 6) + (i << 4) + (l & 15);
        af[i] = *(const bf16x8*)(As + ar * 64 + (slot ^ (ar & 7)) * 8);
        int br = (wn << 6) + (i << 4) + (l & 15);
        bg[i] = *(const bf16x8*)(Bs + br * 64 + (slot ^ (br & 7)) * 8);
      }
#pragma unroll
      for (int i = 0; i < 4; ++i)
#pragma unroll
        for (int j = 0; j < 4; ++j)
          acc[i][j] = __builtin_amdgcn_mfma_f32_16x16x32_bf16(af[i], bg[j],
                                                              acc[i][j], 0, 0, 0);
    }
    __syncthreads();
  }

#pragma unroll
  for (int i = 0; i < 4; ++i) {
    int rbase = m0 + (wm << 6) + (i << 4) + ((l >> 4) << 2);
#pragma unroll
    for (int j = 0; j < 4; ++j) {
      int col = n0 + (wn << 6) + (j << 4) + (l & 15);
      float bv = bias[col];
#pragma unroll
      for (int r = 0; r < 4; ++r) {
        int row = rbase + r;
        float v = acc[i][j][r] + bv;
        if (OUT == 2) {
          v = fmaxf(v, 0.f);
          Cb[(size_t)row * N + col] = f2bf(v);
        } else {
          int b = row >> 11, ll = row & 2047, h = col >> 6, d = col & 63;
          Cb[((size_t)(((b << 3) + h) << 11) + ll) * 64 + d] = f2bf(v);
        }
      }
    }
  }
}

// ---------------------------------------------------------------------------
// bf16 MFMA GEMM (128xBN tile, 256 thr, DBUF). BN=64 for Wo/FFN2. OUT: 3.
// ---------------------------------------------------------------------------
template <int OUT, bool DBUF, int BN>
__global__ __launch_bounds__(256) void mgemm(
    const unsigned short* __restrict__ A, const unsigned short* __restrict__ BT,
    const float* __restrict__ bias0, unsigned short* __restrict__ Cb,
    int M, int N, int K) {
  constexpr int NFRAG = BN / 32;
  constexpr int ASZ = 128 * 64, BSZ = BN * 64;
  __shared__ unsigned short As[(DBUF ? 2 : 1) * ASZ];
  __shared__ unsigned short Bs[(DBUF ? 2 : 1) * BSZ];
  const int t = threadIdx.x, l = t & 63, w = t >> 6;
  const int id = blockIdx.x;
  const int m0 = (id & 63) << 7;
  const int n0 = (id >> 6) * BN;
  const int wm = w >> 1, wn = w & 1;
  const float* bias = bias0;
  f32x4 acc[4][NFRAG] = {};

  const int srow = l >> 3;
  const int gslot = (l & 7) ^ srow;

  auto stage = [&](int buf, int k0) {
#pragma unroll
    for (int j = 0; j < 4; ++j) {
      int c = (w << 2) + j;
      int row = (c << 3) + srow;
      const unsigned short* ga = A + (size_t)(m0 + row) * K + k0 + gslot * 8;
      __builtin_amdgcn_global_load_lds(
          (const __attribute__((address_space(1))) void*)ga,
          (__attribute__((address_space(3))) void*)(As + buf * ASZ + (c << 9)), 16, 0, 0);
      if (BN == 128 || j < 2) {
        int cb = (BN == 128) ? c : ((w << 1) + j);
        int brow = (cb << 3) + srow;
        const unsigned short* gb = BT + (size_t)(n0 + brow) * K + k0 + gslot * 8;
        __builtin_amdgcn_global_load_lds(
            (const __attribute__((address_space(1))) void*)gb,
            (__attribute__((address_space(3))) void*)(Bs + buf * BSZ + (cb << 9)), 16, 0, 0);
      }
    }
  };
  auto compute = [&](int buf) {
#pragma unroll
    for (int ks = 0; ks < 2; ++ks) {
      bf16x8 af[4], bg[NFRAG];
      int slot = (ks << 2) + (l >> 4);
#pragma unroll
      for (int i = 0; i < 4; ++i) {
        int ar = (wm << 6) + (i << 4) + (l & 15);
        af[i] = *(const bf16x8*)(As + buf * ASZ + ar * 64 + (slot ^ (ar & 7)) * 8);
      }
#pragma unroll
      for (int j = 0; j < NFRAG; ++j) {
        int br = wn * (BN >> 1) + (j << 4) + (l & 15);
        bg[j] = *(const bf16x8*)(Bs + buf * BSZ + br * 64 + (slot ^ (br & 7)) * 8);
      }
#pragma unroll
      for (int i = 0; i < 4; ++i)
#pragma unroll
        for (int j = 0; j < NFRAG; ++j)
          acc[i][j] = __builtin_amdgcn_mfma_f32_16x16x32_bf16(af[i], bg[j],
                                                              acc[i][j], 0, 0, 0);
    }
  };

  if (DBUF) {
    int nk = K >> 6, cur = 0;
    stage(0, 0);
    __syncthreads();
    for (int s = 0; s < nk; ++s) {
      if (s + 1 < nk) stage(cur ^ 1, (s + 1) << 6);
      compute(cur);
      __syncthreads();
      cur ^= 1;
    }
  } else {
    for (int k0 = 0; k0 < K; k0 += 64) {
      stage(0, k0);
      __syncthreads();
      compute(0);
      __syncthreads();
    }
  }

#pragma unroll
  for (int i = 0; i < 4; ++i) {
    int rbase = m0 + (wm << 6) + (i << 4) + ((l >> 4) << 2);
#pragma unroll
    for (int j = 0; j < NFRAG; ++j) {
      int col = n0 + wn * (BN >> 1) + (j << 4) + (l & 15);
      float bv = bias[col];
#pragma unroll
      for (int r = 0; r < 4; ++r) {
        int row = rbase + r;
        float v = acc[i][j][r] + bv;
        Cb[(size_t)row * N + col] = f2bf(v);
      }
    }
  }
}

// ---------------------------------------------------------------------------
// MERGED: qk_m (blocks 0..2047) ∥ vmean (blocks 2048..2079).
// Both depend only on QKV; vmean hides under qk_m.
// ---------------------------------------------------------------------------
__global__ __launch_bounds__(256) void qkm_vmean_kernel(
    const unsigned short* __restrict__ Q, const unsigned short* __restrict__ K,
    const int* __restrict__ sidx, float* __restrict__ Mout,
    const unsigned short* __restrict__ V, float* __restrict__ VM,
    unsigned short* __restrict__ VMbf) {
  __shared__ float p[4][64];
  int bid = blockIdx.x;
  int t = threadIdx.x;
  if (bid < 2048) {
    // ---- qk_m: 8 queries/wave, 8 lanes/query, XCD-affinity (bh = bid&31)
    int wave = t >> 6, lane = t & 63;
    int grp = lane >> 3, sub = lane & 7;
    int bh = bid & 31;
    int j = bid >> 5;
    int item = (bh << 11) + (j << 5) + wave * 8 + grp;
    int l = item & 2047;
    uint4 qv = *(const uint4*)(Q + ((size_t)item << 6) + (sub << 3));
    float qf[8] = {bflo(qv.x), bfhi(qv.x), bflo(qv.y), bfhi(qv.y),
                   bflo(qv.z), bfhi(qv.z), bflo(qv.w), bfhi(qv.w)};
    const unsigned short* Kb = K + (((size_t)bh << 11) << 6) + (sub << 3);
    const int* sp = sidx + l * U_;
    float mx = -INFINITY, sm = 0.f;
#pragma unroll 8
    for (int u = 0; u < U_; ++u) {
      int kidx = sp[u];
      uint4 kv = *(const uint4*)(Kb + ((size_t)kidx << 6));
      float pd = qf[0] * bflo(kv.x);
      pd = fmaf(qf[1], bfhi(kv.x), pd);
      pd = fmaf(qf[2], bflo(kv.y), pd);
      pd = fmaf(qf[3], bfhi(kv.y), pd);
      pd = fmaf(qf[4], bflo(kv.z), pd);
      pd = fmaf(qf[5], bfhi(kv.z), pd);
      pd = fmaf(qf[6], bflo(kv.w), pd);
      pd = fmaf(qf[7], bfhi(kv.w), pd);
      pd += __shfl_xor(pd, 1);
      pd += __shfl_xor(pd, 2);
      pd += __shfl_xor(pd, 4);
      mx = fmaxf(mx, pd);
      sm += pd;
    }
    if (sub == 0) Mout[item] = mx - sm * (1.0f / U_);
  } else {
    // ---- vmean: bh = bid - 2048
    int bh = bid - 2048;
    int d = t & 63, c = t >> 6;
    const unsigned short* Vb = V + (((size_t)bh << 11) + c * 512) * 64;
    float s = 0.f;
    for (int l = 0; l < 512; ++l) s += bf1(Vb[l * 64 + d]);
    p[c][d] = s;
    __syncthreads();
    if (t < 64) {
      float m = (p[0][d] + p[1][d] + p[2][d] + p[3][d]) * (1.0f / 2048.0f);
      VM[bh * 64 + d] = m;
      VMbf[bh * 64 + d] = f2bf(m);
    }
  }
}

// ---------------------------------------------------------------------------
// MERGED: ctxfill (blocks 0..2047) ∥ topk radix select (blocks 2048..2079).
// ctxfill needs vmean; topk needs Mb — both from the previous dispatch.
// ---------------------------------------------------------------------------
__global__ __launch_bounds__(256) void ctxfill_topk_kernel(
    const unsigned short* __restrict__ VMbf, unsigned short* __restrict__ CTX,
    const float* __restrict__ Mb, int* __restrict__ TOP) {
  __shared__ unsigned vals[2048];
  __shared__ int hist[256];
  __shared__ int suf[256];
  __shared__ unsigned s_prefix;
  __shared__ int s_want, s_cnt, s_run;
  __shared__ int wcnt[4];
  int bid = blockIdx.x, t = threadIdx.x;
  if (bid < 2048) {
    int t8 = (bid * 256 + t) << 3;
    int c0 = t8 & 511;
    int b = t8 >> 20;
    *(uint4*)(CTX + t8) = *(const uint4*)(VMbf + (b << 9) + c0);
    return;
  }
  int bh = bid - 2048;
  int lane = t & 63, w = t >> 6;
  for (int i = t; i < 2048; i += 256) {
    unsigned u = __float_as_uint(Mb[bh * 2048 + i]);
    vals[i] = (u & 0x80000000u) ? ~u : (u | 0x80000000u);
  }
  if (t == 0) { s_prefix = 0; s_want = U_; s_cnt = 0; s_run = 0; }
  __syncthreads();
#pragma unroll
  for (int shift = 24; shift >= 0; shift -= 8) {
    unsigned pref = s_prefix;
    int want = s_want;
    unsigned hmask = (shift == 24) ? 0u : (0xFFFFFFFFu << (shift + 8));
    hist[t] = 0;
    __syncthreads();
    for (int i = t; i < 2048; i += 256) {
      unsigned v = vals[i];
      if ((v & hmask) == pref) atomicAdd(&hist[(v >> shift) & 255], 1);
    }
    __syncthreads();
    suf[t] = hist[t];
    __syncthreads();
    for (int off = 1; off < 256; off <<= 1) {
      int add = (t + off < 256) ? suf[t + off] : 0;
      __syncthreads();
      suf[t] += add;
      __syncthreads();
    }
    int cgt = (t == 255) ? 0 : suf[t + 1];
    if (suf[t] >= want && cgt < want) {
      s_prefix = pref | ((unsigned)t << shift);
      s_want = want - cgt;
    }
    __syncthreads();
  }
  unsigned T = s_prefix;
  int want_eq = s_want;
  int base = U_ - want_eq;
  for (int i = t; i < 2048; i += 256) {
    if (vals[i] > T) {
      int slot = atomicAdd(&s_cnt, 1);
      TOP[bh * U_ + slot] = i;
    }
  }
  for (int c = 0; c < 8; ++c) {
    int i = (c << 8) + t;
    bool eq = (vals[i] == T);
    unsigned long long m = __ballot(eq);
    if (lane == 0) wcnt[w] = __popcll(m);
    __syncthreads();
    int woff = 0;
    for (int ww = 0; ww < w; ++ww) woff += wcnt[ww];
    if (eq) {
      int rank = s_run + woff + __popcll(m & ((1ull << lane) - 1ull));
      if (rank < want_eq) TOP[bh * U_ + base + rank] = i;
    }
    __syncthreads();
    if (t == 0) s_run += wcnt[0] + wcnt[1] + wcnt[2] + wcnt[3];
    __syncthreads();
  }
}

// ---------------------------------------------------------------------------
// S[bh,u,k] = scale * dot(Q[top[bh,u]], K[bh,k]) — bf16 inputs, fp32 LDS.
// ---------------------------------------------------------------------------
__global__ __launch_bounds__(256) void attn_score(
    const unsigned short* __restrict__ Q, const unsigned short* __restrict__ K,
    const int* __restrict__ TOP, float* __restrict__ S) {
  __shared__ float Ks[128 * 65];
  __shared__ float Qs[40 * 64];
  int bh = blockIdx.y, k0 = blockIdx.x << 7;
  int t = threadIdx.x;
  const unsigned short* Kbase = K + (((size_t)bh << 11) << 6);
  for (int i = t; i < 4096; i += 256) {
    int k = i >> 5, dp = i & 31;
    unsigned u = *(const unsigned*)(Kbase + ((size_t)(k0 + k) << 6) + (dp << 1));
    Ks[k * 65 + (dp << 1)] = bflo(u);
    Ks[k * 65 + (dp << 1) + 1] = bfhi(u);
  }
  for (int i = t; i < 1280; i += 256) {
    int uq = i >> 5, dp = i & 31;
    int row = TOP[bh * U_ + uq];
    unsigned u = *(const unsigned*)(Q + ((((size_t)bh << 11) + row) << 6) + (dp << 1));
    Qs[uq * 64 + (dp << 1)] = bflo(u);
    Qs[uq * 64 + (dp << 1) + 1] = bfhi(u);
  }
  __syncthreads();
  int kk = t & 127, ug = (t >> 7) * 20;
  const float* kp = Ks + kk * 65;
  for (int u = ug; u < ug + 20; ++u) {
    const float* qp = Qs + u * 64;
    float s = 0.f;
#pragma unroll 8
    for (int d = 0; d < 64; ++d) s = fmaf(qp[d], kp[d], s);
    S[((size_t)bh * U_ + u) * 2048 + k0 + kk] = s * SCALE_;
  }
}

// ---------------------------------------------------------------------------
// attn_pv_part: K-split PV (4 chunks), bf16 V staged->fp32 LDS. grid 640.
// ---------------------------------------------------------------------------
__global__ __launch_bounds__(512) void attn_pv_part(
    const float* __restrict__ S, const unsigned short* __restrict__ V,
    float* __restrict__ PART, float* __restrict__ IRED) {
  __shared__ float Vs[128][64];
  __shared__ float ps[8][128];
  __shared__ float mred[8];
  int id = blockIdx.x;
  int bh = id & 31, sub = id >> 5;
  int ug = sub >> 2, kc = sub & 3;
  int t = threadIdx.x, lane = t & 63, w = t >> 6;
  int rowbase = bh * U_ + ug * 8;
  int row = rowbase + w;

  const float* Sr = S + (size_t)row * 2048;
  float mx = -INFINITY;
  for (int j = 0; j < 32; ++j) mx = fmaxf(mx, Sr[j * 64 + lane]);
#pragma unroll
  for (int s = 32; s; s >>= 1) mx = fmaxf(mx, __shfl_xor(mx, s));
  float sm = 0.f;
  for (int j = 0; j < 32; ++j) sm += __expf(Sr[j * 64 + lane] - mx);
#pragma unroll
  for (int s = 32; s; s >>= 1) sm += __shfl_xor(sm, s);
  if (lane == 0) {
    mred[w] = mx;
    if (kc == 0) IRED[row] = 1.0f / sm;
  }
  __syncthreads();

  const unsigned short* Vb = V + (((size_t)bh << 11) << 6);
  float a0 = 0.f, a1 = 0.f, a2 = 0.f, a3 = 0.f;
  for (int c = kc * 4; c < kc * 4 + 4; ++c) {
    int k0 = c << 7;
#pragma unroll
    for (int i = 0; i < 8; ++i) {
      int pe = t + i * 512;
      int k = pe >> 5, dp = pe & 31;
      unsigned u = *(const unsigned*)(Vb + ((size_t)(k0 + k) << 6) + (dp << 1));
      Vs[k][(dp << 1)] = bflo(u);
      Vs[k][(dp << 1) + 1] = bfhi(u);
    }
#pragma unroll
    for (int i = 0; i < 2; ++i) {
      int e = t + i * 512;
      int r = e >> 7, kk = e & 127;
      ps[r][kk] = __expf(S[(size_t)(rowbase + r) * 2048 + k0 + kk] - mred[r]);
    }
    __syncthreads();
    const float* p = ps[w];
#pragma unroll 4
    for (int kk = 0; kk < 128; kk += 4) {
      float4 p4 = *(const float4*)(p + kk);
      a0 = fmaf(p4.x, Vs[kk + 0][lane], a0);
      a1 = fmaf(p4.y, Vs[kk + 1][lane], a1);
      a2 = fmaf(p4.z, Vs[kk + 2][lane], a2);
      a3 = fmaf(p4.w, Vs[kk + 3][lane], a3);
    }
    __syncthreads();
  }
  PART[((size_t)kc * 1280 + row) * 64 + lane] = (a0 + a1) + (a2 + a3);
}

// ---------------------------------------------------------------------------
// pv_reduce: sum 4 partials (fixed order), scale, fused bf16 scatter.
// ---------------------------------------------------------------------------
__global__ __launch_bounds__(256) void pv_reduce(
    const float* __restrict__ PART, const float* __restrict__ IRED,
    const int* __restrict__ TOP, unsigned short* __restrict__ CTX) {
  int gid = blockIdx.x * 256 + threadIdx.x;
  int row = gid >> 6, lane = gid & 63;
  float v = (PART[(size_t)row * 64 + lane] + PART[(size_t)(1280 + row) * 64 + lane]) +
            (PART[(size_t)(2560 + row) * 64 + lane] + PART[(size_t)(3840 + row) * 64 + lane]);
  v *= IRED[row];
  int bh = row / U_;
  int b = bh >> 3, h = bh & 7;
  int orow = TOP[row];
  CTX[((size_t)((b << 11) + orow) << 9) + (h << 6) + lane] = f2bf(v);
}

// ---------------------------------------------------------------------------
// LayerNorm(512) with residual add from bf16 T; writes fp32 X + bf16 Xbf.
// ---------------------------------------------------------------------------
__global__ __launch_bounds__(256) void ln_kernel(
    const float* __restrict__ Xin, const unsigned short* __restrict__ Tin,
    const float* __restrict__ g, const float* __restrict__ bta,
    float* __restrict__ Xout, unsigned short* __restrict__ Xbf) {
  __shared__ float red[8];
  int r = blockIdx.x, t = threadIdx.x;
  int i0 = (r << 9) + (t << 1);
  float2 v = *(const float2*)(Xin + i0);
  unsigned tu = *(const unsigned*)(Tin + i0);
  v.x += bflo(tu);
  v.y += bfhi(tu);
  float sm = v.x + v.y;
#pragma unroll
  for (int s = 32; s; s >>= 1) sm += __shfl_xor(sm, s);
  int lane = t & 63, w = t >> 6;
  if (lane == 0) red[w] = sm;
  __syncthreads();
  float mean = (red[0] + red[1] + red[2] + red[3]) * (1.0f / 512.0f);
  float d0 = v.x - mean, d1 = v.y - mean;
  float sq = d0 * d0 + d1 * d1;
#pragma unroll
  for (int s = 32; s; s >>= 1) sq += __shfl_xor(sq, s);
  if (lane == 0) red[4 + w] = sq;
  __syncthreads();
  float var = (red[4] + red[5] + red[6] + red[7]) * (1.0f / 512.0f);
  float rstd = rsqrtf(var + EPS_);
  float2 gv = *(const float2*)(g + (t << 1));
  float2 bv = *(const float2*)(bta + (t << 1));
  float o0 = d0 * rstd * gv.x + bv.x;
  float o1 = d1 * rstd * gv.y + bv.y;
  *(float2*)(Xout + i0) = make_float2(o0, o1);
  *(unsigned*)(Xbf + i0) = (unsigned)f2bf(o0) | ((unsigned)f2bf(o1) << 16);
}

// ---------------------------------------------------------------------------
// out = softmax(LN(x; lnf) @ W_out + b_out); lnf fused. One wave per row.
// ---------------------------------------------------------------------------
__global__ __launch_bounds__(256) void out_kernel(
    const float* __restrict__ X, const float* __restrict__ lg,
    const float* __restrict__ lb, const float* __restrict__ Wout,
    const float* __restrict__ bout, float* __restrict__ out) {
  int w = threadIdx.x >> 6, lane = threadIdx.x & 63;
  int r = blockIdx.x * 4 + w;
  float xv[8];
  float sm = 0.f;
#pragma unroll
  for (int j = 0; j < 8; ++j) {
    xv[j] = X[(r << 9) + lane + (j << 6)];
    sm += xv[j];
  }
#pragma unroll
  for (int s = 32; s; s >>= 1) sm += __shfl_xor(sm, s);
  float mean = sm * (1.0f / 512.0f);
  float sq = 0.f;
#pragma unroll
  for (int j = 0; j < 8; ++j) {
    float d = xv[j] - mean;
    sq += d * d;
  }
#pragma unroll
  for (int s = 32; s; s >>= 1) sq += __shfl_xor(sq, s);
  float rstd = rsqrtf(sq * (1.0f / 512.0f) + EPS_);
  float p0 = 0.f, p1 = 0.f, p2 = 0.f;
#pragma unroll
  for (int j = 0; j < 8; ++j) {
    int d = lane + (j << 6);
    float xn = (xv[j] - mean) * rstd * lg[d] + lb[d];
    p0 = fmaf(xn, Wout[d * 3 + 0], p0);
    p1 = fmaf(xn, Wout[d * 3 + 1], p1);
    p2 = fmaf(xn, Wout[d * 3 + 2], p2);
  }
#pragma unroll
  for (int s = 32; s; s >>= 1) {
    p0 += __shfl_xor(p0, s);
    p1 += __shfl_xor(p1, s);
    p2 += __shfl_xor(p2, s);
  }
  if (lane == 0) {
    p0 += bout[0]; p1 += bout[1]; p2 += bout[2];
    float m = fmaxf(p0, fmaxf(p1, p2));
    float e0 = __expf(p0 - m), e1 = __expf(p1 - m), e2 = __expf(p2 - m);
    float z = 1.0f / (e0 + e1 + e2);
    out[r * 3 + 0] = e0 * z;
    out[r * 3 + 1] = e1 * z;
    out[r * 3 + 2] = e2 * z;
  }
}

// ---------------------------------------------------------------------------
extern "C" void kernel_launch(void* const* d_in, const int* in_sizes, int n_in,
                              void* d_out, int out_size, void* d_ws, size_t ws_size,
                              hipStream_t stream) {
  const float* DNAs  = (const float*)d_in[0];
  const float* W_pre = (const float*)d_in[1];
  const float* b_pre = (const float*)d_in[2];
  const float* Wq    = (const float*)d_in[3];
  const float* bq    = (const float*)d_in[4];
  const float* Wk    = (const float*)d_in[5];
  const float* bk    = (const float*)d_in[6];
  const float* Wv    = (const float*)d_in[7];
  const float* bv    = (const float*)d_in[8];
  const float* Wo    = (const float*)d_in[9];
  const float* bo    = (const float*)d_in[10];
  const float* ln1_g = (const float*)d_in[11];
  const float* ln1_b = (const float*)d_in[12];
  const float* W1    = (const float*)d_in[13];
  const float* b1    = (const float*)d_in[14];
  const float* W2    = (const float*)d_in[15];
  const float* b2    = (const float*)d_in[16];
  const float* ln2_g = (const float*)d_in[17];
  const float* ln2_b = (const float*)d_in[18];
  const float* lnf_g = (const float*)d_in[19];
  const float* lnf_b = (const float*)d_in[20];
  const float* W_out = (const float*)d_in[21];
  const float* b_out = (const float*)d_in[22];
  const int*   sidx  = (const int*)d_in[23];
  float* out = (float*)d_out;

  float* ws = (float*)d_ws;
  float*          X     = ws;
  unsigned short* Xbf   = (unsigned short*)(ws + 4194304);
  unsigned short* QKVbf = (unsigned short*)(ws + 6291456);
  unsigned short* Qbf   = QKVbf;
  unsigned short* Kbf   = QKVbf + 4194304;
  unsigned short* Vbf   = QKVbf + 8388608;
  unsigned short* Tbf   = (unsigned short*)(ws + 12582912);
  float*          PART  = ws + 12582912;
  float*          IRED  = ws + 12910592;
  float*          S     = ws + 14680064;
  unsigned short* HBbf  = (unsigned short*)(ws + 14680064);
  unsigned short* CTXbf = (unsigned short*)(ws + 23068672);
  unsigned short* WT    = (unsigned short*)(ws + 25165824);
  float*          Mb    = ws + 29884416;
  float*          VM    = ws + 29949952;
  int*            TOP   = (int*)(ws + 29952000);
  unsigned short* VMbf  = (unsigned short*)(ws + 29953280);
  unsigned short* WTqkvo = WT;
  unsigned short* WT1    = WT + 3145728;
  unsigned short* WT2    = WT + 6291456;
  (void)in_sizes; (void)n_in; (void)out_size; (void)ws_size;

  wtrans<<<dim3(16, 16, 12), 256, 0, stream>>>(Wq, Wk, Wv, Wo, WTqkvo, 512, 512, 262144);
  wtrans<<<dim3(64, 16, 3), 256, 0, stream>>>(W1, nullptr, nullptr, nullptr, WT1, 512, 2048, 1048576);
  wtrans<<<dim3(16, 64, 3), 256, 0, stream>>>(W2, nullptr, nullptr, nullptr, WT2, 2048, 512, 1048576);

  pre_kernel<<<16384, 256, 0, stream>>>(DNAs, W_pre, b_pre, X, Xbf);

  for (int i = 0; i < E_; ++i) {
    const int bOff = i * DM_;
    mgemm512<1, true><<<dim3(128, 1, 3), 512, 0, stream>>>(
        Xbf, WTqkvo + (size_t)i * 262144, bq + bOff, bk + bOff, bv + bOff,
        QKVbf, R_, DM_, DM_);

    qkm_vmean_kernel<<<2080, 256, 0, stream>>>(Qbf, Kbf, sidx, Mb, Vbf, VM, VMbf);
    ctxfill_topk_kernel<<<2080, 256, 0, stream>>>(VMbf, CTXbf, Mb, TOP);
    attn_score<<<dim3(16, 32), 256, 0, stream>>>(Qbf, Kbf, TOP, S);
    attn_pv_part<<<640, 512, 0, stream>>>(S, Vbf, PART, IRED);
    pv_reduce<<<320, 256, 0, stream>>>(PART, IRED, TOP, CTXbf);

    mgemm<3, true, 64><<<512, 256, 0, stream>>>(
        CTXbf, WTqkvo + (size_t)(9 + i) * 262144, bo + bOff, Tbf, R_, DM_, DM_);
    ln_kernel<<<8192, 256, 0, stream>>>(X, Tbf, ln1_g + bOff, ln1_b + bOff, X, Xbf);

    mgemm512<2, false><<<512, 512, 0, stream>>>(
        Xbf, WT1 + (size_t)i * 1048576, b1 + i * DFF_, nullptr, nullptr,
        HBbf, R_, DFF_, DM_);
    mgemm<3, true, 64><<<512, 256, 0, stream>>>(
        HBbf, WT2 + (size_t)i * 1048576, b2 + bOff, Tbf, R_, DM_, DFF_);
    ln_kernel<<<8192, 256, 0, stream>>>(X, Tbf, ln2_g + bOff, ln2_b + bOff, X, Xbf);
  }

  out_kernel<<<2048, 256, 0, stream>>>(X, lnf_g, lnf_b, W_out, b_out, out);
}

// Round 19
// 626.837 us; speedup vs baseline: 1.3847x; 1.0271x over previous
//
#include <hip/hip_runtime.h>
#include <math.h>

#define B_   4
#define L_   2048
#define DM_  512
#define H_   8
#define DK_  64
#define DFF_ 2048
#define E_   3
#define U_   40
#define R_   8192
#define SCALE_ 0.125f
#define EPS_ 1e-5f

typedef __bf16 bf16x8 __attribute__((ext_vector_type(8)));
typedef float f32x4 __attribute__((ext_vector_type(4)));

__device__ inline unsigned short f2bf(float x) {
  unsigned int u = __float_as_uint(x);
  unsigned int r = (u + 0x7fffu + ((u >> 16) & 1u)) >> 16;
  return (unsigned short)r;
}
__device__ inline float bflo(unsigned u) { return __uint_as_float(u << 16); }
__device__ inline float bfhi(unsigned u) { return __uint_as_float(u & 0xffff0000u); }
__device__ inline float bf1(unsigned short u) { return __uint_as_float((unsigned)u << 16); }

// ---------------------------------------------------------------------------
// Weight transpose fp32 [R][C] -> bf16 [C][R].
// ---------------------------------------------------------------------------
__global__ __launch_bounds__(256) void wtrans(
    const float* __restrict__ s0, const float* __restrict__ s1,
    const float* __restrict__ s2, const float* __restrict__ s3,
    unsigned short* __restrict__ dst, int R, int C, int permat) {
  __shared__ float tile[32][33];
  int z = blockIdx.z;
  int which = z / 3, e = z % 3;
  const float* src = (which == 0 ? s0 : which == 1 ? s1 : which == 2 ? s2 : s3);
  src += (size_t)e * permat;
  unsigned short* d = dst + (size_t)z * permat;
  int c0 = blockIdx.x << 5, r0 = blockIdx.y << 5;
  int tx = threadIdx.x & 31, ty = threadIdx.x >> 5;
  for (int rr = ty; rr < 32; rr += 8)
    tile[rr][tx] = src[(size_t)(r0 + rr) * C + c0 + tx];
  __syncthreads();
  for (int cc = ty; cc < 32; cc += 8)
    d[(size_t)(c0 + cc) * R + r0 + tx] = f2bf(tile[tx][cc]);
}

// ---------------------------------------------------------------------------
// x = DNAs @ W_pre + b_pre ; residual stream is bf16-only: writes Xbf.
// 2 packed outputs per thread (8192 blocks).
// ---------------------------------------------------------------------------
__global__ __launch_bounds__(256) void pre_kernel(
    const float* __restrict__ DNAs, const float* __restrict__ Wp,
    const float* __restrict__ bp, unsigned short* __restrict__ Xbf) {
  int i = (blockIdx.x * 256 + threadIdx.x) << 1;
  int r = i >> 9, d0 = i & 511;
  float4 dna = *(const float4*)(DNAs + r * 4);
  float v0 = dna.x * Wp[d0] + dna.y * Wp[512 + d0] + dna.z * Wp[1024 + d0] +
             dna.w * Wp[1536 + d0] + bp[d0];
  int d1 = d0 + 1;
  float v1 = dna.x * Wp[d1] + dna.y * Wp[512 + d1] + dna.z * Wp[1024 + d1] +
             dna.w * Wp[1536 + d1] + bp[d1];
  *(unsigned*)(Xbf + i) = (unsigned)f2bf(v0) | ((unsigned)f2bf(v1) << 16);
}

// ---------------------------------------------------------------------------
// bf16 MFMA GEMM, 256x128 tile, 512 threads (8 waves, 4x2), BK=64,
// XOR-swizzled LDS, XCD affinity. OUT: 1 bf16 QKV remap; 2 bf16+ReLU.
// ---------------------------------------------------------------------------
template <int OUT, bool QKVZ>
__global__ __launch_bounds__(512, 4) void mgemm512(
    const unsigned short* __restrict__ A, const unsigned short* __restrict__ BT,
    const float* __restrict__ bias0, const float* __restrict__ bias1,
    const float* __restrict__ bias2, unsigned short* __restrict__ Cb,
    int M, int N, int K) {
  __shared__ unsigned short As[256 * 64];
  __shared__ unsigned short Bs[128 * 64];
  const int t = threadIdx.x, l = t & 63, w = t >> 6;
  const int id = blockIdx.x;
  const int m0 = (id & 31) << 8;
  const int n0 = (id >> 5) << 7;
  const int wm = w >> 1, wn = w & 1;
  const float* bias = bias0;
  if (QKVZ) {
    int z = blockIdx.z;
    BT += (size_t)z * 3 * 262144;
    bias = (z == 0 ? bias0 : z == 1 ? bias1 : bias2);
    Cb += (size_t)z * 4194304;
  }
  f32x4 acc[4][4] = {};

  const int srow = l >> 3;
  const int gslot = (l & 7) ^ srow;

  for (int k0 = 0; k0 < K; k0 += 64) {
#pragma unroll
    for (int j = 0; j < 4; ++j) {
      int c = (w << 2) + j;
      int row = (c << 3) + srow;
      const unsigned short* ga = A + (size_t)(m0 + row) * K + k0 + gslot * 8;
      __builtin_amdgcn_global_load_lds(
          (const __attribute__((address_space(1))) void*)ga,
          (__attribute__((address_space(3))) void*)(As + (c << 9)), 16, 0, 0);
    }
#pragma unroll
    for (int j = 0; j < 2; ++j) {
      int cb = (w << 1) + j;
      int brow = (cb << 3) + srow;
      const unsigned short* gb = BT + (size_t)(n0 + brow) * K + k0 + gslot * 8;
      __builtin_amdgcn_global_load_lds(
          (const __attribute__((address_space(1))) void*)gb,
          (__attribute__((address_space(3))) void*)(Bs + (cb << 9)), 16, 0, 0);
    }
    __syncthreads();
#pragma unroll
    for (int ks = 0; ks < 2; ++ks) {
      bf16x8 af[4], bg[4];
      int slot = (ks << 2) + (l >> 4);
#pragma unroll
      for (int i = 0; i < 4; ++i) {
        int ar = (wm << 6) + (i << 4) + (l & 15);
        af[i] = *(const bf16x8*)(As + ar * 64 + (slot ^ (ar & 7)) * 8);
        int br = (wn << 6) + (i << 4) + (l & 15);
        bg[i] = *(const bf16x8*)(Bs + br * 64 + (slot ^ (br & 7)) * 8);
      }
#pragma unroll
      for (int i = 0; i < 4; ++i)
#pragma unroll
        for (int j = 0; j < 4; ++j)
          acc[i][j] = __builtin_amdgcn_mfma_f32_16x16x32_bf16(af[i], bg[j],
                                                              acc[i][j], 0, 0, 0);
    }
    __syncthreads();
  }

#pragma unroll
  for (int i = 0; i < 4; ++i) {
    int rbase = m0 + (wm << 6) + (i << 4) + ((l >> 4) << 2);
#pragma unroll
    for (int j = 0; j < 4; ++j) {
      int col = n0 + (wn << 6) + (j << 4) + (l & 15);
      float bv = bias[col];
#pragma unroll
      for (int r = 0; r < 4; ++r) {
        int row = rbase + r;
        float v = acc[i][j][r] + bv;
        if (OUT == 2) {
          v = fmaxf(v, 0.f);
          Cb[(size_t)row * N + col] = f2bf(v);
        } else {
          int b = row >> 11, ll = row & 2047, h = col >> 6, d = col & 63;
          Cb[((size_t)(((b << 3) + h) << 11) + ll) * 64 + d] = f2bf(v);
        }
      }
    }
  }
}

// ---------------------------------------------------------------------------
// bf16 MFMA GEMM (128xBN tile, 256 thr, DBUF). BN=64 for Wo/FFN2. OUT: 3.
// ---------------------------------------------------------------------------
template <int OUT, bool DBUF, int BN>
__global__ __launch_bounds__(256) void mgemm(
    const unsigned short* __restrict__ A, const unsigned short* __restrict__ BT,
    const float* __restrict__ bias0, unsigned short* __restrict__ Cb,
    int M, int N, int K) {
  constexpr int NFRAG = BN / 32;
  constexpr int ASZ = 128 * 64, BSZ = BN * 64;
  __shared__ unsigned short As[(DBUF ? 2 : 1) * ASZ];
  __shared__ unsigned short Bs[(DBUF ? 2 : 1) * BSZ];
  const int t = threadIdx.x, l = t & 63, w = t >> 6;
  const int id = blockIdx.x;
  const int m0 = (id & 63) << 7;
  const int n0 = (id >> 6) * BN;
  const int wm = w >> 1, wn = w & 1;
  const float* bias = bias0;
  f32x4 acc[4][NFRAG] = {};

  const int srow = l >> 3;
  const int gslot = (l & 7) ^ srow;

  auto stage = [&](int buf, int k0) {
#pragma unroll
    for (int j = 0; j < 4; ++j) {
      int c = (w << 2) + j;
      int row = (c << 3) + srow;
      const unsigned short* ga = A + (size_t)(m0 + row) * K + k0 + gslot * 8;
      __builtin_amdgcn_global_load_lds(
          (const __attribute__((address_space(1))) void*)ga,
          (__attribute__((address_space(3))) void*)(As + buf * ASZ + (c << 9)), 16, 0, 0);
      if (BN == 128 || j < 2) {
        int cb = (BN == 128) ? c : ((w << 1) + j);
        int brow = (cb << 3) + srow;
        const unsigned short* gb = BT + (size_t)(n0 + brow) * K + k0 + gslot * 8;
        __builtin_amdgcn_global_load_lds(
            (const __attribute__((address_space(1))) void*)gb,
            (__attribute__((address_space(3))) void*)(Bs + buf * BSZ + (cb << 9)), 16, 0, 0);
      }
    }
  };
  auto compute = [&](int buf) {
#pragma unroll
    for (int ks = 0; ks < 2; ++ks) {
      bf16x8 af[4], bg[NFRAG];
      int slot = (ks << 2) + (l >> 4);
#pragma unroll
      for (int i = 0; i < 4; ++i) {
        int ar = (wm << 6) + (i << 4) + (l & 15);
        af[i] = *(const bf16x8*)(As + buf * ASZ + ar * 64 + (slot ^ (ar & 7)) * 8);
      }
#pragma unroll
      for (int j = 0; j < NFRAG; ++j) {
        int br = wn * (BN >> 1) + (j << 4) + (l & 15);
        bg[j] = *(const bf16x8*)(Bs + buf * BSZ + br * 64 + (slot ^ (br & 7)) * 8);
      }
#pragma unroll
      for (int i = 0; i < 4; ++i)
#pragma unroll
        for (int j = 0; j < NFRAG; ++j)
          acc[i][j] = __builtin_amdgcn_mfma_f32_16x16x32_bf16(af[i], bg[j],
                                                              acc[i][j], 0, 0, 0);
    }
  };

  if (DBUF) {
    int nk = K >> 6, cur = 0;
    stage(0, 0);
    __syncthreads();
    for (int s = 0; s < nk; ++s) {
      if (s + 1 < nk) stage(cur ^ 1, (s + 1) << 6);
      compute(cur);
      __syncthreads();
      cur ^= 1;
    }
  } else {
    for (int k0 = 0; k0 < K; k0 += 64) {
      stage(0, k0);
      __syncthreads();
      compute(0);
      __syncthreads();
    }
  }

#pragma unroll
  for (int i = 0; i < 4; ++i) {
    int rbase = m0 + (wm << 6) + (i << 4) + ((l >> 4) << 2);
#pragma unroll
    for (int j = 0; j < NFRAG; ++j) {
      int col = n0 + wn * (BN >> 1) + (j << 4) + (l & 15);
      float bv = bias[col];
#pragma unroll
      for (int r = 0; r < 4; ++r) {
        int row = rbase + r;
        float v = acc[i][j][r] + bv;
        Cb[(size_t)row * N + col] = f2bf(v);
      }
    }
  }
}

// ---------------------------------------------------------------------------
// MERGED: qk_m (blocks 0..2047) ∥ vmean (blocks 2048..2079).
// ---------------------------------------------------------------------------
__global__ __launch_bounds__(256) void qkm_vmean_kernel(
    const unsigned short* __restrict__ Q, const unsigned short* __restrict__ K,
    const int* __restrict__ sidx, float* __restrict__ Mout,
    const unsigned short* __restrict__ V, float* __restrict__ VM,
    unsigned short* __restrict__ VMbf) {
  __shared__ float p[4][64];
  int bid = blockIdx.x;
  int t = threadIdx.x;
  if (bid < 2048) {
    int wave = t >> 6, lane = t & 63;
    int grp = lane >> 3, sub = lane & 7;
    int bh = bid & 31;
    int j = bid >> 5;
    int item = (bh << 11) + (j << 5) + wave * 8 + grp;
    int l = item & 2047;
    uint4 qv = *(const uint4*)(Q + ((size_t)item << 6) + (sub << 3));
    float qf[8] = {bflo(qv.x), bfhi(qv.x), bflo(qv.y), bfhi(qv.y),
                   bflo(qv.z), bfhi(qv.z), bflo(qv.w), bfhi(qv.w)};
    const unsigned short* Kb = K + (((size_t)bh << 11) << 6) + (sub << 3);
    const int* sp = sidx + l * U_;
    float mx = -INFINITY, sm = 0.f;
#pragma unroll 8
    for (int u = 0; u < U_; ++u) {
      int kidx = sp[u];
      uint4 kv = *(const uint4*)(Kb + ((size_t)kidx << 6));
      float pd = qf[0] * bflo(kv.x);
      pd = fmaf(qf[1], bfhi(kv.x), pd);
      pd = fmaf(qf[2], bflo(kv.y), pd);
      pd = fmaf(qf[3], bfhi(kv.y), pd);
      pd = fmaf(qf[4], bflo(kv.z), pd);
      pd = fmaf(qf[5], bfhi(kv.z), pd);
      pd = fmaf(qf[6], bflo(kv.w), pd);
      pd = fmaf(qf[7], bfhi(kv.w), pd);
      pd += __shfl_xor(pd, 1);
      pd += __shfl_xor(pd, 2);
      pd += __shfl_xor(pd, 4);
      mx = fmaxf(mx, pd);
      sm += pd;
    }
    if (sub == 0) Mout[item] = mx - sm * (1.0f / U_);
  } else {
    int bh = bid - 2048;
    int d = t & 63, c = t >> 6;
    const unsigned short* Vb = V + (((size_t)bh << 11) + c * 512) * 64;
    float s = 0.f;
    for (int l = 0; l < 512; ++l) s += bf1(Vb[l * 64 + d]);
    p[c][d] = s;
    __syncthreads();
    if (t < 64) {
      float m = (p[0][d] + p[1][d] + p[2][d] + p[3][d]) * (1.0f / 2048.0f);
      VM[bh * 64 + d] = m;
      VMbf[bh * 64 + d] = f2bf(m);
    }
  }
}

// ---------------------------------------------------------------------------
// MERGED: ctxfill (blocks 0..2047) ∥ topk radix select (blocks 2048..2079).
// ---------------------------------------------------------------------------
__global__ __launch_bounds__(256) void ctxfill_topk_kernel(
    const unsigned short* __restrict__ VMbf, unsigned short* __restrict__ CTX,
    const float* __restrict__ Mb, int* __restrict__ TOP) {
  __shared__ unsigned vals[2048];
  __shared__ int hist[256];
  __shared__ int suf[256];
  __shared__ unsigned s_prefix;
  __shared__ int s_want, s_cnt, s_run;
  __shared__ int wcnt[4];
  int bid = blockIdx.x, t = threadIdx.x;
  if (bid < 2048) {
    int t8 = (bid * 256 + t) << 3;
    int c0 = t8 & 511;
    int b = t8 >> 20;
    *(uint4*)(CTX + t8) = *(const uint4*)(VMbf + (b << 9) + c0);
    return;
  }
  int bh = bid - 2048;
  int lane = t & 63, w = t >> 6;
  for (int i = t; i < 2048; i += 256) {
    unsigned u = __float_as_uint(Mb[bh * 2048 + i]);
    vals[i] = (u & 0x80000000u) ? ~u : (u | 0x80000000u);
  }
  if (t == 0) { s_prefix = 0; s_want = U_; s_cnt = 0; s_run = 0; }
  __syncthreads();
#pragma unroll
  for (int shift = 24; shift >= 0; shift -= 8) {
    unsigned pref = s_prefix;
    int want = s_want;
    unsigned hmask = (shift == 24) ? 0u : (0xFFFFFFFFu << (shift + 8));
    hist[t] = 0;
    __syncthreads();
    for (int i = t; i < 2048; i += 256) {
      unsigned v = vals[i];
      if ((v & hmask) == pref) atomicAdd(&hist[(v >> shift) & 255], 1);
    }
    __syncthreads();
    suf[t] = hist[t];
    __syncthreads();
    for (int off = 1; off < 256; off <<= 1) {
      int add = (t + off < 256) ? suf[t + off] : 0;
      __syncthreads();
      suf[t] += add;
      __syncthreads();
    }
    int cgt = (t == 255) ? 0 : suf[t + 1];
    if (suf[t] >= want && cgt < want) {
      s_prefix = pref | ((unsigned)t << shift);
      s_want = want - cgt;
    }
    __syncthreads();
  }
  unsigned T = s_prefix;
  int want_eq = s_want;
  int base = U_ - want_eq;
  for (int i = t; i < 2048; i += 256) {
    if (vals[i] > T) {
      int slot = atomicAdd(&s_cnt, 1);
      TOP[bh * U_ + slot] = i;
    }
  }
  for (int c = 0; c < 8; ++c) {
    int i = (c << 8) + t;
    bool eq = (vals[i] == T);
    unsigned long long m = __ballot(eq);
    if (lane == 0) wcnt[w] = __popcll(m);
    __syncthreads();
    int woff = 0;
    for (int ww = 0; ww < w; ++ww) woff += wcnt[ww];
    if (eq) {
      int rank = s_run + woff + __popcll(m & ((1ull << lane) - 1ull));
      if (rank < want_eq) TOP[bh * U_ + base + rank] = i;
    }
    __syncthreads();
    if (t == 0) s_run += wcnt[0] + wcnt[1] + wcnt[2] + wcnt[3];
    __syncthreads();
  }
}

// ---------------------------------------------------------------------------
// S[bh,u,k] = scale * dot(Q[top[bh,u]], K[bh,k]) — bf16 inputs, fp32 LDS.
// ---------------------------------------------------------------------------
__global__ __launch_bounds__(256) void attn_score(
    const unsigned short* __restrict__ Q, const unsigned short* __restrict__ K,
    const int* __restrict__ TOP, float* __restrict__ S) {
  __shared__ float Ks[128 * 65];
  __shared__ float Qs[40 * 64];
  int bh = blockIdx.y, k0 = blockIdx.x << 7;
  int t = threadIdx.x;
  const unsigned short* Kbase = K + (((size_t)bh << 11) << 6);
  for (int i = t; i < 4096; i += 256) {
    int k = i >> 5, dp = i & 31;
    unsigned u = *(const unsigned*)(Kbase + ((size_t)(k0 + k) << 6) + (dp << 1));
    Ks[k * 65 + (dp << 1)] = bflo(u);
    Ks[k * 65 + (dp << 1) + 1] = bfhi(u);
  }
  for (int i = t; i < 1280; i += 256) {
    int uq = i >> 5, dp = i & 31;
    int row = TOP[bh * U_ + uq];
    unsigned u = *(const unsigned*)(Q + ((((size_t)bh << 11) + row) << 6) + (dp << 1));
    Qs[uq * 64 + (dp << 1)] = bflo(u);
    Qs[uq * 64 + (dp << 1) + 1] = bfhi(u);
  }
  __syncthreads();
  int kk = t & 127, ug = (t >> 7) * 20;
  const float* kp = Ks + kk * 65;
  for (int u = ug; u < ug + 20; ++u) {
    const float* qp = Qs + u * 64;
    float s = 0.f;
#pragma unroll 8
    for (int d = 0; d < 64; ++d) s = fmaf(qp[d], kp[d], s);
    S[((size_t)bh * U_ + u) * 2048 + k0 + kk] = s * SCALE_;
  }
}

// ---------------------------------------------------------------------------
// attn_pv_part: K-split PV (4 chunks), bf16 V staged->fp32 LDS. grid 640.
// ---------------------------------------------------------------------------
__global__ __launch_bounds__(512) void attn_pv_part(
    const float* __restrict__ S, const unsigned short* __restrict__ V,
    float* __restrict__ PART, float* __restrict__ IRED) {
  __shared__ float Vs[128][64];
  __shared__ float ps[8][128];
  __shared__ float mred[8];
  int id = blockIdx.x;
  int bh = id & 31, sub = id >> 5;
  int ug = sub >> 2, kc = sub & 3;
  int t = threadIdx.x, lane = t & 63, w = t >> 6;
  int rowbase = bh * U_ + ug * 8;
  int row = rowbase + w;

  const float* Sr = S + (size_t)row * 2048;
  float mx = -INFINITY;
  for (int j = 0; j < 32; ++j) mx = fmaxf(mx, Sr[j * 64 + lane]);
#pragma unroll
  for (int s = 32; s; s >>= 1) mx = fmaxf(mx, __shfl_xor(mx, s));
  float sm = 0.f;
  for (int j = 0; j < 32; ++j) sm += __expf(Sr[j * 64 + lane] - mx);
#pragma unroll
  for (int s = 32; s; s >>= 1) sm += __shfl_xor(sm, s);
  if (lane == 0) {
    mred[w] = mx;
    if (kc == 0) IRED[row] = 1.0f / sm;
  }
  __syncthreads();

  const unsigned short* Vb = V + (((size_t)bh << 11) << 6);
  float a0 = 0.f, a1 = 0.f, a2 = 0.f, a3 = 0.f;
  for (int c = kc * 4; c < kc * 4 + 4; ++c) {
    int k0 = c << 7;
#pragma unroll
    for (int i = 0; i < 8; ++i) {
      int pe = t + i * 512;
      int k = pe >> 5, dp = pe & 31;
      unsigned u = *(const unsigned*)(Vb + ((size_t)(k0 + k) << 6) + (dp << 1));
      Vs[k][(dp << 1)] = bflo(u);
      Vs[k][(dp << 1) + 1] = bfhi(u);
    }
#pragma unroll
    for (int i = 0; i < 2; ++i) {
      int e = t + i * 512;
      int r = e >> 7, kk = e & 127;
      ps[r][kk] = __expf(S[(size_t)(rowbase + r) * 2048 + k0 + kk] - mred[r]);
    }
    __syncthreads();
    const float* p = ps[w];
#pragma unroll 4
    for (int kk = 0; kk < 128; kk += 4) {
      float4 p4 = *(const float4*)(p + kk);
      a0 = fmaf(p4.x, Vs[kk + 0][lane], a0);
      a1 = fmaf(p4.y, Vs[kk + 1][lane], a1);
      a2 = fmaf(p4.z, Vs[kk + 2][lane], a2);
      a3 = fmaf(p4.w, Vs[kk + 3][lane], a3);
    }
    __syncthreads();
  }
  PART[((size_t)kc * 1280 + row) * 64 + lane] = (a0 + a1) + (a2 + a3);
}

// ---------------------------------------------------------------------------
// pv_reduce: sum 4 partials (fixed order), scale, fused bf16 scatter.
// ---------------------------------------------------------------------------
__global__ __launch_bounds__(256) void pv_reduce(
    const float* __restrict__ PART, const float* __restrict__ IRED,
    const int* __restrict__ TOP, unsigned short* __restrict__ CTX) {
  int gid = blockIdx.x * 256 + threadIdx.x;
  int row = gid >> 6, lane = gid & 63;
  float v = (PART[(size_t)row * 64 + lane] + PART[(size_t)(1280 + row) * 64 + lane]) +
            (PART[(size_t)(2560 + row) * 64 + lane] + PART[(size_t)(3840 + row) * 64 + lane]);
  v *= IRED[row];
  int bh = row / U_;
  int b = bh >> 3, h = bh & 7;
  int orow = TOP[row];
  CTX[((size_t)((b << 11) + orow) << 9) + (h << 6) + lane] = f2bf(v);
}

// ---------------------------------------------------------------------------
// LayerNorm(512): residual stream in bf16. v = Xbf + Tbf; x = LN(v).
// Reads/writes 24 MB total (was 48 with fp32 X).
// ---------------------------------------------------------------------------
__global__ __launch_bounds__(256) void ln_kernel(
    const unsigned short* __restrict__ Xin, const unsigned short* __restrict__ Tin,
    const float* __restrict__ g, const float* __restrict__ bta,
    unsigned short* __restrict__ Xbf) {
  __shared__ float red[8];
  int r = blockIdx.x, t = threadIdx.x;
  int i0 = (r << 9) + (t << 1);
  unsigned xu = *(const unsigned*)(Xin + i0);
  unsigned tu = *(const unsigned*)(Tin + i0);
  float v0 = bflo(xu) + bflo(tu);
  float v1 = bfhi(xu) + bfhi(tu);
  float sm = v0 + v1;
#pragma unroll
  for (int s = 32; s; s >>= 1) sm += __shfl_xor(sm, s);
  int lane = t & 63, w = t >> 6;
  if (lane == 0) red[w] = sm;
  __syncthreads();
  float mean = (red[0] + red[1] + red[2] + red[3]) * (1.0f / 512.0f);
  float d0 = v0 - mean, d1 = v1 - mean;
  float sq = d0 * d0 + d1 * d1;
#pragma unroll
  for (int s = 32; s; s >>= 1) sq += __shfl_xor(sq, s);
  if (lane == 0) red[4 + w] = sq;
  __syncthreads();
  float var = (red[4] + red[5] + red[6] + red[7]) * (1.0f / 512.0f);
  float rstd = rsqrtf(var + EPS_);
  float2 gv = *(const float2*)(g + (t << 1));
  float2 bv = *(const float2*)(bta + (t << 1));
  float o0 = d0 * rstd * gv.x + bv.x;
  float o1 = d1 * rstd * gv.y + bv.y;
  *(unsigned*)(Xbf + i0) = (unsigned)f2bf(o0) | ((unsigned)f2bf(o1) << 16);
}

// ---------------------------------------------------------------------------
// out = softmax(LN(x; lnf) @ W_out + b_out); x in bf16. One wave per row.
// ---------------------------------------------------------------------------
__global__ __launch_bounds__(256) void out_kernel(
    const unsigned short* __restrict__ X, const float* __restrict__ lg,
    const float* __restrict__ lb, const float* __restrict__ Wout,
    const float* __restrict__ bout, float* __restrict__ out) {
  int w = threadIdx.x >> 6, lane = threadIdx.x & 63;
  int r = blockIdx.x * 4 + w;
  float xv[8];
  float sm = 0.f;
#pragma unroll
  for (int j = 0; j < 8; ++j) {
    xv[j] = bf1(X[(r << 9) + lane + (j << 6)]);
    sm += xv[j];
  }
#pragma unroll
  for (int s = 32; s; s >>= 1) sm += __shfl_xor(sm, s);
  float mean = sm * (1.0f / 512.0f);
  float sq = 0.f;
#pragma unroll
  for (int j = 0; j < 8; ++j) {
    float d = xv[j] - mean;
    sq += d * d;
  }
#pragma unroll
  for (int s = 32; s; s >>= 1) sq += __shfl_xor(sq, s);
  float rstd = rsqrtf(sq * (1.0f / 512.0f) + EPS_);
  float p0 = 0.f, p1 = 0.f, p2 = 0.f;
#pragma unroll
  for (int j = 0; j < 8; ++j) {
    int d = lane + (j << 6);
    float xn = (xv[j] - mean) * rstd * lg[d] + lb[d];
    p0 = fmaf(xn, Wout[d * 3 + 0], p0);
    p1 = fmaf(xn, Wout[d * 3 + 1], p1);
    p2 = fmaf(xn, Wout[d * 3 + 2], p2);
  }
#pragma unroll
  for (int s = 32; s; s >>= 1) {
    p0 += __shfl_xor(p0, s);
    p1 += __shfl_xor(p1, s);
    p2 += __shfl_xor(p2, s);
  }
  if (lane == 0) {
    p0 += bout[0]; p1 += bout[1]; p2 += bout[2];
    float m = fmaxf(p0, fmaxf(p1, p2));
    float e0 = __expf(p0 - m), e1 = __expf(p1 - m), e2 = __expf(p2 - m);
    float z = 1.0f / (e0 + e1 + e2);
    out[r * 3 + 0] = e0 * z;
    out[r * 3 + 1] = e1 * z;
    out[r * 3 + 2] = e2 * z;
  }
}

// ---------------------------------------------------------------------------
extern "C" void kernel_launch(void* const* d_in, const int* in_sizes, int n_in,
                              void* d_out, int out_size, void* d_ws, size_t ws_size,
                              hipStream_t stream) {
  const float* DNAs  = (const float*)d_in[0];
  const float* W_pre = (const float*)d_in[1];
  const float* b_pre = (const float*)d_in[2];
  const float* Wq    = (const float*)d_in[3];
  const float* bq    = (const float*)d_in[4];
  const float* Wk    = (const float*)d_in[5];
  const float* bk    = (const float*)d_in[6];
  const float* Wv    = (const float*)d_in[7];
  const float* bv    = (const float*)d_in[8];
  const float* Wo    = (const float*)d_in[9];
  const float* bo    = (const float*)d_in[10];
  const float* ln1_g = (const float*)d_in[11];
  const float* ln1_b = (const float*)d_in[12];
  const float* W1    = (const float*)d_in[13];
  const float* b1    = (const float*)d_in[14];
  const float* W2    = (const float*)d_in[15];
  const float* b2    = (const float*)d_in[16];
  const float* ln2_g = (const float*)d_in[17];
  const float* ln2_b = (const float*)d_in[18];
  const float* lnf_g = (const float*)d_in[19];
  const float* lnf_b = (const float*)d_in[20];
  const float* W_out = (const float*)d_in[21];
  const float* b_out = (const float*)d_in[22];
  const int*   sidx  = (const int*)d_in[23];
  float* out = (float*)d_out;

  float* ws = (float*)d_ws;
  unsigned short* Xbf   = (unsigned short*)(ws + 4194304);      // residual (bf16)
  unsigned short* QKVbf = (unsigned short*)(ws + 6291456);
  unsigned short* Qbf   = QKVbf;
  unsigned short* Kbf   = QKVbf + 4194304;
  unsigned short* Vbf   = QKVbf + 8388608;
  unsigned short* Tbf   = (unsigned short*)(ws + 12582912);
  float*          PART  = ws;                                   // reuse old X region
  float*          IRED  = ws + 327680;
  float*          S     = ws + 14680064;
  unsigned short* HBbf  = (unsigned short*)(ws + 14680064);
  unsigned short* CTXbf = (unsigned short*)(ws + 23068672);
  unsigned short* WT    = (unsigned short*)(ws + 25165824);
  float*          Mb    = ws + 29884416;
  float*          VM    = ws + 29949952;
  int*            TOP   = (int*)(ws + 29952000);
  unsigned short* VMbf  = (unsigned short*)(ws + 29953280);
  unsigned short* WTqkvo = WT;
  unsigned short* WT1    = WT + 3145728;
  unsigned short* WT2    = WT + 6291456;
  (void)in_sizes; (void)n_in; (void)out_size; (void)ws_size;

  wtrans<<<dim3(16, 16, 12), 256, 0, stream>>>(Wq, Wk, Wv, Wo, WTqkvo, 512, 512, 262144);
  wtrans<<<dim3(64, 16, 3), 256, 0, stream>>>(W1, nullptr, nullptr, nullptr, WT1, 512, 2048, 1048576);
  wtrans<<<dim3(16, 64, 3), 256, 0, stream>>>(W2, nullptr, nullptr, nullptr, WT2, 2048, 512, 1048576);

  pre_kernel<<<8192, 256, 0, stream>>>(DNAs, W_pre, b_pre, Xbf);

  for (int i = 0; i < E_; ++i) {
    const int bOff = i * DM_;
    mgemm512<1, true><<<dim3(128, 1, 3), 512, 0, stream>>>(
        Xbf, WTqkvo + (size_t)i * 262144, bq + bOff, bk + bOff, bv + bOff,
        QKVbf, R_, DM_, DM_);

    qkm_vmean_kernel<<<2080, 256, 0, stream>>>(Qbf, Kbf, sidx, Mb, Vbf, VM, VMbf);
    ctxfill_topk_kernel<<<2080, 256, 0, stream>>>(VMbf, CTXbf, Mb, TOP);
    attn_score<<<dim3(16, 32), 256, 0, stream>>>(Qbf, Kbf, TOP, S);
    attn_pv_part<<<640, 512, 0, stream>>>(S, Vbf, PART, IRED);
    pv_reduce<<<320, 256, 0, stream>>>(PART, IRED, TOP, CTXbf);

    mgemm<3, true, 64><<<512, 256, 0, stream>>>(
        CTXbf, WTqkvo + (size_t)(9 + i) * 262144, bo + bOff, Tbf, R_, DM_, DM_);
    ln_kernel<<<8192, 256, 0, stream>>>(Xbf, Tbf, ln1_g + bOff, ln1_b + bOff, Xbf);

    mgemm512<2, false><<<512, 512, 0, stream>>>(
        Xbf, WT1 + (size_t)i * 1048576, b1 + i * DFF_, nullptr, nullptr,
        HBbf, R_, DFF_, DM_);
    mgemm<3, true, 64><<<512, 256, 0, stream>>>(
        HBbf, WT2 + (size_t)i * 1048576, b2 + bOff, Tbf, R_, DM_, DFF_);
    ln_kernel<<<8192, 256, 0, stream>>>(Xbf, Tbf, ln2_g + bOff, ln2_b + bOff, Xbf);
  }

  out_kernel<<<2048, 256, 0, stream>>>(Xbf, lnf_g, lnf_b, W_out, b_out, out);
}

// Round 20
// 620.981 us; speedup vs baseline: 1.3978x; 1.0094x over previous
//
#include <hip/hip_runtime.h>
#include <math.h>

#define B_   4
#define L_   2048
#define DM_  512
#define H_   8
#define DK_  64
#define DFF_ 2048
#define E_   3
#define U_   40
#define R_   8192
#define SCALE_ 0.125f
#define EPS_ 1e-5f

typedef __bf16 bf16x8 __attribute__((ext_vector_type(8)));
typedef float f32x4 __attribute__((ext_vector_type(4)));

__device__ inline unsigned short f2bf(float x) {
  unsigned int u = __float_as_uint(x);
  unsigned int r = (u + 0x7fffu + ((u >> 16) & 1u)) >> 16;
  return (unsigned short)r;
}
__device__ inline float bflo(unsigned u) { return __uint_as_float(u << 16); }
__device__ inline float bfhi(unsigned u) { return __uint_as_float(u & 0xffff0000u); }
__device__ inline float bf1(unsigned short u) { return __uint_as_float((unsigned)u << 16); }

// ---------------------------------------------------------------------------
// Weight transpose fp32 [R][C] -> bf16 [C][R].
// ---------------------------------------------------------------------------
__global__ __launch_bounds__(256) void wtrans(
    const float* __restrict__ s0, const float* __restrict__ s1,
    const float* __restrict__ s2, const float* __restrict__ s3,
    unsigned short* __restrict__ dst, int R, int C, int permat) {
  __shared__ float tile[32][33];
  int z = blockIdx.z;
  int which = z / 3, e = z % 3;
  const float* src = (which == 0 ? s0 : which == 1 ? s1 : which == 2 ? s2 : s3);
  src += (size_t)e * permat;
  unsigned short* d = dst + (size_t)z * permat;
  int c0 = blockIdx.x << 5, r0 = blockIdx.y << 5;
  int tx = threadIdx.x & 31, ty = threadIdx.x >> 5;
  for (int rr = ty; rr < 32; rr += 8)
    tile[rr][tx] = src[(size_t)(r0 + rr) * C + c0 + tx];
  __syncthreads();
  for (int cc = ty; cc < 32; cc += 8)
    d[(size_t)(c0 + cc) * R + r0 + tx] = f2bf(tile[tx][cc]);
}

// ---------------------------------------------------------------------------
// x = DNAs @ W_pre + b_pre ; residual stream is bf16-only: writes Xbf.
// ---------------------------------------------------------------------------
__global__ __launch_bounds__(256) void pre_kernel(
    const float* __restrict__ DNAs, const float* __restrict__ Wp,
    const float* __restrict__ bp, unsigned short* __restrict__ Xbf) {
  int i = (blockIdx.x * 256 + threadIdx.x) << 1;
  int r = i >> 9, d0 = i & 511;
  float4 dna = *(const float4*)(DNAs + r * 4);
  float v0 = dna.x * Wp[d0] + dna.y * Wp[512 + d0] + dna.z * Wp[1024 + d0] +
             dna.w * Wp[1536 + d0] + bp[d0];
  int d1 = d0 + 1;
  float v1 = dna.x * Wp[d1] + dna.y * Wp[512 + d1] + dna.z * Wp[1024 + d1] +
             dna.w * Wp[1536 + d1] + bp[d1];
  *(unsigned*)(Xbf + i) = (unsigned)f2bf(v0) | ((unsigned)f2bf(v1) << 16);
}

// ---------------------------------------------------------------------------
// bf16 MFMA GEMM, 256x128 tile, 512 threads (8 waves, 4x2), BK=64,
// XOR-swizzled LDS, XCD affinity. OUT: 1 bf16 QKV remap.
// ---------------------------------------------------------------------------
template <int OUT, bool QKVZ>
__global__ __launch_bounds__(512, 4) void mgemm512(
    const unsigned short* __restrict__ A, const unsigned short* __restrict__ BT,
    const float* __restrict__ bias0, const float* __restrict__ bias1,
    const float* __restrict__ bias2, unsigned short* __restrict__ Cb,
    int M, int N, int K) {
  __shared__ unsigned short As[256 * 64];
  __shared__ unsigned short Bs[128 * 64];
  const int t = threadIdx.x, l = t & 63, w = t >> 6;
  const int id = blockIdx.x;
  const int m0 = (id & 31) << 8;
  const int n0 = (id >> 5) << 7;
  const int wm = w >> 1, wn = w & 1;
  const float* bias = bias0;
  if (QKVZ) {
    int z = blockIdx.z;
    BT += (size_t)z * 3 * 262144;
    bias = (z == 0 ? bias0 : z == 1 ? bias1 : bias2);
    Cb += (size_t)z * 4194304;
  }
  f32x4 acc[4][4] = {};

  const int srow = l >> 3;
  const int gslot = (l & 7) ^ srow;

  for (int k0 = 0; k0 < K; k0 += 64) {
#pragma unroll
    for (int j = 0; j < 4; ++j) {
      int c = (w << 2) + j;
      int row = (c << 3) + srow;
      const unsigned short* ga = A + (size_t)(m0 + row) * K + k0 + gslot * 8;
      __builtin_amdgcn_global_load_lds(
          (const __attribute__((address_space(1))) void*)ga,
          (__attribute__((address_space(3))) void*)(As + (c << 9)), 16, 0, 0);
    }
#pragma unroll
    for (int j = 0; j < 2; ++j) {
      int cb = (w << 1) + j;
      int brow = (cb << 3) + srow;
      const unsigned short* gb = BT + (size_t)(n0 + brow) * K + k0 + gslot * 8;
      __builtin_amdgcn_global_load_lds(
          (const __attribute__((address_space(1))) void*)gb,
          (__attribute__((address_space(3))) void*)(Bs + (cb << 9)), 16, 0, 0);
    }
    __syncthreads();
#pragma unroll
    for (int ks = 0; ks < 2; ++ks) {
      bf16x8 af[4], bg[4];
      int slot = (ks << 2) + (l >> 4);
#pragma unroll
      for (int i = 0; i < 4; ++i) {
        int ar = (wm << 6) + (i << 4) + (l & 15);
        af[i] = *(const bf16x8*)(As + ar * 64 + (slot ^ (ar & 7)) * 8);
        int br = (wn << 6) + (i << 4) + (l & 15);
        bg[i] = *(const bf16x8*)(Bs + br * 64 + (slot ^ (br & 7)) * 8);
      }
#pragma unroll
      for (int i = 0; i < 4; ++i)
#pragma unroll
        for (int j = 0; j < 4; ++j)
          acc[i][j] = __builtin_amdgcn_mfma_f32_16x16x32_bf16(af[i], bg[j],
                                                              acc[i][j], 0, 0, 0);
    }
    __syncthreads();
  }

#pragma unroll
  for (int i = 0; i < 4; ++i) {
    int rbase = m0 + (wm << 6) + (i << 4) + ((l >> 4) << 2);
#pragma unroll
    for (int j = 0; j < 4; ++j) {
      int col = n0 + (wn << 6) + (j << 4) + (l & 15);
      float bv = bias[col];
#pragma unroll
      for (int r = 0; r < 4; ++r) {
        int row = rbase + r;
        float v = acc[i][j][r] + bv;
        if (OUT == 2) {
          v = fmaxf(v, 0.f);
          Cb[(size_t)row * N + col] = f2bf(v);
        } else {
          int b = row >> 11, ll = row & 2047, h = col >> 6, d = col & 63;
          Cb[((size_t)(((b << 3) + h) << 11) + ll) * 64 + d] = f2bf(v);
        }
      }
    }
  }
}

// ---------------------------------------------------------------------------
// bf16 MFMA GEMM (128xBN tile, 256 thr, DBUF). BN=64 -> more blocks/CU for
// short-N shapes (Wo, FFN2, and now FFN1 with OUT==2 ReLU).
// OUT: 2 = bf16+ReLU; 3 = bf16 [M,N].
// ---------------------------------------------------------------------------
template <int OUT, bool DBUF, int BN>
__global__ __launch_bounds__(256) void mgemm(
    const unsigned short* __restrict__ A, const unsigned short* __restrict__ BT,
    const float* __restrict__ bias0, unsigned short* __restrict__ Cb,
    int M, int N, int K) {
  constexpr int NFRAG = BN / 32;
  constexpr int ASZ = 128 * 64, BSZ = BN * 64;
  __shared__ unsigned short As[(DBUF ? 2 : 1) * ASZ];
  __shared__ unsigned short Bs[(DBUF ? 2 : 1) * BSZ];
  const int t = threadIdx.x, l = t & 63, w = t >> 6;
  const int id = blockIdx.x;
  const int m0 = (id & 63) << 7;
  const int n0 = (id >> 6) * BN;
  const int wm = w >> 1, wn = w & 1;
  const float* bias = bias0;
  f32x4 acc[4][NFRAG] = {};

  const int srow = l >> 3;
  const int gslot = (l & 7) ^ srow;

  auto stage = [&](int buf, int k0) {
#pragma unroll
    for (int j = 0; j < 4; ++j) {
      int c = (w << 2) + j;
      int row = (c << 3) + srow;
      const unsigned short* ga = A + (size_t)(m0 + row) * K + k0 + gslot * 8;
      __builtin_amdgcn_global_load_lds(
          (const __attribute__((address_space(1))) void*)ga,
          (__attribute__((address_space(3))) void*)(As + buf * ASZ + (c << 9)), 16, 0, 0);
      if (BN == 128 || j < 2) {
        int cb = (BN == 128) ? c : ((w << 1) + j);
        int brow = (cb << 3) + srow;
        const unsigned short* gb = BT + (size_t)(n0 + brow) * K + k0 + gslot * 8;
        __builtin_amdgcn_global_load_lds(
            (const __attribute__((address_space(1))) void*)gb,
            (__attribute__((address_space(3))) void*)(Bs + buf * BSZ + (cb << 9)), 16, 0, 0);
      }
    }
  };
  auto compute = [&](int buf) {
#pragma unroll
    for (int ks = 0; ks < 2; ++ks) {
      bf16x8 af[4], bg[NFRAG];
      int slot = (ks << 2) + (l >> 4);
#pragma unroll
      for (int i = 0; i < 4; ++i) {
        int ar = (wm << 6) + (i << 4) + (l & 15);
        af[i] = *(const bf16x8*)(As + buf * ASZ + ar * 64 + (slot ^ (ar & 7)) * 8);
      }
#pragma unroll
      for (int j = 0; j < NFRAG; ++j) {
        int br = wn * (BN >> 1) + (j << 4) + (l & 15);
        bg[j] = *(const bf16x8*)(Bs + buf * BSZ + br * 64 + (slot ^ (br & 7)) * 8);
      }
#pragma unroll
      for (int i = 0; i < 4; ++i)
#pragma unroll
        for (int j = 0; j < NFRAG; ++j)
          acc[i][j] = __builtin_amdgcn_mfma_f32_16x16x32_bf16(af[i], bg[j],
                                                              acc[i][j], 0, 0, 0);
    }
  };

  if (DBUF) {
    int nk = K >> 6, cur = 0;
    stage(0, 0);
    __syncthreads();
    for (int s = 0; s < nk; ++s) {
      if (s + 1 < nk) stage(cur ^ 1, (s + 1) << 6);
      compute(cur);
      __syncthreads();
      cur ^= 1;
    }
  } else {
    for (int k0 = 0; k0 < K; k0 += 64) {
      stage(0, k0);
      __syncthreads();
      compute(0);
      __syncthreads();
    }
  }

#pragma unroll
  for (int i = 0; i < 4; ++i) {
    int rbase = m0 + (wm << 6) + (i << 4) + ((l >> 4) << 2);
#pragma unroll
    for (int j = 0; j < NFRAG; ++j) {
      int col = n0 + wn * (BN >> 1) + (j << 4) + (l & 15);
      float bv = bias[col];
#pragma unroll
      for (int r = 0; r < 4; ++r) {
        int row = rbase + r;
        float v = acc[i][j][r] + bv;
        if (OUT == 2) v = fmaxf(v, 0.f);
        Cb[(size_t)row * N + col] = f2bf(v);
      }
    }
  }
}

// ---------------------------------------------------------------------------
// MERGED: qk_m (blocks 0..2047) ∥ vmean (blocks 2048..2079).
// ---------------------------------------------------------------------------
__global__ __launch_bounds__(256) void qkm_vmean_kernel(
    const unsigned short* __restrict__ Q, const unsigned short* __restrict__ K,
    const int* __restrict__ sidx, float* __restrict__ Mout,
    const unsigned short* __restrict__ V, float* __restrict__ VM,
    unsigned short* __restrict__ VMbf) {
  __shared__ float p[4][64];
  int bid = blockIdx.x;
  int t = threadIdx.x;
  if (bid < 2048) {
    int wave = t >> 6, lane = t & 63;
    int grp = lane >> 3, sub = lane & 7;
    int bh = bid & 31;
    int j = bid >> 5;
    int item = (bh << 11) + (j << 5) + wave * 8 + grp;
    int l = item & 2047;
    uint4 qv = *(const uint4*)(Q + ((size_t)item << 6) + (sub << 3));
    float qf[8] = {bflo(qv.x), bfhi(qv.x), bflo(qv.y), bfhi(qv.y),
                   bflo(qv.z), bfhi(qv.z), bflo(qv.w), bfhi(qv.w)};
    const unsigned short* Kb = K + (((size_t)bh << 11) << 6) + (sub << 3);
    const int* sp = sidx + l * U_;
    float mx = -INFINITY, sm = 0.f;
#pragma unroll 8
    for (int u = 0; u < U_; ++u) {
      int kidx = sp[u];
      uint4 kv = *(const uint4*)(Kb + ((size_t)kidx << 6));
      float pd = qf[0] * bflo(kv.x);
      pd = fmaf(qf[1], bfhi(kv.x), pd);
      pd = fmaf(qf[2], bflo(kv.y), pd);
      pd = fmaf(qf[3], bfhi(kv.y), pd);
      pd = fmaf(qf[4], bflo(kv.z), pd);
      pd = fmaf(qf[5], bfhi(kv.z), pd);
      pd = fmaf(qf[6], bflo(kv.w), pd);
      pd = fmaf(qf[7], bfhi(kv.w), pd);
      pd += __shfl_xor(pd, 1);
      pd += __shfl_xor(pd, 2);
      pd += __shfl_xor(pd, 4);
      mx = fmaxf(mx, pd);
      sm += pd;
    }
    if (sub == 0) Mout[item] = mx - sm * (1.0f / U_);
  } else {
    int bh = bid - 2048;
    int d = t & 63, c = t >> 6;
    const unsigned short* Vb = V + (((size_t)bh << 11) + c * 512) * 64;
    float s = 0.f;
    for (int l = 0; l < 512; ++l) s += bf1(Vb[l * 64 + d]);
    p[c][d] = s;
    __syncthreads();
    if (t < 64) {
      float m = (p[0][d] + p[1][d] + p[2][d] + p[3][d]) * (1.0f / 2048.0f);
      VM[bh * 64 + d] = m;
      VMbf[bh * 64 + d] = f2bf(m);
    }
  }
}

// ---------------------------------------------------------------------------
// MERGED: ctxfill (blocks 0..2047) ∥ topk radix select (blocks 2048..2079).
// ---------------------------------------------------------------------------
__global__ __launch_bounds__(256) void ctxfill_topk_kernel(
    const unsigned short* __restrict__ VMbf, unsigned short* __restrict__ CTX,
    const float* __restrict__ Mb, int* __restrict__ TOP) {
  __shared__ unsigned vals[2048];
  __shared__ int hist[256];
  __shared__ int suf[256];
  __shared__ unsigned s_prefix;
  __shared__ int s_want, s_cnt, s_run;
  __shared__ int wcnt[4];
  int bid = blockIdx.x, t = threadIdx.x;
  if (bid < 2048) {
    int t8 = (bid * 256 + t) << 3;
    int c0 = t8 & 511;
    int b = t8 >> 20;
    *(uint4*)(CTX + t8) = *(const uint4*)(VMbf + (b << 9) + c0);
    return;
  }
  int bh = bid - 2048;
  int lane = t & 63, w = t >> 6;
  for (int i = t; i < 2048; i += 256) {
    unsigned u = __float_as_uint(Mb[bh * 2048 + i]);
    vals[i] = (u & 0x80000000u) ? ~u : (u | 0x80000000u);
  }
  if (t == 0) { s_prefix = 0; s_want = U_; s_cnt = 0; s_run = 0; }
  __syncthreads();
#pragma unroll
  for (int shift = 24; shift >= 0; shift -= 8) {
    unsigned pref = s_prefix;
    int want = s_want;
    unsigned hmask = (shift == 24) ? 0u : (0xFFFFFFFFu << (shift + 8));
    hist[t] = 0;
    __syncthreads();
    for (int i = t; i < 2048; i += 256) {
      unsigned v = vals[i];
      if ((v & hmask) == pref) atomicAdd(&hist[(v >> shift) & 255], 1);
    }
    __syncthreads();
    suf[t] = hist[t];
    __syncthreads();
    for (int off = 1; off < 256; off <<= 1) {
      int add = (t + off < 256) ? suf[t + off] : 0;
      __syncthreads();
      suf[t] += add;
      __syncthreads();
    }
    int cgt = (t == 255) ? 0 : suf[t + 1];
    if (suf[t] >= want && cgt < want) {
      s_prefix = pref | ((unsigned)t << shift);
      s_want = want - cgt;
    }
    __syncthreads();
  }
  unsigned T = s_prefix;
  int want_eq = s_want;
  int base = U_ - want_eq;
  for (int i = t; i < 2048; i += 256) {
    if (vals[i] > T) {
      int slot = atomicAdd(&s_cnt, 1);
      TOP[bh * U_ + slot] = i;
    }
  }
  for (int c = 0; c < 8; ++c) {
    int i = (c << 8) + t;
    bool eq = (vals[i] == T);
    unsigned long long m = __ballot(eq);
    if (lane == 0) wcnt[w] = __popcll(m);
    __syncthreads();
    int woff = 0;
    for (int ww = 0; ww < w; ++ww) woff += wcnt[ww];
    if (eq) {
      int rank = s_run + woff + __popcll(m & ((1ull << lane) - 1ull));
      if (rank < want_eq) TOP[bh * U_ + base + rank] = i;
    }
    __syncthreads();
    if (t == 0) s_run += wcnt[0] + wcnt[1] + wcnt[2] + wcnt[3];
    __syncthreads();
  }
}

// ---------------------------------------------------------------------------
// S[bh,u,k] = scale * dot(Q[top[bh,u]], K[bh,k]) — bf16 inputs, fp32 LDS.
// ---------------------------------------------------------------------------
__global__ __launch_bounds__(256) void attn_score(
    const unsigned short* __restrict__ Q, const unsigned short* __restrict__ K,
    const int* __restrict__ TOP, float* __restrict__ S) {
  __shared__ float Ks[128 * 65];
  __shared__ float Qs[40 * 64];
  int bh = blockIdx.y, k0 = blockIdx.x << 7;
  int t = threadIdx.x;
  const unsigned short* Kbase = K + (((size_t)bh << 11) << 6);
  for (int i = t; i < 4096; i += 256) {
    int k = i >> 5, dp = i & 31;
    unsigned u = *(const unsigned*)(Kbase + ((size_t)(k0 + k) << 6) + (dp << 1));
    Ks[k * 65 + (dp << 1)] = bflo(u);
    Ks[k * 65 + (dp << 1) + 1] = bfhi(u);
  }
  for (int i = t; i < 1280; i += 256) {
    int uq = i >> 5, dp = i & 31;
    int row = TOP[bh * U_ + uq];
    unsigned u = *(const unsigned*)(Q + ((((size_t)bh << 11) + row) << 6) + (dp << 1));
    Qs[uq * 64 + (dp << 1)] = bflo(u);
    Qs[uq * 64 + (dp << 1) + 1] = bfhi(u);
  }
  __syncthreads();
  int kk = t & 127, ug = (t >> 7) * 20;
  const float* kp = Ks + kk * 65;
  for (int u = ug; u < ug + 20; ++u) {
    const float* qp = Qs + u * 64;
    float s = 0.f;
#pragma unroll 8
    for (int d = 0; d < 64; ++d) s = fmaf(qp[d], kp[d], s);
    S[((size_t)bh * U_ + u) * 2048 + k0 + kk] = s * SCALE_;
  }
}

// ---------------------------------------------------------------------------
// attn_pv_part: K-split PV (4 chunks), bf16 V staged->fp32 LDS. grid 640.
// ---------------------------------------------------------------------------
__global__ __launch_bounds__(512) void attn_pv_part(
    const float* __restrict__ S, const unsigned short* __restrict__ V,
    float* __restrict__ PART, float* __restrict__ IRED) {
  __shared__ float Vs[128][64];
  __shared__ float ps[8][128];
  __shared__ float mred[8];
  int id = blockIdx.x;
  int bh = id & 31, sub = id >> 5;
  int ug = sub >> 2, kc = sub & 3;
  int t = threadIdx.x, lane = t & 63, w = t >> 6;
  int rowbase = bh * U_ + ug * 8;
  int row = rowbase + w;

  const float* Sr = S + (size_t)row * 2048;
  float mx = -INFINITY;
  for (int j = 0; j < 32; ++j) mx = fmaxf(mx, Sr[j * 64 + lane]);
#pragma unroll
  for (int s = 32; s; s >>= 1) mx = fmaxf(mx, __shfl_xor(mx, s));
  float sm = 0.f;
  for (int j = 0; j < 32; ++j) sm += __expf(Sr[j * 64 + lane] - mx);
#pragma unroll
  for (int s = 32; s; s >>= 1) sm += __shfl_xor(sm, s);
  if (lane == 0) {
    mred[w] = mx;
    if (kc == 0) IRED[row] = 1.0f / sm;
  }
  __syncthreads();

  const unsigned short* Vb = V + (((size_t)bh << 11) << 6);
  float a0 = 0.f, a1 = 0.f, a2 = 0.f, a3 = 0.f;
  for (int c = kc * 4; c < kc * 4 + 4; ++c) {
    int k0 = c << 7;
#pragma unroll
    for (int i = 0; i < 8; ++i) {
      int pe = t + i * 512;
      int k = pe >> 5, dp = pe & 31;
      unsigned u = *(const unsigned*)(Vb + ((size_t)(k0 + k) << 6) + (dp << 1));
      Vs[k][(dp << 1)] = bflo(u);
      Vs[k][(dp << 1) + 1] = bfhi(u);
    }
#pragma unroll
    for (int i = 0; i < 2; ++i) {
      int e = t + i * 512;
      int r = e >> 7, kk = e & 127;
      ps[r][kk] = __expf(S[(size_t)(rowbase + r) * 2048 + k0 + kk] - mred[r]);
    }
    __syncthreads();
    const float* p = ps[w];
#pragma unroll 4
    for (int kk = 0; kk < 128; kk += 4) {
      float4 p4 = *(const float4*)(p + kk);
      a0 = fmaf(p4.x, Vs[kk + 0][lane], a0);
      a1 = fmaf(p4.y, Vs[kk + 1][lane], a1);
      a2 = fmaf(p4.z, Vs[kk + 2][lane], a2);
      a3 = fmaf(p4.w, Vs[kk + 3][lane], a3);
    }
    __syncthreads();
  }
  PART[((size_t)kc * 1280 + row) * 64 + lane] = (a0 + a1) + (a2 + a3);
}

// ---------------------------------------------------------------------------
// pv_reduce: sum 4 partials (fixed order), scale, fused bf16 scatter.
// ---------------------------------------------------------------------------
__global__ __launch_bounds__(256) void pv_reduce(
    const float* __restrict__ PART, const float* __restrict__ IRED,
    const int* __restrict__ TOP, unsigned short* __restrict__ CTX) {
  int gid = blockIdx.x * 256 + threadIdx.x;
  int row = gid >> 6, lane = gid & 63;
  float v = (PART[(size_t)row * 64 + lane] + PART[(size_t)(1280 + row) * 64 + lane]) +
            (PART[(size_t)(2560 + row) * 64 + lane] + PART[(size_t)(3840 + row) * 64 + lane]);
  v *= IRED[row];
  int bh = row / U_;
  int b = bh >> 3, h = bh & 7;
  int orow = TOP[row];
  CTX[((size_t)((b << 11) + orow) << 9) + (h << 6) + lane] = f2bf(v);
}

// ---------------------------------------------------------------------------
// LayerNorm(512): residual stream in bf16. v = Xbf + Tbf; x = LN(v).
// ---------------------------------------------------------------------------
__global__ __launch_bounds__(256) void ln_kernel(
    const unsigned short* __restrict__ Xin, const unsigned short* __restrict__ Tin,
    const float* __restrict__ g, const float* __restrict__ bta,
    unsigned short* __restrict__ Xbf) {
  __shared__ float red[8];
  int r = blockIdx.x, t = threadIdx.x;
  int i0 = (r << 9) + (t << 1);
  unsigned xu = *(const unsigned*)(Xin + i0);
  unsigned tu = *(const unsigned*)(Tin + i0);
  float v0 = bflo(xu) + bflo(tu);
  float v1 = bfhi(xu) + bfhi(tu);
  float sm = v0 + v1;
#pragma unroll
  for (int s = 32; s; s >>= 1) sm += __shfl_xor(sm, s);
  int lane = t & 63, w = t >> 6;
  if (lane == 0) red[w] = sm;
  __syncthreads();
  float mean = (red[0] + red[1] + red[2] + red[3]) * (1.0f / 512.0f);
  float d0 = v0 - mean, d1 = v1 - mean;
  float sq = d0 * d0 + d1 * d1;
#pragma unroll
  for (int s = 32; s; s >>= 1) sq += __shfl_xor(sq, s);
  if (lane == 0) red[4 + w] = sq;
  __syncthreads();
  float var = (red[4] + red[5] + red[6] + red[7]) * (1.0f / 512.0f);
  float rstd = rsqrtf(var + EPS_);
  float2 gv = *(const float2*)(g + (t << 1));
  float2 bv = *(const float2*)(bta + (t << 1));
  float o0 = d0 * rstd * gv.x + bv.x;
  float o1 = d1 * rstd * gv.y + bv.y;
  *(unsigned*)(Xbf + i0) = (unsigned)f2bf(o0) | ((unsigned)f2bf(o1) << 16);
}

// ---------------------------------------------------------------------------
// out = softmax(LN(x; lnf) @ W_out + b_out); x in bf16. One wave per row.
// ---------------------------------------------------------------------------
__global__ __launch_bounds__(256) void out_kernel(
    const unsigned short* __restrict__ X, const float* __restrict__ lg,
    const float* __restrict__ lb, const float* __restrict__ Wout,
    const float* __restrict__ bout, float* __restrict__ out) {
  int w = threadIdx.x >> 6, lane = threadIdx.x & 63;
  int r = blockIdx.x * 4 + w;
  float xv[8];
  float sm = 0.f;
#pragma unroll
  for (int j = 0; j < 8; ++j) {
    xv[j] = bf1(X[(r << 9) + lane + (j << 6)]);
    sm += xv[j];
  }
#pragma unroll
  for (int s = 32; s; s >>= 1) sm += __shfl_xor(sm, s);
  float mean = sm * (1.0f / 512.0f);
  float sq = 0.f;
#pragma unroll
  for (int j = 0; j < 8; ++j) {
    float d = xv[j] - mean;
    sq += d * d;
  }
#pragma unroll
  for (int s = 32; s; s >>= 1) sq += __shfl_xor(sq, s);
  float rstd = rsqrtf(sq * (1.0f / 512.0f) + EPS_);
  float p0 = 0.f, p1 = 0.f, p2 = 0.f;
#pragma unroll
  for (int j = 0; j < 8; ++j) {
    int d = lane + (j << 6);
    float xn = (xv[j] - mean) * rstd * lg[d] + lb[d];
    p0 = fmaf(xn, Wout[d * 3 + 0], p0);
    p1 = fmaf(xn, Wout[d * 3 + 1], p1);
    p2 = fmaf(xn, Wout[d * 3 + 2], p2);
  }
#pragma unroll
  for (int s = 32; s; s >>= 1) {
    p0 += __shfl_xor(p0, s);
    p1 += __shfl_xor(p1, s);
    p2 += __shfl_xor(p2, s);
  }
  if (lane == 0) {
    p0 += bout[0]; p1 += bout[1]; p2 += bout[2];
    float m = fmaxf(p0, fmaxf(p1, p2));
    float e0 = __expf(p0 - m), e1 = __expf(p1 - m), e2 = __expf(p2 - m);
    float z = 1.0f / (e0 + e1 + e2);
    out[r * 3 + 0] = e0 * z;
    out[r * 3 + 1] = e1 * z;
    out[r * 3 + 2] = e2 * z;
  }
}

// ---------------------------------------------------------------------------
extern "C" void kernel_launch(void* const* d_in, const int* in_sizes, int n_in,
                              void* d_out, int out_size, void* d_ws, size_t ws_size,
                              hipStream_t stream) {
  const float* DNAs  = (const float*)d_in[0];
  const float* W_pre = (const float*)d_in[1];
  const float* b_pre = (const float*)d_in[2];
  const float* Wq    = (const float*)d_in[3];
  const float* bq    = (const float*)d_in[4];
  const float* Wk    = (const float*)d_in[5];
  const float* bk    = (const float*)d_in[6];
  const float* Wv    = (const float*)d_in[7];
  const float* bv    = (const float*)d_in[8];
  const float* Wo    = (const float*)d_in[9];
  const float* bo    = (const float*)d_in[10];
  const float* ln1_g = (const float*)d_in[11];
  const float* ln1_b = (const float*)d_in[12];
  const float* W1    = (const float*)d_in[13];
  const float* b1    = (const float*)d_in[14];
  const float* W2    = (const float*)d_in[15];
  const float* b2    = (const float*)d_in[16];
  const float* ln2_g = (const float*)d_in[17];
  const float* ln2_b = (const float*)d_in[18];
  const float* lnf_g = (const float*)d_in[19];
  const float* lnf_b = (const float*)d_in[20];
  const float* W_out = (const float*)d_in[21];
  const float* b_out = (const float*)d_in[22];
  const int*   sidx  = (const int*)d_in[23];
  float* out = (float*)d_out;

  float* ws = (float*)d_ws;
  unsigned short* Xbf   = (unsigned short*)(ws + 4194304);
  unsigned short* QKVbf = (unsigned short*)(ws + 6291456);
  unsigned short* Qbf   = QKVbf;
  unsigned short* Kbf   = QKVbf + 4194304;
  unsigned short* Vbf   = QKVbf + 8388608;
  unsigned short* Tbf   = (unsigned short*)(ws + 12582912);
  float*          PART  = ws;
  float*          IRED  = ws + 327680;
  float*          S     = ws + 14680064;
  unsigned short* HBbf  = (unsigned short*)(ws + 14680064);
  unsigned short* CTXbf = (unsigned short*)(ws + 23068672);
  unsigned short* WT    = (unsigned short*)(ws + 25165824);
  float*          Mb    = ws + 29884416;
  float*          VM    = ws + 29949952;
  int*            TOP   = (int*)(ws + 29952000);
  unsigned short* VMbf  = (unsigned short*)(ws + 29953280);
  unsigned short* WTqkvo = WT;
  unsigned short* WT1    = WT + 3145728;
  unsigned short* WT2    = WT + 6291456;
  (void)in_sizes; (void)n_in; (void)out_size; (void)ws_size;

  wtrans<<<dim3(16, 16, 12), 256, 0, stream>>>(Wq, Wk, Wv, Wo, WTqkvo, 512, 512, 262144);
  wtrans<<<dim3(64, 16, 3), 256, 0, stream>>>(W1, nullptr, nullptr, nullptr, WT1, 512, 2048, 1048576);
  wtrans<<<dim3(16, 64, 3), 256, 0, stream>>>(W2, nullptr, nullptr, nullptr, WT2, 2048, 512, 1048576);

  pre_kernel<<<8192, 256, 0, stream>>>(DNAs, W_pre, b_pre, Xbf);

  for (int i = 0; i < E_; ++i) {
    const int bOff = i * DM_;
    mgemm512<1, true><<<dim3(128, 1, 3), 512, 0, stream>>>(
        Xbf, WTqkvo + (size_t)i * 262144, bq + bOff, bk + bOff, bv + bOff,
        QKVbf, R_, DM_, DM_);

    qkm_vmean_kernel<<<2080, 256, 0, stream>>>(Qbf, Kbf, sidx, Mb, Vbf, VM, VMbf);
    ctxfill_topk_kernel<<<2080, 256, 0, stream>>>(VMbf, CTXbf, Mb, TOP);
    attn_score<<<dim3(16, 32), 256, 0, stream>>>(Qbf, Kbf, TOP, S);
    attn_pv_part<<<640, 512, 0, stream>>>(S, Vbf, PART, IRED);
    pv_reduce<<<320, 256, 0, stream>>>(PART, IRED, TOP, CTXbf);

    mgemm<3, true, 64><<<512, 256, 0, stream>>>(
        CTXbf, WTqkvo + (size_t)(9 + i) * 262144, bo + bOff, Tbf, R_, DM_, DM_);
    ln_kernel<<<8192, 256, 0, stream>>>(Xbf, Tbf, ln1_g + bOff, ln1_b + bOff, Xbf);

    mgemm<2, true, 64><<<2048, 256, 0, stream>>>(
        Xbf, WT1 + (size_t)i * 1048576, b1 + i * DFF_, HBbf, R_, DFF_, DM_);
    mgemm<3, true, 64><<<512, 256, 0, stream>>>(
        HBbf, WT2 + (size_t)i * 1048576, b2 + bOff, Tbf, R_, DM_, DFF_);
    ln_kernel<<<8192, 256, 0, stream>>>(Xbf, Tbf, ln2_g + bOff, ln2_b + bOff, Xbf);
  }

  out_kernel<<<2048, 256, 0, stream>>>(Xbf, lnf_g, lnf_b, W_out, b_out, out);
}